// Round 1
// baseline (991.800 us; speedup 1.0000x reference)
//
#include <hip/hip_runtime.h>
#include <cstddef>

#define DEV static __device__ __forceinline__

DEV float siluf(float v) { return v / (1.f + expf(-v)); }

// ---------------------------------------------------------------------------
// Tiled fp32 GEMM: C[b,o,p] = bias[o] + sum_k W[o,k] * X_b[k,p]
// W: M x K row-major.
// XT=0: X per-batch K x N row-major (n contiguous).
// XT=1: X per-batch N x K row-major (k contiguous).
// EPI=0: Y0[b,o,p] = v
// EPI=1: (M=512) o<256 -> Y0[b,o,p]=v ; o>=256 -> Y1[b,o-256,p]=silu(v)
// 64x64 tile / block of 256 threads, 4x4 micro-tile, K-chunks of 16.
// ---------------------------------------------------------------------------
template <int XT, int EPI>
__global__ __launch_bounds__(256) void gemm_k(
    const float* __restrict__ W, const float* __restrict__ X,
    const float* __restrict__ bias, float* __restrict__ Y0, float* __restrict__ Y1,
    int M, int N, int K, int Mt, int Nt)
{
  __shared__ __align__(16) float Wt[16][68];   // [k][o], pitch 68 avoids bank conflicts
  __shared__ __align__(16) float Xt[16][68];   // [k][p]
  int bid = blockIdx.x;
  int tiles = Mt * Nt;
  int bb = bid / tiles;
  int rr = bid - bb * tiles;
  int m0 = (rr / Nt) * 64;
  int n0 = (rr % Nt) * 64;
  const float* Xb = X + (size_t)bb * K * N;
  int t  = threadIdx.x;
  int tr = t >> 4, tc = t & 15;
  int kw = t & 15, ow = t >> 4;      // W-tile load mapping
  int px0 = t & 63, kx0 = t >> 6;    // X-tile load mapping (XT=0)
  int kx1 = t & 15, px1 = t >> 4;    // X-tile load mapping (XT=1)
  float acc[4][4] = {};

  for (int k0 = 0; k0 < K; k0 += 16) {
    __syncthreads();
#pragma unroll
    for (int i = 0; i < 4; i++)
      Wt[kw][ow + 16 * i] = W[(size_t)(m0 + ow + 16 * i) * K + k0 + kw];
    if (XT == 0) {
#pragma unroll
      for (int i = 0; i < 4; i++)
        Xt[kx0 + 4 * i][px0] = Xb[(size_t)(k0 + kx0 + 4 * i) * N + n0 + px0];
    } else {
#pragma unroll
      for (int i = 0; i < 4; i++)
        Xt[kx1][px1 + 16 * i] = Xb[(size_t)(n0 + px1 + 16 * i) * K + k0 + kx1];
    }
    __syncthreads();
#pragma unroll
    for (int k = 0; k < 16; k++) {
      float4 av = *(const float4*)&Wt[k][tr * 4];
      float4 bv = *(const float4*)&Xt[k][tc * 4];
      acc[0][0] += av.x * bv.x; acc[0][1] += av.x * bv.y; acc[0][2] += av.x * bv.z; acc[0][3] += av.x * bv.w;
      acc[1][0] += av.y * bv.x; acc[1][1] += av.y * bv.y; acc[1][2] += av.y * bv.z; acc[1][3] += av.y * bv.w;
      acc[2][0] += av.z * bv.x; acc[2][1] += av.z * bv.y; acc[2][2] += av.z * bv.z; acc[2][3] += av.z * bv.w;
      acc[3][0] += av.w * bv.x; acc[3][1] += av.w * bv.y; acc[3][2] += av.w * bv.z; acc[3][3] += av.w * bv.w;
    }
  }

#pragma unroll
  for (int i = 0; i < 4; i++) {
    int o = m0 + tr * 4 + i;
    float bv = bias[o];
    float4 v = make_float4(acc[i][0] + bv, acc[i][1] + bv, acc[i][2] + bv, acc[i][3] + bv);
    if (EPI == 0) {
      *(float4*)&Y0[((size_t)bb * M + o) * N + n0 + tc * 4] = v;
    } else {
      if (o < 256) {
        *(float4*)&Y0[((size_t)bb * 256 + o) * N + n0 + tc * 4] = v;
      } else {
        v.x = siluf(v.x); v.y = siluf(v.y); v.z = siluf(v.z); v.w = siluf(v.w);
        *(float4*)&Y1[((size_t)bb * 256 + (o - 256)) * N + n0 + tc * 4] = v;
      }
    }
  }
}

// ---------------------------------------------------------------------------
// Transpose sz (b,c,p) -> szT (b,p,c).  32x32 LDS tiles.
// ---------------------------------------------------------------------------
__global__ __launch_bounds__(256) void transpose_k(const float* __restrict__ in,
                                                   float* __restrict__ outp)
{
  __shared__ float tile[32][33];
  int b  = blockIdx.y;
  int pt = blockIdx.x & 31;   // 1024/32 p-tiles
  int ct = blockIdx.x >> 5;   // 256/32 c-tiles
  int p0 = pt * 32, c0 = ct * 32;
  int r  = threadIdx.x >> 5;  // 0..7
  int cc = threadIdx.x & 31;
#pragma unroll
  for (int i = 0; i < 4; i++) {
    int row = r + 8 * i;
    tile[row][cc] = in[((size_t)b * 256 + c0 + row) * 1024 + p0 + cc];
  }
  __syncthreads();
#pragma unroll
  for (int i = 0; i < 4; i++) {
    int row = r + 8 * i;
    outp[((size_t)b * 1024 + p0 + row) * 256 + c0 + cc] = tile[cc][row];
  }
}

// ---------------------------------------------------------------------------
// im2col for 2x2 stride-2 convs: out (b, k=c*4+i*2+j, n=y*Wo+x)
// ---------------------------------------------------------------------------
__global__ __launch_bounds__(256) void im2col2_k(const float* __restrict__ f1,
                                                 float* __restrict__ out)
{
  int idx = blockIdx.x * 256 + threadIdx.x;           // < 8*1024*256
  int n = idx & 255;
  int k = (idx >> 8) & 1023;
  int b = idx >> 18;
  int c = k >> 2, i = (k >> 1) & 1, j = k & 1;
  int y = n >> 4, x = n & 15;
  out[idx] = f1[((size_t)b * 256 + c) * 1024 + (2 * y + i) * 32 + (2 * x + j)];
}

__global__ __launch_bounds__(256) void im2col3_k(const float* __restrict__ f2,
                                                 float* __restrict__ out)
{
  int idx = blockIdx.x * 256 + threadIdx.x;           // < 8*1024*64
  int n = idx & 63;
  int k = (idx >> 6) & 1023;
  int b = idx >> 16;
  int c = k >> 2, i = (k >> 1) & 1, j = k & 1;
  int y = n >> 3, x = n & 7;
  out[idx] = f2[((size_t)b * 256 + c) * 256 + (2 * y + i) * 16 + (2 * x + j)];
}

// ---------------------------------------------------------------------------
// SSM projection: per tile of 16 positions, compute
//   xd[l,k] = sum_d x[b,d,l]*xw[k,d]   (k<40)
//   delta[b,l,d] = softplus(sum_r xd[l,r]*dtw[d,r] + dtb[d])
//   bc[b,l,0:16]=xd[l,8:24] (B), bc[b,l,16:32]=xd[l,24:40] (C)
// ---------------------------------------------------------------------------
__global__ __launch_bounds__(256) void proj_k(
    const float* __restrict__ xin, int L,
    const float* __restrict__ xw, const float* __restrict__ dtw,
    const float* __restrict__ dtb,
    float* __restrict__ delta_g, float* __restrict__ bc_g)
{
  __shared__ __align__(16) float xw_s[256 * 41];  // [d][k], pitch 41
  __shared__ __align__(16) float xs[256 * 16];    // [d][l]
  __shared__ __align__(16) float xd_s[16 * 40];   // [l][k]
  int t  = threadIdx.x;
  int b  = blockIdx.y;
  int l0 = blockIdx.x * 16;

#pragma unroll 8
  for (int i = 0; i < 40; i++) xw_s[t * 41 + i] = xw[i * 256 + t];
  {
    const float* xr = xin + ((size_t)b * 256 + t) * L + l0;
#pragma unroll
    for (int i = 0; i < 4; i++)
      *(float4*)&xs[t * 16 + 4 * i] = *(const float4*)&xr[4 * i];
  }
  __syncthreads();

#pragma unroll
  for (int ii = 0; ii < 3; ii++) {
    int idx = t + 256 * ii;
    if (idx < 640) {
      int l = idx / 40, k = idx - l * 40;
      float a0 = 0, a1 = 0, a2 = 0, a3 = 0;
      for (int d = 0; d < 256; d += 4) {
        a0 += xs[(d + 0) * 16 + l] * xw_s[(d + 0) * 41 + k];
        a1 += xs[(d + 1) * 16 + l] * xw_s[(d + 1) * 41 + k];
        a2 += xs[(d + 2) * 16 + l] * xw_s[(d + 2) * 41 + k];
        a3 += xs[(d + 3) * 16 + l] * xw_s[(d + 3) * 41 + k];
      }
      xd_s[l * 40 + k] = (a0 + a1) + (a2 + a3);
    }
  }
  __syncthreads();

  int d = t;
  float dtwv[8];
#pragma unroll
  for (int r = 0; r < 8; r++) dtwv[r] = dtw[d * 8 + r];
  float dtbv = dtb[d];
  size_t ob = (size_t)b * L + l0;
  for (int l = 0; l < 16; l++) {
    float s = dtbv;
#pragma unroll
    for (int r = 0; r < 8; r++) s += xd_s[l * 40 + r] * dtwv[r];
    float sp = fmaxf(s, 0.f) + log1pf(expf(-fabsf(s)));   // stable softplus
    delta_g[(ob + l) * 256 + d] = sp;
  }
  for (int ii = t; ii < 512; ii += 256) {
    int l = ii >> 5, c = ii & 31;
    bc_g[(ob + l) * 32 + c] = xd_s[l * 40 + 8 + c];
  }
}

// ---------------------------------------------------------------------------
// Selective-scan. Thread = (d-local, n). 768 blocks cover all
// (level, b, dir, d-group). Backward direction == same arrays traversed in
// reverse (pointwise projections commute with flip).
// ---------------------------------------------------------------------------
__global__ __launch_bounds__(256) void scan_k(
    const float* __restrict__ f1, const float* __restrict__ f2, const float* __restrict__ f3,
    const float* __restrict__ d1f, const float* __restrict__ bc1f,
    const float* __restrict__ d1b, const float* __restrict__ bc1b,
    const float* __restrict__ d2,  const float* __restrict__ bc2,
    const float* __restrict__ d3,  const float* __restrict__ bc3,
    float* __restrict__ y1f, float* __restrict__ y1b,
    float* __restrict__ y2f, float* __restrict__ y2b,
    float* __restrict__ y3f, float* __restrict__ y3b,
    const float* __restrict__ Al1, const float* __restrict__ Dv1,
    const float* __restrict__ Al2, const float* __restrict__ Dv2,
    const float* __restrict__ Al3, const float* __restrict__ Dv3)
{
  int bid = blockIdx.x;
  int lvl = bid >> 8;
  int r   = bid & 255;
  int b   = r >> 5;
  int dir = (r >> 4) & 1;
  int g   = r & 15;

  int L; const float *xin, *dlp, *bcp, *Alp, *Dvp; float* yo;
  if (lvl == 0) {
    L = 1024; xin = f1;
    if (dir == 0) { dlp = d1f; bcp = bc1f; Alp = Al1; Dvp = Dv1; yo = y1f; }
    else          { dlp = d1b; bcp = bc1b; Alp = Al2; Dvp = Dv2; yo = y1b; }
  } else if (lvl == 1) {
    L = 256; xin = f2; dlp = d2; bcp = bc2; Alp = Al2; Dvp = Dv2; yo = dir ? y2b : y2f;
  } else {
    L = 64;  xin = f3; dlp = d3; bcp = bc3; Alp = Al3; Dvp = Dv3; yo = dir ? y3b : y3f;
  }

  int t = threadIdx.x;
  int n = t & 15;
  int d = g * 16 + (t >> 4);
  float A   = -expf(Alp[d * 16 + n]);
  float Dvv = Dvp[d];
  size_t bL = (size_t)b * L;
  int l0 = dir ? (L - 1) : 0;
  const float* dp = dlp + (bL + l0) * 256 + d;
  const float* bp = bcp + (bL + l0) * 32 + n;
  const float* xp = xin + ((size_t)b * 256 + d) * L + l0;
  float*       yp = yo  + (bL + l0) * 256 + d;
  int dstep = dir ? -256 : 256;
  int bstep = dir ? -32 : 32;
  int xstep = dir ? -1 : 1;

  float h = 0.f;
  for (int s = 0; s < L; ++s) {
    float dv = *dp;
    float xv = *xp;
    float Bv = bp[0];
    float Cv = bp[16];
    h = h * expf(dv * A) + dv * Bv * xv;
    float p = h * Cv;
    p += __shfl_xor(p, 1);
    p += __shfl_xor(p, 2);
    p += __shfl_xor(p, 4);
    p += __shfl_xor(p, 8);
    if (n == 0) *yp = p + xv * Dvv;
    dp += dstep; bp += bstep; xp += xstep; yp += dstep;
  }
}

// ---------------------------------------------------------------------------
// LayerNorm(fwd) + LayerNorm(bwd) + optional 2x upsample add + optional *szT
// Block = one (b,l); 256 threads = d.
// ---------------------------------------------------------------------------
__global__ __launch_bounds__(256) void ln_combine(
    const float* __restrict__ yf, const float* __restrict__ yb,
    const float* __restrict__ gf, const float* __restrict__ bef,
    const float* __restrict__ gb, const float* __restrict__ beb,
    const float* __restrict__ up, int Wc,
    const float* __restrict__ szT, float* __restrict__ out,
    int L, int Wf)
{
  int bid = blockIdx.x;
  int b = bid / L;
  int l = bid - b * L;
  int d = threadIdx.x;
  size_t base = ((size_t)b * L + l) * 256 + d;
  float vf = yf[base], vb = yb[base];
  float4 s = make_float4(vf, vf * vf, vb, vb * vb);
#pragma unroll
  for (int m = 1; m < 64; m <<= 1) {
    s.x += __shfl_xor(s.x, m);
    s.y += __shfl_xor(s.y, m);
    s.z += __shfl_xor(s.z, m);
    s.w += __shfl_xor(s.w, m);
  }
  __shared__ float red[4][4];
  int w = threadIdx.x >> 6;
  if ((threadIdx.x & 63) == 0) {
    red[w][0] = s.x; red[w][1] = s.y; red[w][2] = s.z; red[w][3] = s.w;
  }
  __syncthreads();
  float s0 = red[0][0] + red[1][0] + red[2][0] + red[3][0];
  float s1 = red[0][1] + red[1][1] + red[2][1] + red[3][1];
  float s2 = red[0][2] + red[1][2] + red[2][2] + red[3][2];
  float s3 = red[0][3] + red[1][3] + red[2][3] + red[3][3];
  const float inv = 1.f / 256.f;
  float muf = s0 * inv, varf = s1 * inv - muf * muf;
  float mub = s2 * inv, varb = s3 * inv - mub * mub;
  float rf = rsqrtf(varf + 1e-5f);
  float rb = rsqrtf(varb + 1e-5f);
  float v = (vf - muf) * rf * gf[d] + bef[d] + (vb - mub) * rb * gb[d] + beb[d];
  if (up) {
    int y = l / Wf, x = l - y * Wf;
    int lc = (y >> 1) * Wc + (x >> 1);
    v += up[((size_t)b * (L >> 2) + lc) * 256 + d];
  }
  if (szT) v *= szT[base];
  out[base] = v;
}

// ---------------------------------------------------------------------------
extern "C" void kernel_launch(void* const* d_in, const int* in_sizes, int n_in,
                              void* d_out, int out_size, void* d_ws, size_t ws_size,
                              hipStream_t stream) {
  (void)in_sizes; (void)n_in; (void)out_size; (void)ws_size;
  const float* input_f = (const float*)d_in[0];
  const float* in_w  = (const float*)d_in[1];
  const float* in_b  = (const float*)d_in[2];
  const float* c1_w  = (const float*)d_in[3];
  const float* c1_b  = (const float*)d_in[4];
  const float* c2_w  = (const float*)d_in[5];
  const float* c2_b  = (const float*)d_in[6];
  const float* c3_w  = (const float*)d_in[7];
  const float* c3_b  = (const float*)d_in[8];
  const float* out_w = (const float*)d_in[9];
  const float* out_b = (const float*)d_in[10];
  const float* xw1  = (const float*)d_in[11];
  const float* dtw1 = (const float*)d_in[12];
  const float* dtb1 = (const float*)d_in[13];
  const float* Al1  = (const float*)d_in[14];
  const float* Dv1  = (const float*)d_in[15];
  const float* g1   = (const float*)d_in[16];
  const float* be1  = (const float*)d_in[17];
  const float* xw2  = (const float*)d_in[18];
  const float* dtw2 = (const float*)d_in[19];
  const float* dtb2 = (const float*)d_in[20];
  const float* Al2  = (const float*)d_in[21];
  const float* Dv2  = (const float*)d_in[22];
  const float* g2   = (const float*)d_in[23];
  const float* be2  = (const float*)d_in[24];
  const float* xw3  = (const float*)d_in[25];
  const float* dtw3 = (const float*)d_in[26];
  const float* dtb3 = (const float*)d_in[27];
  const float* Al3  = (const float*)d_in[28];
  const float* Dv3  = (const float*)d_in[29];
  const float* g3   = (const float*)d_in[30];
  const float* be3  = (const float*)d_in[31];

  float* ws = (float*)d_ws;
  constexpr size_t M1 = 2097152;     // 8*256*1024
  float* x    = ws + 0 * M1;         // (b,256,1024); later reused as d1f
  float* sz   = ws + 1 * M1;         // silu(z) (b,256,1024); reused as ic2, y1f
  float* szT  = ws + 2 * M1;         // (b,1024,256)
  float* f1   = ws + 3 * M1;         // (b,256,1024); reused as G
  float* d1b  = ws + 4 * M1;
  float* y1b  = ws + 5 * M1;
  size_t o = 6 * M1;
  float* f2   = ws + o; o += 524288;   // (b,256,256)
  float* f3   = ws + o; o += 131072;   // (b,256,64)
  float* ic3  = ws + o; o += 524288;   // (b,1024,64)
  float* bc1f = ws + o; o += 262144;
  float* bc1b = ws + o; o += 262144;
  float* d2   = ws + o; o += 524288;
  float* bc2  = ws + o; o += 65536;
  float* d3   = ws + o; o += 131072;
  float* bc3  = ws + o; o += 16384;
  float* y2f  = ws + o; o += 524288;
  float* y2b  = ws + o; o += 524288;
  float* y3f  = ws + o; o += 131072;
  float* y3b  = ws + o; o += 131072;
  float* y3c  = ws + o; o += 131072;
  float* y2c  = ws + o; o += 524288;
  // aliases (lifetimes verified against launch order below)
  float* d1f = x;    // x dead after c1
  float* ic2 = sz;   // sz dead after transpose
  float* y1f = sz;   // ic2 dead after c2 gemm
  float* G   = f1;   // f1 dead after scan

  dim3 blk(256);

  // 1. in-proj: xz = in_w @ input_f + in_b; split into x and silu(z)
  gemm_k<0, 1><<<dim3(1024), blk, 0, stream>>>(in_w, input_f, in_b, x, sz,
                                               512, 1024, 512, 8, 16);
  // 2. transpose silu(z) -> (b,p,c)
  transpose_k<<<dim3(256, 8), blk, 0, stream>>>(sz, szT);
  // 3. c1 1x1 conv
  gemm_k<0, 0><<<dim3(512), blk, 0, stream>>>(c1_w, x, c1_b, f1, nullptr,
                                              256, 1024, 256, 4, 16);
  // 4-5. c2 stride-2 conv (im2col + GEMM)
  im2col2_k<<<dim3(8192), blk, 0, stream>>>(f1, ic2);
  gemm_k<0, 0><<<dim3(128), blk, 0, stream>>>(c2_w, ic2, c2_b, f2, nullptr,
                                              256, 256, 1024, 4, 4);
  // 6-7. c3 stride-2 conv
  im2col3_k<<<dim3(2048), blk, 0, stream>>>(f2, ic3);
  gemm_k<0, 0><<<dim3(32), blk, 0, stream>>>(c3_w, ic3, c3_b, f3, nullptr,
                                             256, 64, 1024, 4, 1);
  // 8-11. SSM projections (level1 fwd uses params1; level1 BWD uses params2
  //        replicating the reference; levels 2/3 share across directions)
  proj_k<<<dim3(4, 8),  blk, 0, stream>>>(f3, 64,   xw3, dtw3, dtb3, d3,  bc3);
  proj_k<<<dim3(16, 8), blk, 0, stream>>>(f2, 256,  xw2, dtw2, dtb2, d2,  bc2);
  proj_k<<<dim3(64, 8), blk, 0, stream>>>(f1, 1024, xw1, dtw1, dtb1, d1f, bc1f);
  proj_k<<<dim3(64, 8), blk, 0, stream>>>(f1, 1024, xw2, dtw2, dtb2, d1b, bc1b);
  // 12. all scans (3 levels x 2 directions x 8 batches x 16 d-groups)
  scan_k<<<dim3(768), blk, 0, stream>>>(f1, f2, f3,
                                        d1f, bc1f, d1b, bc1b, d2, bc2, d3, bc3,
                                        y1f, y1b, y2f, y2b, y3f, y3b,
                                        Al1, Dv1, Al2, Dv2, Al3, Dv3);
  // 13-15. LN + combine (+upsample) (+silu multiply at level 1)
  ln_combine<<<dim3(512), blk, 0, stream>>>(y3f, y3b, g3, be3, g3, be3,
                                            nullptr, 0, nullptr, y3c, 64, 8);
  ln_combine<<<dim3(2048), blk, 0, stream>>>(y2f, y2b, g2, be2, g2, be2,
                                             y3c, 8, nullptr, y2c, 256, 16);
  ln_combine<<<dim3(8192), blk, 0, stream>>>(y1f, y1b, g1, be1, g2, be2,
                                             y2c, 16, szT, G, 1024, 32);
  // 16. out-proj: d_out[b,o,p] = out_b[o] + sum_c out_w[o,c]*G[b,p,c]
  gemm_k<1, 0><<<dim3(1024), blk, 0, stream>>>(out_w, G, out_b, (float*)d_out,
                                               nullptr, 512, 1024, 256, 8, 16);
}

// Round 2
// 723.060 us; speedup vs baseline: 1.3717x; 1.3717x over previous
//
#include <hip/hip_runtime.h>
#include <cstddef>

#define DEV static __device__ __forceinline__

DEV float siluf(float v) { return v / (1.f + expf(-v)); }

// ---------------------------------------------------------------------------
// Tiled fp32 GEMM: C[b,o,p] = bias[o] + sum_k W[o,k] * X_b[k,p]
// W: M x K row-major.
// XT=0: X per-batch K x N row-major (n contiguous).
// XT=1: X per-batch N x K row-major (k contiguous).
// EPI=0: Y0[b,o,p] = v
// EPI=1: (M=512) o<256 -> Y0[b,o,p]=v ; o>=256 -> Y1[b,o-256,p]=silu(v)
// 64x64 tile / block of 256 threads, 4x4 micro-tile, K-chunks of 16.
// ---------------------------------------------------------------------------
template <int XT, int EPI>
__global__ __launch_bounds__(256) void gemm_k(
    const float* __restrict__ W, const float* __restrict__ X,
    const float* __restrict__ bias, float* __restrict__ Y0, float* __restrict__ Y1,
    int M, int N, int K, int Mt, int Nt)
{
  __shared__ __align__(16) float Wt[16][68];   // [k][o], pitch 68 avoids bank conflicts
  __shared__ __align__(16) float Xt[16][68];   // [k][p]
  int bid = blockIdx.x;
  int tiles = Mt * Nt;
  int bb = bid / tiles;
  int rr = bid - bb * tiles;
  int m0 = (rr / Nt) * 64;
  int n0 = (rr % Nt) * 64;
  const float* Xb = X + (size_t)bb * K * N;
  int t  = threadIdx.x;
  int tr = t >> 4, tc = t & 15;
  int kw = t & 15, ow = t >> 4;      // W-tile load mapping
  int px0 = t & 63, kx0 = t >> 6;    // X-tile load mapping (XT=0)
  int kx1 = t & 15, px1 = t >> 4;    // X-tile load mapping (XT=1)
  float acc[4][4] = {};

  for (int k0 = 0; k0 < K; k0 += 16) {
    __syncthreads();
#pragma unroll
    for (int i = 0; i < 4; i++)
      Wt[kw][ow + 16 * i] = W[(size_t)(m0 + ow + 16 * i) * K + k0 + kw];
    if (XT == 0) {
#pragma unroll
      for (int i = 0; i < 4; i++)
        Xt[kx0 + 4 * i][px0] = Xb[(size_t)(k0 + kx0 + 4 * i) * N + n0 + px0];
    } else {
#pragma unroll
      for (int i = 0; i < 4; i++)
        Xt[kx1][px1 + 16 * i] = Xb[(size_t)(n0 + px1 + 16 * i) * K + k0 + kx1];
    }
    __syncthreads();
#pragma unroll
    for (int k = 0; k < 16; k++) {
      float4 av = *(const float4*)&Wt[k][tr * 4];
      float4 bv = *(const float4*)&Xt[k][tc * 4];
      acc[0][0] += av.x * bv.x; acc[0][1] += av.x * bv.y; acc[0][2] += av.x * bv.z; acc[0][3] += av.x * bv.w;
      acc[1][0] += av.y * bv.x; acc[1][1] += av.y * bv.y; acc[1][2] += av.y * bv.z; acc[1][3] += av.y * bv.w;
      acc[2][0] += av.z * bv.x; acc[2][1] += av.z * bv.y; acc[2][2] += av.z * bv.z; acc[2][3] += av.z * bv.w;
      acc[3][0] += av.w * bv.x; acc[3][1] += av.w * bv.y; acc[3][2] += av.w * bv.z; acc[3][3] += av.w * bv.w;
    }
  }

#pragma unroll
  for (int i = 0; i < 4; i++) {
    int o = m0 + tr * 4 + i;
    float bv = bias[o];
    float4 v = make_float4(acc[i][0] + bv, acc[i][1] + bv, acc[i][2] + bv, acc[i][3] + bv);
    if (EPI == 0) {
      *(float4*)&Y0[((size_t)bb * M + o) * N + n0 + tc * 4] = v;
    } else {
      if (o < 256) {
        *(float4*)&Y0[((size_t)bb * 256 + o) * N + n0 + tc * 4] = v;
      } else {
        v.x = siluf(v.x); v.y = siluf(v.y); v.z = siluf(v.z); v.w = siluf(v.w);
        *(float4*)&Y1[((size_t)bb * 256 + (o - 256)) * N + n0 + tc * 4] = v;
      }
    }
  }
}

// ---------------------------------------------------------------------------
// Transpose sz (b,c,p) -> szT (b,p,c).  32x32 LDS tiles.
// ---------------------------------------------------------------------------
__global__ __launch_bounds__(256) void transpose_k(const float* __restrict__ in,
                                                   float* __restrict__ outp)
{
  __shared__ float tile[32][33];
  int b  = blockIdx.y;
  int pt = blockIdx.x & 31;   // 1024/32 p-tiles
  int ct = blockIdx.x >> 5;   // 256/32 c-tiles
  int p0 = pt * 32, c0 = ct * 32;
  int r  = threadIdx.x >> 5;  // 0..7
  int cc = threadIdx.x & 31;
#pragma unroll
  for (int i = 0; i < 4; i++) {
    int row = r + 8 * i;
    tile[row][cc] = in[((size_t)b * 256 + c0 + row) * 1024 + p0 + cc];
  }
  __syncthreads();
#pragma unroll
  for (int i = 0; i < 4; i++) {
    int row = r + 8 * i;
    outp[((size_t)b * 1024 + p0 + row) * 256 + c0 + cc] = tile[cc][row];
  }
}

// ---------------------------------------------------------------------------
// im2col for 2x2 stride-2 convs: out (b, k=c*4+i*2+j, n=y*Wo+x)
// ---------------------------------------------------------------------------
__global__ __launch_bounds__(256) void im2col2_k(const float* __restrict__ f1,
                                                 float* __restrict__ out)
{
  int idx = blockIdx.x * 256 + threadIdx.x;           // < 8*1024*256
  int n = idx & 255;
  int k = (idx >> 8) & 1023;
  int b = idx >> 18;
  int c = k >> 2, i = (k >> 1) & 1, j = k & 1;
  int y = n >> 4, x = n & 15;
  out[idx] = f1[((size_t)b * 256 + c) * 1024 + (2 * y + i) * 32 + (2 * x + j)];
}

__global__ __launch_bounds__(256) void im2col3_k(const float* __restrict__ f2,
                                                 float* __restrict__ out)
{
  int idx = blockIdx.x * 256 + threadIdx.x;           // < 8*1024*64
  int n = idx & 63;
  int k = (idx >> 6) & 1023;
  int b = idx >> 16;
  int c = k >> 2, i = (k >> 1) & 1, j = k & 1;
  int y = n >> 3, x = n & 7;
  out[idx] = f2[((size_t)b * 256 + c) * 256 + (2 * y + i) * 16 + (2 * x + j)];
}

// ---------------------------------------------------------------------------
// SSM projection: per tile of 16 positions, compute
//   xd[l,k] = sum_d x[b,d,l]*xw[k,d]   (k<40)
//   delta[b,d,l] = softplus(sum_r xd[l,r]*dtw[d,r] + dtb[d])  -> (b,256,L) layout
//   bc[b,c,l], c<16: B_n ; c>=16: C_n                         -> (b,32,L) layout
// Layouts are l-contiguous so scan_k can stream them coalesced.
// ---------------------------------------------------------------------------
__global__ __launch_bounds__(256) void proj_k(
    const float* __restrict__ xin, int L,
    const float* __restrict__ xw, const float* __restrict__ dtw,
    const float* __restrict__ dtb,
    float* __restrict__ delta_g, float* __restrict__ bc_g)
{
  __shared__ __align__(16) float xw_s[256 * 41];  // [d][k], pitch 41
  __shared__ __align__(16) float xs[256 * 16];    // [d][l]
  __shared__ __align__(16) float xd_s[16 * 40];   // [l][k]
  int t  = threadIdx.x;
  int b  = blockIdx.y;
  int l0 = blockIdx.x * 16;

#pragma unroll 8
  for (int i = 0; i < 40; i++) xw_s[t * 41 + i] = xw[i * 256 + t];
  {
    const float* xr = xin + ((size_t)b * 256 + t) * L + l0;
#pragma unroll
    for (int i = 0; i < 4; i++)
      *(float4*)&xs[t * 16 + 4 * i] = *(const float4*)&xr[4 * i];
  }
  __syncthreads();

#pragma unroll
  for (int ii = 0; ii < 3; ii++) {
    int idx = t + 256 * ii;
    if (idx < 640) {
      int l = idx / 40, k = idx - l * 40;
      float a0 = 0, a1 = 0, a2 = 0, a3 = 0;
      for (int d = 0; d < 256; d += 4) {
        a0 += xs[(d + 0) * 16 + l] * xw_s[(d + 0) * 41 + k];
        a1 += xs[(d + 1) * 16 + l] * xw_s[(d + 1) * 41 + k];
        a2 += xs[(d + 2) * 16 + l] * xw_s[(d + 2) * 41 + k];
        a3 += xs[(d + 3) * 16 + l] * xw_s[(d + 3) * 41 + k];
      }
      xd_s[l * 40 + k] = (a0 + a1) + (a2 + a3);
    }
  }
  __syncthreads();

  int d = t;
  float dtwv[8];
#pragma unroll
  for (int r = 0; r < 8; r++) dtwv[r] = dtw[d * 8 + r];
  float dtbv = dtb[d];
  float spv[16];
#pragma unroll
  for (int l = 0; l < 16; l++) {
    float s = dtbv;
#pragma unroll
    for (int r = 0; r < 8; r++) s += xd_s[l * 40 + r] * dtwv[r];
    spv[l] = fmaxf(s, 0.f) + log1pf(expf(-fabsf(s)));   // stable softplus
  }
  {
    float* dout = delta_g + ((size_t)b * 256 + d) * L + l0;
#pragma unroll
    for (int i = 0; i < 4; i++)
      *(float4*)&dout[4 * i] = make_float4(spv[4 * i], spv[4 * i + 1],
                                           spv[4 * i + 2], spv[4 * i + 3]);
  }
  if (t < 128) {
    int c = t >> 2, seg = t & 3;
    int lb = seg * 4;
    float4 vv = make_float4(xd_s[(lb + 0) * 40 + 8 + c], xd_s[(lb + 1) * 40 + 8 + c],
                            xd_s[(lb + 2) * 40 + 8 + c], xd_s[(lb + 3) * 40 + 8 + c]);
    *(float4*)&bc_g[((size_t)b * 32 + c) * L + l0 + lb] = vv;
  }
}

// ---------------------------------------------------------------------------
// Selective-scan, LDS double-buffered. Thread = (d-local, n). 768 blocks cover
// all (level, b, dir, d-group). Backward direction == same arrays traversed in
// reverse (pointwise projections commute with flip).
// Chunk = 64 steps: 64 LDS rows (16 delta + 16 x + 32 bc) x 64 cols, pitch 68.
// Next chunk is prefetched into registers during compute, committed after.
// ---------------------------------------------------------------------------
__global__ __launch_bounds__(256) void scan_k(
    const float* __restrict__ f1, const float* __restrict__ f2, const float* __restrict__ f3,
    const float* __restrict__ d1f, const float* __restrict__ bc1f,
    const float* __restrict__ d1b, const float* __restrict__ bc1b,
    const float* __restrict__ d2,  const float* __restrict__ bc2,
    const float* __restrict__ d3,  const float* __restrict__ bc3,
    float* __restrict__ y1f, float* __restrict__ y1b,
    float* __restrict__ y2f, float* __restrict__ y2b,
    float* __restrict__ y3f, float* __restrict__ y3b,
    const float* __restrict__ Al1, const float* __restrict__ Dv1,
    const float* __restrict__ Al2, const float* __restrict__ Dv2,
    const float* __restrict__ Al3, const float* __restrict__ Dv3)
{
  __shared__ __align__(16) float lds[2][64][68];
  int bid = blockIdx.x;
  int lvl = bid >> 8;
  int r   = bid & 255;
  int b   = r >> 5;
  int dir = (r >> 4) & 1;
  int g   = r & 15;

  int L; const float *xin, *dlp, *bcp, *Alp, *Dvp; float* yo;
  if (lvl == 0) {
    L = 1024; xin = f1;
    if (dir == 0) { dlp = d1f; bcp = bc1f; Alp = Al1; Dvp = Dv1; yo = y1f; }
    else          { dlp = d1b; bcp = bc1b; Alp = Al2; Dvp = Dv2; yo = y1b; }
  } else if (lvl == 1) {
    L = 256; xin = f2; dlp = d2; bcp = bc2; Alp = Al2; Dvp = Dv2; yo = dir ? y2b : y2f;
  } else {
    L = 64;  xin = f3; dlp = d3; bcp = bc3; Alp = Al3; Dvp = Dv3; yo = dir ? y3b : y3f;
  }

  int t = threadIdx.x;
  int n = t & 15;
  int dloc = t >> 4;
  int d = g * 16 + dloc;
  float A   = -__expf(Alp[d * 16 + n] * 0.69314718056f) ; // exp(x)=2^(x*log2e)... see below
  // NOTE: __expf(x) computes e^x; we want -exp(Al). Use expf for the
  // once-per-thread constant (accuracy) :
  A = -expf(Alp[d * 16 + n]);
  float Dvv = Dvp[d];
  size_t bL = (size_t)b * L;

  // loader mapping: 16 threads per row, 4 row-passes
  int r0 = t >> 4;      // 0..15
  int cs = t & 15;      // float4 segment within 64-col row
  const float* rp[4];
#pragma unroll
  for (int p = 0; p < 4; p++) {
    int row = r0 + 16 * p;
    if (row < 16)      rp[p] = dlp + ((size_t)b * 256 + g * 16 + row) * L;
    else if (row < 32) rp[p] = xin + ((size_t)b * 256 + g * 16 + (row - 16)) * L;
    else               rp[p] = bcp + ((size_t)b * 32 + (row - 32)) * L;
  }

  int nch = L >> 6;
  // preload chunk 0
  {
    int base = dir ? (L - 64) : 0;
    float4 v[4];
#pragma unroll
    for (int p = 0; p < 4; p++) v[p] = *(const float4*)(rp[p] + base + cs * 4);
#pragma unroll
    for (int p = 0; p < 4; p++) *(float4*)&lds[0][r0 + 16 * p][cs * 4] = v[p];
  }
  __syncthreads();

  float h = 0.f;
  for (int c = 0; c < nch; ++c) {
    int buf = c & 1;
    bool more = (c + 1 < nch);
    float4 v[4];
    if (more) {
      int nbase = dir ? (L - 64 * (c + 2)) : 64 * (c + 1);
#pragma unroll
      for (int p = 0; p < 4; p++) v[p] = *(const float4*)(rp[p] + nbase + cs * 4);
    }
    int base = dir ? (L - 64 * (c + 1)) : 64 * c;
    float* yrow = yo + (bL + base) * 256 + d;
#pragma unroll 8
    for (int j = 0; j < 64; j++) {
      int col = dir ? 63 - j : j;
      float dv = lds[buf][dloc][col];
      float xv = lds[buf][16 + dloc][col];
      float Bv = lds[buf][32 + n][col];
      float Cv = lds[buf][48 + n][col];
      h = h * __expf(dv * A) + dv * Bv * xv;
      float pp = h * Cv;
      pp += __shfl_xor(pp, 1);
      pp += __shfl_xor(pp, 2);
      pp += __shfl_xor(pp, 4);
      pp += __shfl_xor(pp, 8);
      if (n == 0) yrow[(size_t)col * 256] = pp + xv * Dvv;
    }
    __syncthreads();
    if (more) {
#pragma unroll
      for (int p = 0; p < 4; p++) *(float4*)&lds[buf ^ 1][r0 + 16 * p][cs * 4] = v[p];
      __syncthreads();
    }
  }
}

// ---------------------------------------------------------------------------
// LayerNorm(fwd) + LayerNorm(bwd) + optional 2x upsample add + optional *szT
// Block = one (b,l); 256 threads = d.
// ---------------------------------------------------------------------------
__global__ __launch_bounds__(256) void ln_combine(
    const float* __restrict__ yf, const float* __restrict__ yb,
    const float* __restrict__ gf, const float* __restrict__ bef,
    const float* __restrict__ gb, const float* __restrict__ beb,
    const float* __restrict__ up, int Wc,
    const float* __restrict__ szT, float* __restrict__ out,
    int L, int Wf)
{
  int bid = blockIdx.x;
  int b = bid / L;
  int l = bid - b * L;
  int d = threadIdx.x;
  size_t base = ((size_t)b * L + l) * 256 + d;
  float vf = yf[base], vb = yb[base];
  float4 s = make_float4(vf, vf * vf, vb, vb * vb);
#pragma unroll
  for (int m = 1; m < 64; m <<= 1) {
    s.x += __shfl_xor(s.x, m);
    s.y += __shfl_xor(s.y, m);
    s.z += __shfl_xor(s.z, m);
    s.w += __shfl_xor(s.w, m);
  }
  __shared__ float red[4][4];
  int w = threadIdx.x >> 6;
  if ((threadIdx.x & 63) == 0) {
    red[w][0] = s.x; red[w][1] = s.y; red[w][2] = s.z; red[w][3] = s.w;
  }
  __syncthreads();
  float s0 = red[0][0] + red[1][0] + red[2][0] + red[3][0];
  float s1 = red[0][1] + red[1][1] + red[2][1] + red[3][1];
  float s2 = red[0][2] + red[1][2] + red[2][2] + red[3][2];
  float s3 = red[0][3] + red[1][3] + red[2][3] + red[3][3];
  const float inv = 1.f / 256.f;
  float muf = s0 * inv, varf = s1 * inv - muf * muf;
  float mub = s2 * inv, varb = s3 * inv - mub * mub;
  float rf = rsqrtf(varf + 1e-5f);
  float rb = rsqrtf(varb + 1e-5f);
  float v = (vf - muf) * rf * gf[d] + bef[d] + (vb - mub) * rb * gb[d] + beb[d];
  if (up) {
    int y = l / Wf, x = l - y * Wf;
    int lc = (y >> 1) * Wc + (x >> 1);
    v += up[((size_t)b * (L >> 2) + lc) * 256 + d];
  }
  if (szT) v *= szT[base];
  out[base] = v;
}

// ---------------------------------------------------------------------------
extern "C" void kernel_launch(void* const* d_in, const int* in_sizes, int n_in,
                              void* d_out, int out_size, void* d_ws, size_t ws_size,
                              hipStream_t stream) {
  (void)in_sizes; (void)n_in; (void)out_size; (void)ws_size;
  const float* input_f = (const float*)d_in[0];
  const float* in_w  = (const float*)d_in[1];
  const float* in_b  = (const float*)d_in[2];
  const float* c1_w  = (const float*)d_in[3];
  const float* c1_b  = (const float*)d_in[4];
  const float* c2_w  = (const float*)d_in[5];
  const float* c2_b  = (const float*)d_in[6];
  const float* c3_w  = (const float*)d_in[7];
  const float* c3_b  = (const float*)d_in[8];
  const float* out_w = (const float*)d_in[9];
  const float* out_b = (const float*)d_in[10];
  const float* xw1  = (const float*)d_in[11];
  const float* dtw1 = (const float*)d_in[12];
  const float* dtb1 = (const float*)d_in[13];
  const float* Al1  = (const float*)d_in[14];
  const float* Dv1  = (const float*)d_in[15];
  const float* g1   = (const float*)d_in[16];
  const float* be1  = (const float*)d_in[17];
  const float* xw2  = (const float*)d_in[18];
  const float* dtw2 = (const float*)d_in[19];
  const float* dtb2 = (const float*)d_in[20];
  const float* Al2  = (const float*)d_in[21];
  const float* Dv2  = (const float*)d_in[22];
  const float* g2   = (const float*)d_in[23];
  const float* be2  = (const float*)d_in[24];
  const float* xw3  = (const float*)d_in[25];
  const float* dtw3 = (const float*)d_in[26];
  const float* dtb3 = (const float*)d_in[27];
  const float* Al3  = (const float*)d_in[28];
  const float* Dv3  = (const float*)d_in[29];
  const float* g3   = (const float*)d_in[30];
  const float* be3  = (const float*)d_in[31];

  float* ws = (float*)d_ws;
  constexpr size_t M1 = 2097152;     // 8*256*1024
  float* x    = ws + 0 * M1;         // (b,256,1024); later reused as d1f
  float* sz   = ws + 1 * M1;         // silu(z) (b,256,1024); reused as ic2, y1f
  float* szT  = ws + 2 * M1;         // (b,1024,256)
  float* f1   = ws + 3 * M1;         // (b,256,1024); reused as G
  float* d1b  = ws + 4 * M1;
  float* y1b  = ws + 5 * M1;
  size_t o = 6 * M1;
  float* f2   = ws + o; o += 524288;   // (b,256,256)
  float* f3   = ws + o; o += 131072;   // (b,256,64)
  float* ic3  = ws + o; o += 524288;   // (b,1024,64)
  float* bc1f = ws + o; o += 262144;
  float* bc1b = ws + o; o += 262144;
  float* d2   = ws + o; o += 524288;
  float* bc2  = ws + o; o += 65536;
  float* d3   = ws + o; o += 131072;
  float* bc3  = ws + o; o += 16384;
  float* y2f  = ws + o; o += 524288;
  float* y2b  = ws + o; o += 524288;
  float* y3f  = ws + o; o += 131072;
  float* y3b  = ws + o; o += 131072;
  float* y3c  = ws + o; o += 131072;
  float* y2c  = ws + o; o += 524288;
  // aliases (lifetimes verified against launch order below)
  float* d1f = x;    // x dead after c1
  float* ic2 = sz;   // sz dead after transpose
  float* y1f = sz;   // ic2 dead after c2 gemm
  float* G   = f1;   // f1 dead after scan

  dim3 blk(256);

  // 1. in-proj: xz = in_w @ input_f + in_b; split into x and silu(z)
  gemm_k<0, 1><<<dim3(1024), blk, 0, stream>>>(in_w, input_f, in_b, x, sz,
                                               512, 1024, 512, 8, 16);
  // 2. transpose silu(z) -> (b,p,c)
  transpose_k<<<dim3(256, 8), blk, 0, stream>>>(sz, szT);
  // 3. c1 1x1 conv
  gemm_k<0, 0><<<dim3(512), blk, 0, stream>>>(c1_w, x, c1_b, f1, nullptr,
                                              256, 1024, 256, 4, 16);
  // 4-5. c2 stride-2 conv (im2col + GEMM)
  im2col2_k<<<dim3(8192), blk, 0, stream>>>(f1, ic2);
  gemm_k<0, 0><<<dim3(128), blk, 0, stream>>>(c2_w, ic2, c2_b, f2, nullptr,
                                              256, 256, 1024, 4, 4);
  // 6-7. c3 stride-2 conv
  im2col3_k<<<dim3(2048), blk, 0, stream>>>(f2, ic3);
  gemm_k<0, 0><<<dim3(32), blk, 0, stream>>>(c3_w, ic3, c3_b, f3, nullptr,
                                             256, 64, 1024, 4, 1);
  // 8-11. SSM projections (level1 fwd uses params1; level1 BWD uses params2
  //        replicating the reference; levels 2/3 share across directions)
  proj_k<<<dim3(4, 8),  blk, 0, stream>>>(f3, 64,   xw3, dtw3, dtb3, d3,  bc3);
  proj_k<<<dim3(16, 8), blk, 0, stream>>>(f2, 256,  xw2, dtw2, dtb2, d2,  bc2);
  proj_k<<<dim3(64, 8), blk, 0, stream>>>(f1, 1024, xw1, dtw1, dtb1, d1f, bc1f);
  proj_k<<<dim3(64, 8), blk, 0, stream>>>(f1, 1024, xw2, dtw2, dtb2, d1b, bc1b);
  // 12. all scans (3 levels x 2 directions x 8 batches x 16 d-groups)
  scan_k<<<dim3(768), blk, 0, stream>>>(f1, f2, f3,
                                        d1f, bc1f, d1b, bc1b, d2, bc2, d3, bc3,
                                        y1f, y1b, y2f, y2b, y3f, y3b,
                                        Al1, Dv1, Al2, Dv2, Al3, Dv3);
  // 13-15. LN + combine (+upsample) (+silu multiply at level 1)
  ln_combine<<<dim3(512), blk, 0, stream>>>(y3f, y3b, g3, be3, g3, be3,
                                            nullptr, 0, nullptr, y3c, 64, 8);
  ln_combine<<<dim3(2048), blk, 0, stream>>>(y2f, y2b, g2, be2, g2, be2,
                                             y3c, 8, nullptr, y2c, 256, 16);
  ln_combine<<<dim3(8192), blk, 0, stream>>>(y1f, y1b, g1, be1, g2, be2,
                                             y2c, 16, szT, G, 1024, 32);
  // 16. out-proj: d_out[b,o,p] = out_b[o] + sum_c out_w[o,c]*G[b,p,c]
  gemm_k<1, 0><<<dim3(1024), blk, 0, stream>>>(out_w, G, out_b, (float*)d_out,
                                               nullptr, 512, 1024, 256, 8, 16);
}

// Round 3
// 602.802 us; speedup vs baseline: 1.6453x; 1.1995x over previous
//
#include <hip/hip_runtime.h>
#include <cstddef>

#define DEV static __device__ __forceinline__

DEV float siluf(float v) { return v / (1.f + expf(-v)); }

// DPP row-rotate add: sums within each 16-lane row after amounts 1,2,4,8.
template <int AMT>
DEV float ror_add(float v) {
  int s = __builtin_amdgcn_update_dpp(0, __float_as_int(v), 0x120 | AMT, 0xF, 0xF, false);
  return v + __int_as_float(s);
}

// ---------------------------------------------------------------------------
// Tiled fp32 GEMM: C[b,o,p] = bias[o] + sum_k W[o,k] * X_b[k,p]
// W: M x K row-major.
// XT=0: X per-batch K x N row-major (n contiguous).
// XT=1: X per-batch N x K row-major (k contiguous).
// EPI=0: Y0[b,o,p] = v
// EPI=1: (M=512) o<256 -> Y0[b,o,p]=v ; o>=256 -> Y1[b,o-256,p]=silu(v)
// 64x64 tile / block of 256 threads, 4x4 micro-tile, K-chunks of 16.
// ---------------------------------------------------------------------------
template <int XT, int EPI>
__global__ __launch_bounds__(256) void gemm_k(
    const float* __restrict__ W, const float* __restrict__ X,
    const float* __restrict__ bias, float* __restrict__ Y0, float* __restrict__ Y1,
    int M, int N, int K, int Mt, int Nt)
{
  __shared__ __align__(16) float Wt[16][68];   // [k][o], pitch 68 avoids bank conflicts
  __shared__ __align__(16) float Xt[16][68];   // [k][p]
  int bid = blockIdx.x;
  int tiles = Mt * Nt;
  int bb = bid / tiles;
  int rr = bid - bb * tiles;
  int m0 = (rr / Nt) * 64;
  int n0 = (rr % Nt) * 64;
  const float* Xb = X + (size_t)bb * K * N;
  int t  = threadIdx.x;
  int tr = t >> 4, tc = t & 15;
  int kw = t & 15, ow = t >> 4;      // W-tile load mapping
  int px0 = t & 63, kx0 = t >> 6;    // X-tile load mapping (XT=0)
  int kx1 = t & 15, px1 = t >> 4;    // X-tile load mapping (XT=1)
  float acc[4][4] = {};

  for (int k0 = 0; k0 < K; k0 += 16) {
    __syncthreads();
#pragma unroll
    for (int i = 0; i < 4; i++)
      Wt[kw][ow + 16 * i] = W[(size_t)(m0 + ow + 16 * i) * K + k0 + kw];
    if (XT == 0) {
#pragma unroll
      for (int i = 0; i < 4; i++)
        Xt[kx0 + 4 * i][px0] = Xb[(size_t)(k0 + kx0 + 4 * i) * N + n0 + px0];
    } else {
#pragma unroll
      for (int i = 0; i < 4; i++)
        Xt[kx1][px1 + 16 * i] = Xb[(size_t)(n0 + px1 + 16 * i) * K + k0 + kx1];
    }
    __syncthreads();
#pragma unroll
    for (int k = 0; k < 16; k++) {
      float4 av = *(const float4*)&Wt[k][tr * 4];
      float4 bv = *(const float4*)&Xt[k][tc * 4];
      acc[0][0] += av.x * bv.x; acc[0][1] += av.x * bv.y; acc[0][2] += av.x * bv.z; acc[0][3] += av.x * bv.w;
      acc[1][0] += av.y * bv.x; acc[1][1] += av.y * bv.y; acc[1][2] += av.y * bv.z; acc[1][3] += av.y * bv.w;
      acc[2][0] += av.z * bv.x; acc[2][1] += av.z * bv.y; acc[2][2] += av.z * bv.z; acc[2][3] += av.z * bv.w;
      acc[3][0] += av.w * bv.x; acc[3][1] += av.w * bv.y; acc[3][2] += av.w * bv.z; acc[3][3] += av.w * bv.w;
    }
  }

#pragma unroll
  for (int i = 0; i < 4; i++) {
    int o = m0 + tr * 4 + i;
    float bv = bias[o];
    float4 v = make_float4(acc[i][0] + bv, acc[i][1] + bv, acc[i][2] + bv, acc[i][3] + bv);
    if (EPI == 0) {
      *(float4*)&Y0[((size_t)bb * M + o) * N + n0 + tc * 4] = v;
    } else {
      if (o < 256) {
        *(float4*)&Y0[((size_t)bb * 256 + o) * N + n0 + tc * 4] = v;
      } else {
        v.x = siluf(v.x); v.y = siluf(v.y); v.z = siluf(v.z); v.w = siluf(v.w);
        *(float4*)&Y1[((size_t)bb * 256 + (o - 256)) * N + n0 + tc * 4] = v;
      }
    }
  }
}

// ---------------------------------------------------------------------------
// Transpose sz (b,c,p) -> szT (b,p,c).  32x32 LDS tiles.
// ---------------------------------------------------------------------------
__global__ __launch_bounds__(256) void transpose_k(const float* __restrict__ in,
                                                   float* __restrict__ outp)
{
  __shared__ float tile[32][33];
  int b  = blockIdx.y;
  int pt = blockIdx.x & 31;   // 1024/32 p-tiles
  int ct = blockIdx.x >> 5;   // 256/32 c-tiles
  int p0 = pt * 32, c0 = ct * 32;
  int r  = threadIdx.x >> 5;  // 0..7
  int cc = threadIdx.x & 31;
#pragma unroll
  for (int i = 0; i < 4; i++) {
    int row = r + 8 * i;
    tile[row][cc] = in[((size_t)b * 256 + c0 + row) * 1024 + p0 + cc];
  }
  __syncthreads();
#pragma unroll
  for (int i = 0; i < 4; i++) {
    int row = r + 8 * i;
    outp[((size_t)b * 1024 + p0 + row) * 256 + c0 + cc] = tile[cc][row];
  }
}

// ---------------------------------------------------------------------------
// im2col for 2x2 stride-2 convs: out (b, k=c*4+i*2+j, n=y*Wo+x)
// ---------------------------------------------------------------------------
__global__ __launch_bounds__(256) void im2col2_k(const float* __restrict__ f1,
                                                 float* __restrict__ out)
{
  int idx = blockIdx.x * 256 + threadIdx.x;           // < 8*1024*256
  int n = idx & 255;
  int k = (idx >> 8) & 1023;
  int b = idx >> 18;
  int c = k >> 2, i = (k >> 1) & 1, j = k & 1;
  int y = n >> 4, x = n & 15;
  out[idx] = f1[((size_t)b * 256 + c) * 1024 + (2 * y + i) * 32 + (2 * x + j)];
}

__global__ __launch_bounds__(256) void im2col3_k(const float* __restrict__ f2,
                                                 float* __restrict__ out)
{
  int idx = blockIdx.x * 256 + threadIdx.x;           // < 8*1024*64
  int n = idx & 63;
  int k = (idx >> 6) & 1023;
  int b = idx >> 16;
  int c = k >> 2, i = (k >> 1) & 1, j = k & 1;
  int y = n >> 3, x = n & 7;
  out[idx] = f2[((size_t)b * 256 + c) * 256 + (2 * y + i) * 16 + (2 * x + j)];
}

// ---------------------------------------------------------------------------
// SSM projection: per tile of 16 positions, compute
//   xd[l,k] = sum_d x[b,d,l]*xw[k,d]   (k<40)
//   delta[b,d,l] = softplus(sum_r xd[l,r]*dtw[d,r] + dtb[d])  -> (b,256,L) layout
//   bc[b,c,l], c<16: B_n ; c>=16: C_n                         -> (b,32,L) layout
// Layouts are l-contiguous so scan_k can stream them coalesced.
// ---------------------------------------------------------------------------
__global__ __launch_bounds__(256) void proj_k(
    const float* __restrict__ xin, int L,
    const float* __restrict__ xw, const float* __restrict__ dtw,
    const float* __restrict__ dtb,
    float* __restrict__ delta_g, float* __restrict__ bc_g)
{
  __shared__ __align__(16) float xw_s[256 * 41];  // [d][k], pitch 41
  __shared__ __align__(16) float xs[256 * 16];    // [d][l]
  __shared__ __align__(16) float xd_s[16 * 40];   // [l][k]
  int t  = threadIdx.x;
  int b  = blockIdx.y;
  int l0 = blockIdx.x * 16;

#pragma unroll 8
  for (int i = 0; i < 40; i++) xw_s[t * 41 + i] = xw[i * 256 + t];
  {
    const float* xr = xin + ((size_t)b * 256 + t) * L + l0;
#pragma unroll
    for (int i = 0; i < 4; i++)
      *(float4*)&xs[t * 16 + 4 * i] = *(const float4*)&xr[4 * i];
  }
  __syncthreads();

#pragma unroll
  for (int ii = 0; ii < 3; ii++) {
    int idx = t + 256 * ii;
    if (idx < 640) {
      int l = idx / 40, k = idx - l * 40;
      float a0 = 0, a1 = 0, a2 = 0, a3 = 0;
      for (int d = 0; d < 256; d += 4) {
        a0 += xs[(d + 0) * 16 + l] * xw_s[(d + 0) * 41 + k];
        a1 += xs[(d + 1) * 16 + l] * xw_s[(d + 1) * 41 + k];
        a2 += xs[(d + 2) * 16 + l] * xw_s[(d + 2) * 41 + k];
        a3 += xs[(d + 3) * 16 + l] * xw_s[(d + 3) * 41 + k];
      }
      xd_s[l * 40 + k] = (a0 + a1) + (a2 + a3);
    }
  }
  __syncthreads();

  int d = t;
  float dtwv[8];
#pragma unroll
  for (int r = 0; r < 8; r++) dtwv[r] = dtw[d * 8 + r];
  float dtbv = dtb[d];
  float spv[16];
#pragma unroll
  for (int l = 0; l < 16; l++) {
    float s = dtbv;
#pragma unroll
    for (int r = 0; r < 8; r++) s += xd_s[l * 40 + r] * dtwv[r];
    spv[l] = fmaxf(s, 0.f) + log1pf(expf(-fabsf(s)));   // stable softplus
  }
  {
    float* dout = delta_g + ((size_t)b * 256 + d) * L + l0;
#pragma unroll
    for (int i = 0; i < 4; i++)
      *(float4*)&dout[4 * i] = make_float4(spv[4 * i], spv[4 * i + 1],
                                           spv[4 * i + 2], spv[4 * i + 3]);
  }
  if (t < 128) {
    int c = t >> 2, seg = t & 3;
    int lb = seg * 4;
    float4 vv = make_float4(xd_s[(lb + 0) * 40 + 8 + c], xd_s[(lb + 1) * 40 + 8 + c],
                            xd_s[(lb + 2) * 40 + 8 + c], xd_s[(lb + 3) * 40 + 8 + c]);
    *(float4*)&bc_g[((size_t)b * 32 + c) * L + l0 + lb] = vv;
  }
}

// ---------------------------------------------------------------------------
// Selective-scan, LDS double-buffered. Thread = (d-local, n). 768 blocks cover
// all (level, b, dir, d-group). Backward direction == same arrays traversed in
// reverse (pointwise projections commute with flip).
// Chunk = 64 steps: 64 LDS rows (16 delta + 16 x + 32 bc) x 64 cols, pitch 68.
// n-reduction via DPP row_ror adds (VALU-only, no ds_swizzle); result kept per
// lane via cndmask and stored unguarded once per 16 steps (no exec-mask churn).
// ---------------------------------------------------------------------------
__global__ __launch_bounds__(256) void scan_k(
    const float* __restrict__ f1, const float* __restrict__ f2, const float* __restrict__ f3,
    const float* __restrict__ d1f, const float* __restrict__ bc1f,
    const float* __restrict__ d1b, const float* __restrict__ bc1b,
    const float* __restrict__ d2,  const float* __restrict__ bc2,
    const float* __restrict__ d3,  const float* __restrict__ bc3,
    float* __restrict__ y1f, float* __restrict__ y1b,
    float* __restrict__ y2f, float* __restrict__ y2b,
    float* __restrict__ y3f, float* __restrict__ y3b,
    const float* __restrict__ Al1, const float* __restrict__ Dv1,
    const float* __restrict__ Al2, const float* __restrict__ Dv2,
    const float* __restrict__ Al3, const float* __restrict__ Dv3)
{
  __shared__ __align__(16) float lds[2][64][68];
  int bid = blockIdx.x;
  int lvl = bid >> 8;
  int r   = bid & 255;
  int b   = r >> 5;
  int dir = (r >> 4) & 1;
  int g   = r & 15;

  int L; const float *xin, *dlp, *bcp, *Alp, *Dvp; float* yo;
  if (lvl == 0) {
    L = 1024; xin = f1;
    if (dir == 0) { dlp = d1f; bcp = bc1f; Alp = Al1; Dvp = Dv1; yo = y1f; }
    else          { dlp = d1b; bcp = bc1b; Alp = Al2; Dvp = Dv2; yo = y1b; }
  } else if (lvl == 1) {
    L = 256; xin = f2; dlp = d2; bcp = bc2; Alp = Al2; Dvp = Dv2; yo = dir ? y2b : y2f;
  } else {
    L = 64;  xin = f3; dlp = d3; bcp = bc3; Alp = Al3; Dvp = Dv3; yo = dir ? y3b : y3f;
  }

  int t = threadIdx.x;
  int n = t & 15;
  int dloc = t >> 4;
  int d = g * 16 + dloc;
  float A   = -expf(Alp[d * 16 + n]);
  float Dvv = Dvp[d];
  size_t bL = (size_t)b * L;

  // loader mapping: 16 threads per row, 4 row-passes
  int r0 = t >> 4;      // 0..15
  int cs = t & 15;      // float4 segment within 64-col row
  const float* rp[4];
#pragma unroll
  for (int p = 0; p < 4; p++) {
    int row = r0 + 16 * p;
    if (row < 16)      rp[p] = dlp + ((size_t)b * 256 + g * 16 + row) * L;
    else if (row < 32) rp[p] = xin + ((size_t)b * 256 + g * 16 + (row - 16)) * L;
    else               rp[p] = bcp + ((size_t)b * 32 + (row - 32)) * L;
  }

  int nch = L >> 6;
  // preload chunk 0
  {
    int base = dir ? (L - 64) : 0;
    float4 v[4];
#pragma unroll
    for (int p = 0; p < 4; p++) v[p] = *(const float4*)(rp[p] + base + cs * 4);
#pragma unroll
    for (int p = 0; p < 4; p++) *(float4*)&lds[0][r0 + 16 * p][cs * 4] = v[p];
  }
  __syncthreads();

  int coff  = dir ? 63 : 0;   // col = coff + csign*j
  int csign = dir ? -1 : 1;

  float h = 0.f;
  for (int c = 0; c < nch; ++c) {
    int buf = c & 1;
    bool more = (c + 1 < nch);
    float4 v[4];
    if (more) {
      int nbase = dir ? (L - 64 * (c + 2)) : 64 * (c + 1);
#pragma unroll
      for (int p = 0; p < 4; p++) v[p] = *(const float4*)(rp[p] + nbase + cs * 4);
    }
    int base = dir ? (L - 64 * (c + 1)) : 64 * c;
    float* ybase = yo + (bL + base) * 256 + d;
#pragma unroll
    for (int jj0 = 0; jj0 < 64; jj0 += 16) {
      float ysel = 0.f;
#pragma unroll
      for (int q = 0; q < 16; q++) {
        int j = jj0 + q;
        int col = coff + csign * j;
        float dv = lds[buf][dloc][col];
        float xv = lds[buf][16 + dloc][col];
        float Bv = lds[buf][32 + n][col];
        float Cv = lds[buf][48 + n][col];
        h = h * __expf(dv * A) + dv * Bv * xv;
        float pp = h * Cv;
        pp = ror_add<1>(pp);
        pp = ror_add<2>(pp);
        pp = ror_add<4>(pp);
        pp = ror_add<8>(pp);
        float yv = pp + xv * Dvv;
        ysel = ((col & 15) == n) ? yv : ysel;
      }
      int colbase = dir ? 48 - jj0 : jj0;   // 16-aligned block of cols covered
      ybase[(size_t)(colbase + n) * 256] = ysel;
    }
    __syncthreads();
    if (more) {
#pragma unroll
      for (int p = 0; p < 4; p++) *(float4*)&lds[buf ^ 1][r0 + 16 * p][cs * 4] = v[p];
      __syncthreads();
    }
  }
}

// ---------------------------------------------------------------------------
// LayerNorm(fwd) + LayerNorm(bwd) + optional 2x upsample add + optional *szT
// Block = one (b,l); 256 threads = d.
// ---------------------------------------------------------------------------
__global__ __launch_bounds__(256) void ln_combine(
    const float* __restrict__ yf, const float* __restrict__ yb,
    const float* __restrict__ gf, const float* __restrict__ bef,
    const float* __restrict__ gb, const float* __restrict__ beb,
    const float* __restrict__ up, int Wc,
    const float* __restrict__ szT, float* __restrict__ out,
    int L, int Wf)
{
  int bid = blockIdx.x;
  int b = bid / L;
  int l = bid - b * L;
  int d = threadIdx.x;
  size_t base = ((size_t)b * L + l) * 256 + d;
  float vf = yf[base], vb = yb[base];
  float4 s = make_float4(vf, vf * vf, vb, vb * vb);
#pragma unroll
  for (int m = 1; m < 64; m <<= 1) {
    s.x += __shfl_xor(s.x, m);
    s.y += __shfl_xor(s.y, m);
    s.z += __shfl_xor(s.z, m);
    s.w += __shfl_xor(s.w, m);
  }
  __shared__ float red[4][4];
  int w = threadIdx.x >> 6;
  if ((threadIdx.x & 63) == 0) {
    red[w][0] = s.x; red[w][1] = s.y; red[w][2] = s.z; red[w][3] = s.w;
  }
  __syncthreads();
  float s0 = red[0][0] + red[1][0] + red[2][0] + red[3][0];
  float s1 = red[0][1] + red[1][1] + red[2][1] + red[3][1];
  float s2 = red[0][2] + red[1][2] + red[2][2] + red[3][2];
  float s3 = red[0][3] + red[1][3] + red[2][3] + red[3][3];
  const float inv = 1.f / 256.f;
  float muf = s0 * inv, varf = s1 * inv - muf * muf;
  float mub = s2 * inv, varb = s3 * inv - mub * mub;
  float rf = rsqrtf(varf + 1e-5f);
  float rb = rsqrtf(varb + 1e-5f);
  float v = (vf - muf) * rf * gf[d] + bef[d] + (vb - mub) * rb * gb[d] + beb[d];
  if (up) {
    int y = l / Wf, x = l - y * Wf;
    int lc = (y >> 1) * Wc + (x >> 1);
    v += up[((size_t)b * (L >> 2) + lc) * 256 + d];
  }
  if (szT) v *= szT[base];
  out[base] = v;
}

// ---------------------------------------------------------------------------
extern "C" void kernel_launch(void* const* d_in, const int* in_sizes, int n_in,
                              void* d_out, int out_size, void* d_ws, size_t ws_size,
                              hipStream_t stream) {
  (void)in_sizes; (void)n_in; (void)out_size; (void)ws_size;
  const float* input_f = (const float*)d_in[0];
  const float* in_w  = (const float*)d_in[1];
  const float* in_b  = (const float*)d_in[2];
  const float* c1_w  = (const float*)d_in[3];
  const float* c1_b  = (const float*)d_in[4];
  const float* c2_w  = (const float*)d_in[5];
  const float* c2_b  = (const float*)d_in[6];
  const float* c3_w  = (const float*)d_in[7];
  const float* c3_b  = (const float*)d_in[8];
  const float* out_w = (const float*)d_in[9];
  const float* out_b = (const float*)d_in[10];
  const float* xw1  = (const float*)d_in[11];
  const float* dtw1 = (const float*)d_in[12];
  const float* dtb1 = (const float*)d_in[13];
  const float* Al1  = (const float*)d_in[14];
  const float* Dv1  = (const float*)d_in[15];
  const float* g1   = (const float*)d_in[16];
  const float* be1  = (const float*)d_in[17];
  const float* xw2  = (const float*)d_in[18];
  const float* dtw2 = (const float*)d_in[19];
  const float* dtb2 = (const float*)d_in[20];
  const float* Al2  = (const float*)d_in[21];
  const float* Dv2  = (const float*)d_in[22];
  const float* g2   = (const float*)d_in[23];
  const float* be2  = (const float*)d_in[24];
  const float* xw3  = (const float*)d_in[25];
  const float* dtw3 = (const float*)d_in[26];
  const float* dtb3 = (const float*)d_in[27];
  const float* Al3  = (const float*)d_in[28];
  const float* Dv3  = (const float*)d_in[29];
  const float* g3   = (const float*)d_in[30];
  const float* be3  = (const float*)d_in[31];

  float* ws = (float*)d_ws;
  constexpr size_t M1 = 2097152;     // 8*256*1024
  float* x    = ws + 0 * M1;         // (b,256,1024); later reused as d1f
  float* sz   = ws + 1 * M1;         // silu(z) (b,256,1024); reused as ic2, y1f
  float* szT  = ws + 2 * M1;         // (b,1024,256)
  float* f1   = ws + 3 * M1;         // (b,256,1024); reused as G
  float* d1b  = ws + 4 * M1;
  float* y1b  = ws + 5 * M1;
  size_t o = 6 * M1;
  float* f2   = ws + o; o += 524288;   // (b,256,256)
  float* f3   = ws + o; o += 131072;   // (b,256,64)
  float* ic3  = ws + o; o += 524288;   // (b,1024,64)
  float* bc1f = ws + o; o += 262144;
  float* bc1b = ws + o; o += 262144;
  float* d2   = ws + o; o += 524288;
  float* bc2  = ws + o; o += 65536;
  float* d3   = ws + o; o += 131072;
  float* bc3  = ws + o; o += 16384;
  float* y2f  = ws + o; o += 524288;
  float* y2b  = ws + o; o += 524288;
  float* y3f  = ws + o; o += 131072;
  float* y3b  = ws + o; o += 131072;
  float* y3c  = ws + o; o += 131072;
  float* y2c  = ws + o; o += 524288;
  // aliases (lifetimes verified against launch order below)
  float* d1f = x;    // x dead after c1
  float* ic2 = sz;   // sz dead after transpose
  float* y1f = sz;   // ic2 dead after c2 gemm
  float* G   = f1;   // f1 dead after scan

  dim3 blk(256);

  // 1. in-proj: xz = in_w @ input_f + in_b; split into x and silu(z)
  gemm_k<0, 1><<<dim3(1024), blk, 0, stream>>>(in_w, input_f, in_b, x, sz,
                                               512, 1024, 512, 8, 16);
  // 2. transpose silu(z) -> (b,p,c)
  transpose_k<<<dim3(256, 8), blk, 0, stream>>>(sz, szT);
  // 3. c1 1x1 conv
  gemm_k<0, 0><<<dim3(512), blk, 0, stream>>>(c1_w, x, c1_b, f1, nullptr,
                                              256, 1024, 256, 4, 16);
  // 4-5. c2 stride-2 conv (im2col + GEMM)
  im2col2_k<<<dim3(8192), blk, 0, stream>>>(f1, ic2);
  gemm_k<0, 0><<<dim3(128), blk, 0, stream>>>(c2_w, ic2, c2_b, f2, nullptr,
                                              256, 256, 1024, 4, 4);
  // 6-7. c3 stride-2 conv
  im2col3_k<<<dim3(2048), blk, 0, stream>>>(f2, ic3);
  gemm_k<0, 0><<<dim3(32), blk, 0, stream>>>(c3_w, ic3, c3_b, f3, nullptr,
                                             256, 64, 1024, 4, 1);
  // 8-11. SSM projections (level1 fwd uses params1; level1 BWD uses params2
  //        replicating the reference; levels 2/3 share across directions)
  proj_k<<<dim3(4, 8),  blk, 0, stream>>>(f3, 64,   xw3, dtw3, dtb3, d3,  bc3);
  proj_k<<<dim3(16, 8), blk, 0, stream>>>(f2, 256,  xw2, dtw2, dtb2, d2,  bc2);
  proj_k<<<dim3(64, 8), blk, 0, stream>>>(f1, 1024, xw1, dtw1, dtb1, d1f, bc1f);
  proj_k<<<dim3(64, 8), blk, 0, stream>>>(f1, 1024, xw2, dtw2, dtb2, d1b, bc1b);
  // 12. all scans (3 levels x 2 directions x 8 batches x 16 d-groups)
  scan_k<<<dim3(768), blk, 0, stream>>>(f1, f2, f3,
                                        d1f, bc1f, d1b, bc1b, d2, bc2, d3, bc3,
                                        y1f, y1b, y2f, y2b, y3f, y3b,
                                        Al1, Dv1, Al2, Dv2, Al3, Dv3);
  // 13-15. LN + combine (+upsample) (+silu multiply at level 1)
  ln_combine<<<dim3(512), blk, 0, stream>>>(y3f, y3b, g3, be3, g3, be3,
                                            nullptr, 0, nullptr, y3c, 64, 8);
  ln_combine<<<dim3(2048), blk, 0, stream>>>(y2f, y2b, g2, be2, g2, be2,
                                             y3c, 8, nullptr, y2c, 256, 16);
  ln_combine<<<dim3(8192), blk, 0, stream>>>(y1f, y1b, g1, be1, g2, be2,
                                             y2c, 16, szT, G, 1024, 32);
  // 16. out-proj: d_out[b,o,p] = out_b[o] + sum_c out_w[o,c]*G[b,p,c]
  gemm_k<1, 0><<<dim3(1024), blk, 0, stream>>>(out_w, G, out_b, (float*)d_out,
                                               nullptr, 512, 1024, 256, 8, 16);
}

// Round 4
// 575.121 us; speedup vs baseline: 1.7245x; 1.0481x over previous
//
#include <hip/hip_runtime.h>
#include <cstddef>

#define DEV static __device__ __forceinline__

DEV float siluf(float v) { return v / (1.f + expf(-v)); }

// DPP row-rotate add: sums within each 16-lane row after amounts 1,2,4,8.
template <int AMT>
DEV float ror_add(float v) {
  int s = __builtin_amdgcn_update_dpp(0, __float_as_int(v), 0x120 | AMT, 0xF, 0xF, false);
  return v + __int_as_float(s);
}

// ---------------------------------------------------------------------------
// Tiled fp32 GEMM: C[b,o,p] = bias[o] + sum_k W[o,k] * X_b[k,p]
// W: M x K row-major.
// XT=0: X per-batch K x N row-major. XT=1: X per-batch N x K row-major.
// EPI=0: plain store. EPI=1: (M=512) split + silu on top half.
// ---------------------------------------------------------------------------
template <int XT, int EPI>
__global__ __launch_bounds__(256) void gemm_k(
    const float* __restrict__ W, const float* __restrict__ X,
    const float* __restrict__ bias, float* __restrict__ Y0, float* __restrict__ Y1,
    int M, int N, int K, int Mt, int Nt)
{
  __shared__ __align__(16) float Wt[16][68];
  __shared__ __align__(16) float Xt[16][68];
  int bid = blockIdx.x;
  int tiles = Mt * Nt;
  int bb = bid / tiles;
  int rr = bid - bb * tiles;
  int m0 = (rr / Nt) * 64;
  int n0 = (rr % Nt) * 64;
  const float* Xb = X + (size_t)bb * K * N;
  int t  = threadIdx.x;
  int tr = t >> 4, tc = t & 15;
  int kw = t & 15, ow = t >> 4;
  int px0 = t & 63, kx0 = t >> 6;
  int kx1 = t & 15, px1 = t >> 4;
  float acc[4][4] = {};

  for (int k0 = 0; k0 < K; k0 += 16) {
    __syncthreads();
#pragma unroll
    for (int i = 0; i < 4; i++)
      Wt[kw][ow + 16 * i] = W[(size_t)(m0 + ow + 16 * i) * K + k0 + kw];
    if (XT == 0) {
#pragma unroll
      for (int i = 0; i < 4; i++)
        Xt[kx0 + 4 * i][px0] = Xb[(size_t)(k0 + kx0 + 4 * i) * N + n0 + px0];
    } else {
#pragma unroll
      for (int i = 0; i < 4; i++)
        Xt[kx1][px1 + 16 * i] = Xb[(size_t)(n0 + px1 + 16 * i) * K + k0 + kx1];
    }
    __syncthreads();
#pragma unroll
    for (int k = 0; k < 16; k++) {
      float4 av = *(const float4*)&Wt[k][tr * 4];
      float4 bv = *(const float4*)&Xt[k][tc * 4];
      acc[0][0] += av.x * bv.x; acc[0][1] += av.x * bv.y; acc[0][2] += av.x * bv.z; acc[0][3] += av.x * bv.w;
      acc[1][0] += av.y * bv.x; acc[1][1] += av.y * bv.y; acc[1][2] += av.y * bv.z; acc[1][3] += av.y * bv.w;
      acc[2][0] += av.z * bv.x; acc[2][1] += av.z * bv.y; acc[2][2] += av.z * bv.z; acc[2][3] += av.z * bv.w;
      acc[3][0] += av.w * bv.x; acc[3][1] += av.w * bv.y; acc[3][2] += av.w * bv.z; acc[3][3] += av.w * bv.w;
    }
  }

#pragma unroll
  for (int i = 0; i < 4; i++) {
    int o = m0 + tr * 4 + i;
    float bv = bias[o];
    float4 v = make_float4(acc[i][0] + bv, acc[i][1] + bv, acc[i][2] + bv, acc[i][3] + bv);
    if (EPI == 0) {
      *(float4*)&Y0[((size_t)bb * M + o) * N + n0 + tc * 4] = v;
    } else {
      if (o < 256) {
        *(float4*)&Y0[((size_t)bb * 256 + o) * N + n0 + tc * 4] = v;
      } else {
        v.x = siluf(v.x); v.y = siluf(v.y); v.z = siluf(v.z); v.w = siluf(v.w);
        *(float4*)&Y1[((size_t)bb * 256 + (o - 256)) * N + n0 + tc * 4] = v;
      }
    }
  }
}

// ---------------------------------------------------------------------------
__global__ __launch_bounds__(256) void transpose_k(const float* __restrict__ in,
                                                   float* __restrict__ outp)
{
  __shared__ float tile[32][33];
  int b  = blockIdx.y;
  int pt = blockIdx.x & 31;
  int ct = blockIdx.x >> 5;
  int p0 = pt * 32, c0 = ct * 32;
  int r  = threadIdx.x >> 5;
  int cc = threadIdx.x & 31;
#pragma unroll
  for (int i = 0; i < 4; i++) {
    int row = r + 8 * i;
    tile[row][cc] = in[((size_t)b * 256 + c0 + row) * 1024 + p0 + cc];
  }
  __syncthreads();
#pragma unroll
  for (int i = 0; i < 4; i++) {
    int row = r + 8 * i;
    outp[((size_t)b * 1024 + p0 + row) * 256 + c0 + cc] = tile[cc][row];
  }
}

// ---------------------------------------------------------------------------
__global__ __launch_bounds__(256) void im2col2_k(const float* __restrict__ f1,
                                                 float* __restrict__ out)
{
  int idx = blockIdx.x * 256 + threadIdx.x;
  int n = idx & 255;
  int k = (idx >> 8) & 1023;
  int b = idx >> 18;
  int c = k >> 2, i = (k >> 1) & 1, j = k & 1;
  int y = n >> 4, x = n & 15;
  out[idx] = f1[((size_t)b * 256 + c) * 1024 + (2 * y + i) * 32 + (2 * x + j)];
}

__global__ __launch_bounds__(256) void im2col3_k(const float* __restrict__ f2,
                                                 float* __restrict__ out)
{
  int idx = blockIdx.x * 256 + threadIdx.x;
  int n = idx & 63;
  int k = (idx >> 6) & 1023;
  int b = idx >> 16;
  int c = k >> 2, i = (k >> 1) & 1, j = k & 1;
  int y = n >> 3, x = n & 7;
  out[idx] = f2[((size_t)b * 256 + c) * 256 + (2 * y + i) * 16 + (2 * x + j)];
}

// ---------------------------------------------------------------------------
// SSM projection: delta -> (b,256,L) l-contiguous; bc -> (b,32,L) l-contiguous.
// ---------------------------------------------------------------------------
__global__ __launch_bounds__(256) void proj_k(
    const float* __restrict__ xin, int L,
    const float* __restrict__ xw, const float* __restrict__ dtw,
    const float* __restrict__ dtb,
    float* __restrict__ delta_g, float* __restrict__ bc_g)
{
  __shared__ __align__(16) float xw_s[256 * 41];
  __shared__ __align__(16) float xs[256 * 16];
  __shared__ __align__(16) float xd_s[16 * 40];
  int t  = threadIdx.x;
  int b  = blockIdx.y;
  int l0 = blockIdx.x * 16;

#pragma unroll 8
  for (int i = 0; i < 40; i++) xw_s[t * 41 + i] = xw[i * 256 + t];
  {
    const float* xr = xin + ((size_t)b * 256 + t) * L + l0;
#pragma unroll
    for (int i = 0; i < 4; i++)
      *(float4*)&xs[t * 16 + 4 * i] = *(const float4*)&xr[4 * i];
  }
  __syncthreads();

#pragma unroll
  for (int ii = 0; ii < 3; ii++) {
    int idx = t + 256 * ii;
    if (idx < 640) {
      int l = idx / 40, k = idx - l * 40;
      float a0 = 0, a1 = 0, a2 = 0, a3 = 0;
      for (int d = 0; d < 256; d += 4) {
        a0 += xs[(d + 0) * 16 + l] * xw_s[(d + 0) * 41 + k];
        a1 += xs[(d + 1) * 16 + l] * xw_s[(d + 1) * 41 + k];
        a2 += xs[(d + 2) * 16 + l] * xw_s[(d + 2) * 41 + k];
        a3 += xs[(d + 3) * 16 + l] * xw_s[(d + 3) * 41 + k];
      }
      xd_s[l * 40 + k] = (a0 + a1) + (a2 + a3);
    }
  }
  __syncthreads();

  int d = t;
  float dtwv[8];
#pragma unroll
  for (int r = 0; r < 8; r++) dtwv[r] = dtw[d * 8 + r];
  float dtbv = dtb[d];
  float spv[16];
#pragma unroll
  for (int l = 0; l < 16; l++) {
    float s = dtbv;
#pragma unroll
    for (int r = 0; r < 8; r++) s += xd_s[l * 40 + r] * dtwv[r];
    spv[l] = fmaxf(s, 0.f) + log1pf(expf(-fabsf(s)));
  }
  {
    float* dout = delta_g + ((size_t)b * 256 + d) * L + l0;
#pragma unroll
    for (int i = 0; i < 4; i++)
      *(float4*)&dout[4 * i] = make_float4(spv[4 * i], spv[4 * i + 1],
                                           spv[4 * i + 2], spv[4 * i + 3]);
  }
  if (t < 128) {
    int c = t >> 2, seg = t & 3;
    int lb = seg * 4;
    float4 vv = make_float4(xd_s[(lb + 0) * 40 + 8 + c], xd_s[(lb + 1) * 40 + 8 + c],
                            xd_s[(lb + 2) * 40 + 8 + c], xd_s[(lb + 3) * 40 + 8 + c]);
    *(float4*)&bc_g[((size_t)b * 32 + c) * L + l0 + lb] = vv;
  }
}

// ---------------------------------------------------------------------------
// Segment-parallel selective scan, 3 passes.
// Streams: sid = b*32 + dir*16 + g (g = 16-d group). Segments of 64 steps in
// TRAVERSAL order (dir=1 walks memory backward). Carry slot == blockIdx.x:
//   lvl0: bid 0..4095   (sid*16 + tseg), L=1024, 16 segs
//   lvl1: bid 4096..5119 (4096 + sid*4 + tseg), L=256, 4 segs
//   lvl2 (pass C only): bid 5120..5375, L=64, 1 seg, h_in=0
// Pass A: per-segment carry (P = prod e, Q = h starting from 0).
// Pass B: in-place prefix over segments: cP[slot] <- h_in.
// Pass C: re-scan from h_in, DPP n-reduction, emit y.
// ---------------------------------------------------------------------------
#define SCAN_STEP(DVV, XVV, BVV) {                 \
    float e_ = __expf((DVV) * A);                  \
    h = h * e_ + (DVV) * (BVV) * (XVV);            \
    P *= e_; }

__global__ __launch_bounds__(256) void scanA_k(
    const float* __restrict__ f1, const float* __restrict__ f2,
    const float* __restrict__ d1f, const float* __restrict__ bc1f,
    const float* __restrict__ d1b, const float* __restrict__ bc1b,
    const float* __restrict__ d2,  const float* __restrict__ bc2,
    const float* __restrict__ Al1, const float* __restrict__ Al2,
    float* __restrict__ cP, float* __restrict__ cQ)
{
  __shared__ __align__(16) float lds[48][68];
  int bid = blockIdx.x;
  int sid, tseg, L; const float *xin, *dlp, *bcp, *Alp;
  if (bid < 4096) {
    sid = bid >> 4; tseg = bid & 15; L = 1024; xin = f1;
    if (((sid >> 4) & 1) == 0) { dlp = d1f; bcp = bc1f; Alp = Al1; }
    else                       { dlp = d1b; bcp = bc1b; Alp = Al2; }
  } else {
    int idx = bid - 4096; sid = idx >> 2; tseg = idx & 3; L = 256;
    xin = f2; dlp = d2; bcp = bc2; Alp = Al2;
  }
  int b = sid >> 5, dir = (sid >> 4) & 1, g = sid & 15;
  int t = threadIdx.x, n = t & 15, dloc = t >> 4, d = g * 16 + dloc;
  int mbase = dir ? (L - 64 * (tseg + 1)) : 64 * tseg;

  int r0 = t >> 4, cs = t & 15;
  {
    const float* p0 = dlp + ((size_t)b * 256 + g * 16 + r0) * L + mbase;
    const float* p1 = xin + ((size_t)b * 256 + g * 16 + r0) * L + mbase;
    const float* p2 = bcp + ((size_t)b * 32 + r0) * L + mbase;   // B rows
    float4 v0 = *(const float4*)(p0 + cs * 4);
    float4 v1 = *(const float4*)(p1 + cs * 4);
    float4 v2 = *(const float4*)(p2 + cs * 4);
    *(float4*)&lds[r0][cs * 4]      = v0;
    *(float4*)&lds[16 + r0][cs * 4] = v1;
    *(float4*)&lds[32 + r0][cs * 4] = v2;
  }
  __syncthreads();

  float A = -expf(Alp[d * 16 + n]);
  float h = 0.f, P = 1.f;
  if (dir == 0) {
#pragma unroll
    for (int g4 = 0; g4 < 16; g4++) {
      int cb = 4 * g4;
      float4 dv4 = *(const float4*)&lds[dloc][cb];
      float4 xv4 = *(const float4*)&lds[16 + dloc][cb];
      float4 bv4 = *(const float4*)&lds[32 + n][cb];
      SCAN_STEP(dv4.x, xv4.x, bv4.x);
      SCAN_STEP(dv4.y, xv4.y, bv4.y);
      SCAN_STEP(dv4.z, xv4.z, bv4.z);
      SCAN_STEP(dv4.w, xv4.w, bv4.w);
    }
  } else {
#pragma unroll
    for (int g4 = 0; g4 < 16; g4++) {
      int cb = 60 - 4 * g4;
      float4 dv4 = *(const float4*)&lds[dloc][cb];
      float4 xv4 = *(const float4*)&lds[16 + dloc][cb];
      float4 bv4 = *(const float4*)&lds[32 + n][cb];
      SCAN_STEP(dv4.w, xv4.w, bv4.w);
      SCAN_STEP(dv4.z, xv4.z, bv4.z);
      SCAN_STEP(dv4.y, xv4.y, bv4.y);
      SCAN_STEP(dv4.x, xv4.x, bv4.x);
    }
  }
  cP[(size_t)bid * 256 + t] = P;
  cQ[(size_t)bid * 256 + t] = h;
}

__global__ __launch_bounds__(256) void scanB_k(float* __restrict__ cP,
                                               const float* __restrict__ cQ)
{
  int bidx = blockIdx.x, t = threadIdx.x;
  int S, base;
  if (bidx < 256) { S = 16; base = bidx * 16; }
  else            { S = 4;  base = 4096 + (bidx - 256) * 4; }
  float h = 0.f;
  for (int s = 0; s < S; s++) {
    size_t off = (size_t)(base + s) * 256 + t;
    float p = cP[off], q = cQ[off];
    cP[off] = h;          // overwrite with h_in for this segment
    h = p * h + q;
  }
}

#define SCAN_STEPY(DVV, XVV, BVV, CVV, COL) {      \
    float e_ = __expf((DVV) * A);                  \
    h = h * e_ + (DVV) * (BVV) * (XVV);            \
    float pp_ = h * (CVV);                         \
    pp_ = ror_add<1>(pp_);                         \
    pp_ = ror_add<2>(pp_);                         \
    pp_ = ror_add<4>(pp_);                         \
    pp_ = ror_add<8>(pp_);                         \
    float yv_ = pp_ + (XVV) * Dvv;                 \
    ysel = (((COL) & 15) == n) ? yv_ : ysel; }

__global__ __launch_bounds__(256) void scanC_k(
    const float* __restrict__ f1, const float* __restrict__ f2, const float* __restrict__ f3,
    const float* __restrict__ d1f, const float* __restrict__ bc1f,
    const float* __restrict__ d1b, const float* __restrict__ bc1b,
    const float* __restrict__ d2,  const float* __restrict__ bc2,
    const float* __restrict__ d3,  const float* __restrict__ bc3,
    float* __restrict__ y1f, float* __restrict__ y1b,
    float* __restrict__ y2f, float* __restrict__ y2b,
    float* __restrict__ y3f, float* __restrict__ y3b,
    const float* __restrict__ Al1, const float* __restrict__ Dv1,
    const float* __restrict__ Al2, const float* __restrict__ Dv2,
    const float* __restrict__ Al3, const float* __restrict__ Dv3,
    const float* __restrict__ cP)
{
  __shared__ __align__(16) float lds[64][68];
  int bid = blockIdx.x;
  int sid, tseg, L, slot; const float *xin, *dlp, *bcp, *Alp, *Dvp; float* yo;
  if (bid < 4096) {
    sid = bid >> 4; tseg = bid & 15; slot = bid; L = 1024; xin = f1;
    if (((sid >> 4) & 1) == 0) { dlp = d1f; bcp = bc1f; Alp = Al1; Dvp = Dv1; yo = y1f; }
    else                       { dlp = d1b; bcp = bc1b; Alp = Al2; Dvp = Dv2; yo = y1b; }
  } else if (bid < 5120) {
    int idx = bid - 4096; sid = idx >> 2; tseg = idx & 3; slot = bid; L = 256;
    xin = f2; dlp = d2; bcp = bc2; Alp = Al2; Dvp = Dv2;
    yo = ((sid >> 4) & 1) ? y2b : y2f;
  } else {
    sid = bid - 5120; tseg = 0; slot = -1; L = 64;
    xin = f3; dlp = d3; bcp = bc3; Alp = Al3; Dvp = Dv3;
    yo = ((sid >> 4) & 1) ? y3b : y3f;
  }
  int b = sid >> 5, dir = (sid >> 4) & 1, g = sid & 15;
  int t = threadIdx.x, n = t & 15, dloc = t >> 4, d = g * 16 + dloc;
  int mbase = dir ? (L - 64 * (tseg + 1)) : 64 * tseg;

  int r0 = t >> 4, cs = t & 15;
  {
    const float* p0 = dlp + ((size_t)b * 256 + g * 16 + r0) * L + mbase;
    const float* p1 = xin + ((size_t)b * 256 + g * 16 + r0) * L + mbase;
    const float* p2 = bcp + ((size_t)b * 32 + r0) * L + mbase;        // B
    const float* p3 = bcp + ((size_t)b * 32 + 16 + r0) * L + mbase;   // C
    float4 v0 = *(const float4*)(p0 + cs * 4);
    float4 v1 = *(const float4*)(p1 + cs * 4);
    float4 v2 = *(const float4*)(p2 + cs * 4);
    float4 v3 = *(const float4*)(p3 + cs * 4);
    *(float4*)&lds[r0][cs * 4]      = v0;
    *(float4*)&lds[16 + r0][cs * 4] = v1;
    *(float4*)&lds[32 + r0][cs * 4] = v2;
    *(float4*)&lds[48 + r0][cs * 4] = v3;
  }
  float A   = -expf(Alp[d * 16 + n]);
  float Dvv = Dvp[d];
  float h = (slot >= 0) ? cP[(size_t)slot * 256 + t] : 0.f;
  __syncthreads();

  float* ybase = yo + ((size_t)b * L + mbase) * 256 + d;
#pragma unroll
  for (int jj0 = 0; jj0 < 64; jj0 += 16) {
    float ysel = 0.f;
    if (dir == 0) {
#pragma unroll
      for (int g4 = 0; g4 < 4; g4++) {
        int cb = jj0 + 4 * g4;
        float4 dv4 = *(const float4*)&lds[dloc][cb];
        float4 xv4 = *(const float4*)&lds[16 + dloc][cb];
        float4 bv4 = *(const float4*)&lds[32 + n][cb];
        float4 cv4 = *(const float4*)&lds[48 + n][cb];
        SCAN_STEPY(dv4.x, xv4.x, bv4.x, cv4.x, cb + 0);
        SCAN_STEPY(dv4.y, xv4.y, bv4.y, cv4.y, cb + 1);
        SCAN_STEPY(dv4.z, xv4.z, bv4.z, cv4.z, cb + 2);
        SCAN_STEPY(dv4.w, xv4.w, bv4.w, cv4.w, cb + 3);
      }
    } else {
#pragma unroll
      for (int g4 = 0; g4 < 4; g4++) {
        int cb = 60 - jj0 - 4 * g4;
        float4 dv4 = *(const float4*)&lds[dloc][cb];
        float4 xv4 = *(const float4*)&lds[16 + dloc][cb];
        float4 bv4 = *(const float4*)&lds[32 + n][cb];
        float4 cv4 = *(const float4*)&lds[48 + n][cb];
        SCAN_STEPY(dv4.w, xv4.w, bv4.w, cv4.w, cb + 3);
        SCAN_STEPY(dv4.z, xv4.z, bv4.z, cv4.z, cb + 2);
        SCAN_STEPY(dv4.y, xv4.y, bv4.y, cv4.y, cb + 1);
        SCAN_STEPY(dv4.x, xv4.x, bv4.x, cv4.x, cb + 0);
      }
    }
    int colbase = dir ? 48 - jj0 : jj0;
    ybase[(size_t)(colbase + n) * 256] = ysel;
  }
}

// ---------------------------------------------------------------------------
// LayerNorm(fwd) + LayerNorm(bwd) + optional 2x upsample add + optional *szT
// ---------------------------------------------------------------------------
__global__ __launch_bounds__(256) void ln_combine(
    const float* __restrict__ yf, const float* __restrict__ yb,
    const float* __restrict__ gf, const float* __restrict__ bef,
    const float* __restrict__ gb, const float* __restrict__ beb,
    const float* __restrict__ up, int Wc,
    const float* __restrict__ szT, float* __restrict__ out,
    int L, int Wf)
{
  int bid = blockIdx.x;
  int b = bid / L;
  int l = bid - b * L;
  int d = threadIdx.x;
  size_t base = ((size_t)b * L + l) * 256 + d;
  float vf = yf[base], vb = yb[base];
  float4 s = make_float4(vf, vf * vf, vb, vb * vb);
#pragma unroll
  for (int m = 1; m < 64; m <<= 1) {
    s.x += __shfl_xor(s.x, m);
    s.y += __shfl_xor(s.y, m);
    s.z += __shfl_xor(s.z, m);
    s.w += __shfl_xor(s.w, m);
  }
  __shared__ float red[4][4];
  int w = threadIdx.x >> 6;
  if ((threadIdx.x & 63) == 0) {
    red[w][0] = s.x; red[w][1] = s.y; red[w][2] = s.z; red[w][3] = s.w;
  }
  __syncthreads();
  float s0 = red[0][0] + red[1][0] + red[2][0] + red[3][0];
  float s1 = red[0][1] + red[1][1] + red[2][1] + red[3][1];
  float s2 = red[0][2] + red[1][2] + red[2][2] + red[3][2];
  float s3 = red[0][3] + red[1][3] + red[2][3] + red[3][3];
  const float inv = 1.f / 256.f;
  float muf = s0 * inv, varf = s1 * inv - muf * muf;
  float mub = s2 * inv, varb = s3 * inv - mub * mub;
  float rf = rsqrtf(varf + 1e-5f);
  float rb = rsqrtf(varb + 1e-5f);
  float v = (vf - muf) * rf * gf[d] + bef[d] + (vb - mub) * rb * gb[d] + beb[d];
  if (up) {
    int y = l / Wf, x = l - y * Wf;
    int lc = (y >> 1) * Wc + (x >> 1);
    v += up[((size_t)b * (L >> 2) + lc) * 256 + d];
  }
  if (szT) v *= szT[base];
  out[base] = v;
}

// ---------------------------------------------------------------------------
extern "C" void kernel_launch(void* const* d_in, const int* in_sizes, int n_in,
                              void* d_out, int out_size, void* d_ws, size_t ws_size,
                              hipStream_t stream) {
  (void)in_sizes; (void)n_in; (void)out_size; (void)ws_size;
  const float* input_f = (const float*)d_in[0];
  const float* in_w  = (const float*)d_in[1];
  const float* in_b  = (const float*)d_in[2];
  const float* c1_w  = (const float*)d_in[3];
  const float* c1_b  = (const float*)d_in[4];
  const float* c2_w  = (const float*)d_in[5];
  const float* c2_b  = (const float*)d_in[6];
  const float* c3_w  = (const float*)d_in[7];
  const float* c3_b  = (const float*)d_in[8];
  const float* out_w = (const float*)d_in[9];
  const float* out_b = (const float*)d_in[10];
  const float* xw1  = (const float*)d_in[11];
  const float* dtw1 = (const float*)d_in[12];
  const float* dtb1 = (const float*)d_in[13];
  const float* Al1  = (const float*)d_in[14];
  const float* Dv1  = (const float*)d_in[15];
  const float* g1   = (const float*)d_in[16];
  const float* be1  = (const float*)d_in[17];
  const float* xw2  = (const float*)d_in[18];
  const float* dtw2 = (const float*)d_in[19];
  const float* dtb2 = (const float*)d_in[20];
  const float* Al2  = (const float*)d_in[21];
  const float* Dv2  = (const float*)d_in[22];
  const float* g2   = (const float*)d_in[23];
  const float* be2  = (const float*)d_in[24];
  const float* xw3  = (const float*)d_in[25];
  const float* dtw3 = (const float*)d_in[26];
  const float* dtb3 = (const float*)d_in[27];
  const float* Al3  = (const float*)d_in[28];
  const float* Dv3  = (const float*)d_in[29];
  const float* g3   = (const float*)d_in[30];
  const float* be3  = (const float*)d_in[31];

  float* ws = (float*)d_ws;
  constexpr size_t M1 = 2097152;     // 8*256*1024
  float* x    = ws + 0 * M1;         // (b,256,1024); later reused as d1f
  float* sz   = ws + 1 * M1;         // silu(z); reused as ic2, y1f
  float* szT  = ws + 2 * M1;         // (b,1024,256)
  float* f1   = ws + 3 * M1;         // (b,256,1024); reused as G
  float* d1b  = ws + 4 * M1;
  float* y1b  = ws + 5 * M1;
  size_t o = 6 * M1;
  float* f2   = ws + o; o += 524288;
  float* f3   = ws + o; o += 131072;
  float* ic3  = ws + o; o += 524288;
  float* bc1f = ws + o; o += 262144;
  float* bc1b = ws + o; o += 262144;
  float* d2   = ws + o; o += 524288;
  float* bc2  = ws + o; o += 65536;
  float* d3   = ws + o; o += 131072;
  float* bc3  = ws + o; o += 16384;
  float* y2f  = ws + o; o += 524288;
  float* y2b  = ws + o; o += 524288;
  float* y3f  = ws + o; o += 131072;
  float* y3b  = ws + o; o += 131072;
  float* y3c  = ws + o; o += 131072;
  float* y2c  = ws + o; o += 524288;
  float* cP   = ws + o; o += 1310720;  // 5120 slots x 256
  float* cQ   = ws + o; o += 1310720;
  // aliases (lifetimes verified against launch order below)
  float* d1f = x;    // x dead after c1
  float* ic2 = sz;   // sz dead after transpose
  float* y1f = sz;   // ic2 dead after c2 gemm
  float* G   = f1;   // f1 dead after scanC

  dim3 blk(256);

  // 1. in-proj
  gemm_k<0, 1><<<dim3(1024), blk, 0, stream>>>(in_w, input_f, in_b, x, sz,
                                               512, 1024, 512, 8, 16);
  // 2. transpose silu(z)
  transpose_k<<<dim3(256, 8), blk, 0, stream>>>(sz, szT);
  // 3. c1
  gemm_k<0, 0><<<dim3(512), blk, 0, stream>>>(c1_w, x, c1_b, f1, nullptr,
                                              256, 1024, 256, 4, 16);
  // 4-5. c2
  im2col2_k<<<dim3(8192), blk, 0, stream>>>(f1, ic2);
  gemm_k<0, 0><<<dim3(128), blk, 0, stream>>>(c2_w, ic2, c2_b, f2, nullptr,
                                              256, 256, 1024, 4, 4);
  // 6-7. c3
  im2col3_k<<<dim3(2048), blk, 0, stream>>>(f2, ic3);
  gemm_k<0, 0><<<dim3(32), blk, 0, stream>>>(c3_w, ic3, c3_b, f3, nullptr,
                                             256, 64, 1024, 4, 1);
  // 8-11. SSM projections
  proj_k<<<dim3(4, 8),  blk, 0, stream>>>(f3, 64,   xw3, dtw3, dtb3, d3,  bc3);
  proj_k<<<dim3(16, 8), blk, 0, stream>>>(f2, 256,  xw2, dtw2, dtb2, d2,  bc2);
  proj_k<<<dim3(64, 8), blk, 0, stream>>>(f1, 1024, xw1, dtw1, dtb1, d1f, bc1f);
  proj_k<<<dim3(64, 8), blk, 0, stream>>>(f1, 1024, xw2, dtw2, dtb2, d1b, bc1b);
  // 12. segment-parallel scan: carries -> prefix -> final
  scanA_k<<<dim3(5120), blk, 0, stream>>>(f1, f2, d1f, bc1f, d1b, bc1b,
                                          d2, bc2, Al1, Al2, cP, cQ);
  scanB_k<<<dim3(512), blk, 0, stream>>>(cP, cQ);
  scanC_k<<<dim3(5376), blk, 0, stream>>>(f1, f2, f3,
                                          d1f, bc1f, d1b, bc1b, d2, bc2, d3, bc3,
                                          y1f, y1b, y2f, y2b, y3f, y3b,
                                          Al1, Dv1, Al2, Dv2, Al3, Dv3, cP);
  // 13-15. LN + combine
  ln_combine<<<dim3(512), blk, 0, stream>>>(y3f, y3b, g3, be3, g3, be3,
                                            nullptr, 0, nullptr, y3c, 64, 8);
  ln_combine<<<dim3(2048), blk, 0, stream>>>(y2f, y2b, g2, be2, g2, be2,
                                             y3c, 8, nullptr, y2c, 256, 16);
  ln_combine<<<dim3(8192), blk, 0, stream>>>(y1f, y1b, g1, be1, g2, be2,
                                             y2c, 16, szT, G, 1024, 32);
  // 16. out-proj
  gemm_k<1, 0><<<dim3(1024), blk, 0, stream>>>(out_w, G, out_b, (float*)d_out,
                                               nullptr, 512, 1024, 256, 8, 16);
}

// Round 7
// 445.382 us; speedup vs baseline: 2.2269x; 1.2913x over previous
//
#include <hip/hip_runtime.h>
#include <cstddef>

#define DEV static __device__ __forceinline__

typedef __attribute__((ext_vector_type(8))) short short8;
typedef __attribute__((ext_vector_type(4))) float floatx4;

DEV float siluf(float v) { return v / (1.f + expf(-v)); }

DEV unsigned short f2bf(float f) {             // RNE fp32 -> bf16
  unsigned int u = __float_as_uint(f);
  u += 0x7fff + ((u >> 16) & 1);
  return (unsigned short)(u >> 16);
}

// DPP row-rotate add: sums within each 16-lane row after amounts 1,2,4,8.
template <int AMT>
DEV float ror_add(float v) {
  int s = __builtin_amdgcn_update_dpp(0, __float_as_int(v), 0x120 | AMT, 0xF, 0xF, false);
  return v + __int_as_float(s);
}

// ---------------------------------------------------------------------------
// Weight/params fp32 -> bf16 (one launch, fixed segment map).
// ---------------------------------------------------------------------------
__global__ __launch_bounds__(256) void cvt_w_k(
    const float* __restrict__ in_w, const float* __restrict__ c1_w,
    const float* __restrict__ c2_w, const float* __restrict__ c3_w,
    const float* __restrict__ out_w, const float* __restrict__ xw1,
    const float* __restrict__ xw2, const float* __restrict__ xw3,
    unsigned short* __restrict__ wsW)
{
  int gid = blockIdx.x * 256 + threadIdx.x;   // < 1013760
  const float* src; int off;
  if      (gid < 262144)  { src = in_w;  off = gid; }
  else if (gid < 327680)  { src = c1_w;  off = gid - 262144; }
  else if (gid < 589824)  { src = c2_w;  off = gid - 327680; }
  else if (gid < 851968)  { src = c3_w;  off = gid - 589824; }
  else if (gid < 983040)  { src = out_w; off = gid - 851968; }
  else if (gid < 993280)  { src = xw1;   off = gid - 983040; }
  else if (gid < 1003520) { src = xw2;   off = gid - 993280; }
  else                    { src = xw3;   off = gid - 1003520; }
  wsW[gid] = f2bf(src[off]);
}

// ---------------------------------------------------------------------------
// Transpose-convert: in fp32 (b, C, L) -> out bf16 (b, L, C). 32x32 tiles.
// ---------------------------------------------------------------------------
__global__ __launch_bounds__(256) void tcvt_k(const float* __restrict__ in,
                                              unsigned short* __restrict__ outp,
                                              int C, int L)
{
  __shared__ float tile[32][33];
  int b = blockIdx.y;
  int nLt = L >> 5;
  int pt = blockIdx.x % nLt, ct = blockIdx.x / nLt;
  int p0 = pt * 32, c0 = ct * 32;
  int r = threadIdx.x >> 5, cc = threadIdx.x & 31;
#pragma unroll
  for (int i = 0; i < 4; i++) {
    int row = r + 8 * i;
    tile[row][cc] = in[((size_t)b * C + c0 + row) * L + p0 + cc];
  }
  __syncthreads();
#pragma unroll
  for (int i = 0; i < 4; i++) {
    int row = r + 8 * i;
    outp[((size_t)b * L + p0 + row) * C + c0 + cc] = f2bf(tile[cc][row]);
  }
}

// ---------------------------------------------------------------------------
// im2col for 2x2 stride-2 convs -> bf16 (b, n, k) with k = c*4 + i*2 + j.
// ---------------------------------------------------------------------------
__global__ __launch_bounds__(256) void im2col2_k(const float* __restrict__ f1,
                                                 unsigned short* __restrict__ outp)
{
  int idx = blockIdx.x * 256 + threadIdx.x;   // 8*256*256
  int c = idx & 255, n = (idx >> 8) & 255, b = idx >> 16;
  int y = n >> 4, x = n & 15;
  const float* s = f1 + ((size_t)b * 256 + c) * 1024 + (2 * y) * 32 + 2 * x;
  ushort4 o;
  o.x = f2bf(s[0]); o.y = f2bf(s[1]); o.z = f2bf(s[32]); o.w = f2bf(s[33]);
  *(ushort4*)&outp[((size_t)b * 256 + n) * 1024 + c * 4] = o;
}

__global__ __launch_bounds__(256) void im2col3_k(const float* __restrict__ f2,
                                                 unsigned short* __restrict__ outp)
{
  int idx = blockIdx.x * 256 + threadIdx.x;   // 8*64*256
  int c = idx & 255, n = (idx >> 8) & 63, b = idx >> 14;
  int y = n >> 3, x = n & 7;
  const float* s = f2 + ((size_t)b * 256 + c) * 256 + (2 * y) * 16 + 2 * x;
  ushort4 o;
  o.x = f2bf(s[0]); o.y = f2bf(s[1]); o.z = f2bf(s[16]); o.w = f2bf(s[17]);
  *(ushort4*)&outp[((size_t)b * 64 + n) * 1024 + c * 4] = o;
}

// ---------------------------------------------------------------------------
// bf16 MFMA GEMM: Y[b,m,n] = bias[m] + sum_k W[m,k]*X[b,n,k]  (both bf16,
// k-contiguous). 128x128 tile, 4 waves of 64x64 via 4x4 mfma_16x16x32_bf16.
// A rows clamped to M-1, B rows clamped to N-1 (pad tiles); stores guarded.
// EPI=0: Y0 fp32 (b,M,N) n-contig.  bias may be nullptr.
// EPI=1: in-proj: m<256 -> Yxt bf16 (b,1024,256) transposed;
//                 m>=256 -> YszT fp32 (b,1024,256) transposed silu.
// ---------------------------------------------------------------------------
template <int EPI>
__global__ __launch_bounds__(256) void mgemm_k(
    const unsigned short* __restrict__ Wb, const unsigned short* __restrict__ Xb,
    const float* __restrict__ bias, float* __restrict__ Y0,
    unsigned short* __restrict__ Yxt, float* __restrict__ YszT,
    int M, int N, int K, int Mt, int Nt)
{
  __shared__ __align__(16) unsigned short Ab[128 * 40];  // [m][k], pitch 40
  __shared__ __align__(16) unsigned short Bb[128 * 40];  // [n][k]
  int bid = blockIdx.x;
  int tiles = Mt * Nt;
  int bb = bid / tiles;
  int rr = bid - bb * tiles;
  int mt = rr / Nt;
  int m0 = mt * 128;
  int n0 = (rr - mt * Nt) * 128;
  const unsigned short* Xp = Xb + (size_t)bb * N * K;

  int t = threadIdx.x;
  int lane = t & 63;
  int wm = ((t >> 7) & 1) * 64;
  int wn = ((t >> 6) & 1) * 64;
  int l15 = lane & 15, quad = lane >> 4;

  int srow = t >> 1;
  int shalf = (t & 1) * 16;
  int arow = m0 + srow; if (arow > M - 1) arow = M - 1;
  int brow = n0 + srow; if (brow > N - 1) brow = N - 1;
  const unsigned short* ap = Wb + (size_t)arow * K + shalf;
  const unsigned short* bp = Xp + (size_t)brow * K + shalf;
  unsigned short* as = &Ab[srow * 40 + shalf];
  unsigned short* bs = &Bb[srow * 40 + shalf];

  floatx4 acc[4][4] = {};

  for (int k0 = 0; k0 < K; k0 += 32) {
    uint4 a0 = *(const uint4*)(ap + k0);
    uint4 a1 = *(const uint4*)(ap + k0 + 8);
    uint4 b0 = *(const uint4*)(bp + k0);
    uint4 b1 = *(const uint4*)(bp + k0 + 8);
    __syncthreads();
    *(uint4*)as = a0; *(uint4*)(as + 8) = a1;
    *(uint4*)bs = b0; *(uint4*)(bs + 8) = b1;
    __syncthreads();
    short8 af[4], bf[4];
#pragma unroll
    for (int i = 0; i < 4; i++)
      af[i] = *(const short8*)&Ab[(wm + i * 16 + l15) * 40 + quad * 8];
#pragma unroll
    for (int j = 0; j < 4; j++)
      bf[j] = *(const short8*)&Bb[(wn + j * 16 + l15) * 40 + quad * 8];
#pragma unroll
    for (int i = 0; i < 4; i++)
#pragma unroll
      for (int j = 0; j < 4; j++)
        acc[i][j] = __builtin_amdgcn_mfma_f32_16x16x32_bf16(af[i], bf[j],
                                                            acc[i][j], 0, 0, 0);
  }

#pragma unroll
  for (int i = 0; i < 4; i++) {
    int m = m0 + wm + i * 16 + quad * 4;      // M is a multiple of 4 everywhere
#pragma unroll
    for (int j = 0; j < 4; j++) {
      int n = n0 + wn + j * 16 + l15;
      if (EPI == 0) {
        if (m < M && n < N) {
          float* yp = &Y0[((size_t)bb * M + m) * N + n];
#pragma unroll
          for (int r = 0; r < 4; r++)
            yp[(size_t)r * N] = acc[i][j][r] + (bias ? bias[m + r] : 0.f);
        }
      } else {
        float vr[4];
#pragma unroll
        for (int r = 0; r < 4; r++) vr[r] = acc[i][j][r] + bias[m + r];
        if (m < 256) {
          ushort4 o;
          o.x = f2bf(vr[0]); o.y = f2bf(vr[1]); o.z = f2bf(vr[2]); o.w = f2bf(vr[3]);
          *(ushort4*)&Yxt[((size_t)bb * 1024 + n) * 256 + m] = o;
        } else {
          float4 o = make_float4(siluf(vr[0]), siluf(vr[1]), siluf(vr[2]), siluf(vr[3]));
          *(float4*)&YszT[((size_t)bb * 1024 + n) * 256 + (m - 256)] = o;
        }
      }
    }
  }
}

// ---------------------------------------------------------------------------
// Post-projection: delta[b,d,l] = softplus(sum_r xd[r,l]*dtw[d,r] + dtb[d]);
// bc[b,c,l] = xd[8+c, l].  xd is (b, XDM, L) fp32 (rows 0..39 used via offset).
// Block = (l-tile of 16, b), 256 threads = d.
// ---------------------------------------------------------------------------
__global__ __launch_bounds__(256) void post_k(
    const float* __restrict__ xd, int bstride, int L,
    const float* __restrict__ dtw, const float* __restrict__ dtb,
    float* __restrict__ delta_g, float* __restrict__ bc_g)
{
  __shared__ float dl[8][16];
  int t = threadIdx.x, b = blockIdx.y, l0 = blockIdx.x * 16;
  const float* xb = xd + (size_t)b * bstride + l0;
  if (t < 128) {
    int r = t >> 4, l = t & 15;
    dl[r][l] = xb[(size_t)r * L + l];
  } else {
    int tt = t - 128;
    int c = tt >> 2, seg = tt & 3;
    float4 v = *(const float4*)&xb[(size_t)(8 + c) * L + seg * 4];
    *(float4*)&bc_g[((size_t)b * 32 + c) * L + l0 + seg * 4] = v;
  }
  __syncthreads();
  int d = t;
  float dtwv[8];
#pragma unroll
  for (int r = 0; r < 8; r++) dtwv[r] = dtw[d * 8 + r];
  float dtbv = dtb[d];
  float spv[16];
#pragma unroll
  for (int l = 0; l < 16; l++) {
    float s = dtbv;
#pragma unroll
    for (int r = 0; r < 8; r++) s += dl[r][l] * dtwv[r];
    spv[l] = fmaxf(s, 0.f) + log1pf(expf(-fabsf(s)));
  }
  float* dout = delta_g + ((size_t)b * 256 + d) * L + l0;
#pragma unroll
  for (int i = 0; i < 4; i++)
    *(float4*)&dout[4 * i] = make_float4(spv[4 * i], spv[4 * i + 1],
                                         spv[4 * i + 2], spv[4 * i + 3]);
}

// ---------------------------------------------------------------------------
// Segment-parallel selective scan, 3 passes (proven in round 4).
// ---------------------------------------------------------------------------
#define SCAN_STEP(DVV, XVV, BVV) {                 \
    float e_ = __expf((DVV) * A);                  \
    h = h * e_ + (DVV) * (BVV) * (XVV);            \
    P *= e_; }

__global__ __launch_bounds__(256) void scanA_k(
    const float* __restrict__ f1, const float* __restrict__ f2,
    const float* __restrict__ d1f, const float* __restrict__ bc1f,
    const float* __restrict__ d1b, const float* __restrict__ bc1b,
    const float* __restrict__ d2,  const float* __restrict__ bc2,
    const float* __restrict__ Al1, const float* __restrict__ Al2,
    float* __restrict__ cP, float* __restrict__ cQ)
{
  __shared__ __align__(16) float lds[48][68];
  int bid = blockIdx.x;
  int sid, tseg, L; const float *xin, *dlp, *bcp, *Alp;
  if (bid < 4096) {
    sid = bid >> 4; tseg = bid & 15; L = 1024; xin = f1;
    if (((sid >> 4) & 1) == 0) { dlp = d1f; bcp = bc1f; Alp = Al1; }
    else                       { dlp = d1b; bcp = bc1b; Alp = Al2; }
  } else {
    int idx = bid - 4096; sid = idx >> 2; tseg = idx & 3; L = 256;
    xin = f2; dlp = d2; bcp = bc2; Alp = Al2;
  }
  int b = sid >> 5, dir = (sid >> 4) & 1, g = sid & 15;
  int t = threadIdx.x, n = t & 15, dloc = t >> 4, d = g * 16 + dloc;
  int mbase = dir ? (L - 64 * (tseg + 1)) : 64 * tseg;

  int r0 = t >> 4, cs = t & 15;
  {
    const float* p0 = dlp + ((size_t)b * 256 + g * 16 + r0) * L + mbase;
    const float* p1 = xin + ((size_t)b * 256 + g * 16 + r0) * L + mbase;
    const float* p2 = bcp + ((size_t)b * 32 + r0) * L + mbase;
    float4 v0 = *(const float4*)(p0 + cs * 4);
    float4 v1 = *(const float4*)(p1 + cs * 4);
    float4 v2 = *(const float4*)(p2 + cs * 4);
    *(float4*)&lds[r0][cs * 4]      = v0;
    *(float4*)&lds[16 + r0][cs * 4] = v1;
    *(float4*)&lds[32 + r0][cs * 4] = v2;
  }
  __syncthreads();

  float A = -expf(Alp[d * 16 + n]);
  float h = 0.f, P = 1.f;
  if (dir == 0) {
#pragma unroll
    for (int g4 = 0; g4 < 16; g4++) {
      int cb = 4 * g4;
      float4 dv4 = *(const float4*)&lds[dloc][cb];
      float4 xv4 = *(const float4*)&lds[16 + dloc][cb];
      float4 bv4 = *(const float4*)&lds[32 + n][cb];
      SCAN_STEP(dv4.x, xv4.x, bv4.x);
      SCAN_STEP(dv4.y, xv4.y, bv4.y);
      SCAN_STEP(dv4.z, xv4.z, bv4.z);
      SCAN_STEP(dv4.w, xv4.w, bv4.w);
    }
  } else {
#pragma unroll
    for (int g4 = 0; g4 < 16; g4++) {
      int cb = 60 - 4 * g4;
      float4 dv4 = *(const float4*)&lds[dloc][cb];
      float4 xv4 = *(const float4*)&lds[16 + dloc][cb];
      float4 bv4 = *(const float4*)&lds[32 + n][cb];
      SCAN_STEP(dv4.w, xv4.w, bv4.w);
      SCAN_STEP(dv4.z, xv4.z, bv4.z);
      SCAN_STEP(dv4.y, xv4.y, bv4.y);
      SCAN_STEP(dv4.x, xv4.x, bv4.x);
    }
  }
  cP[(size_t)bid * 256 + t] = P;
  cQ[(size_t)bid * 256 + t] = h;
}

__global__ __launch_bounds__(256) void scanB_k(float* __restrict__ cP,
                                               const float* __restrict__ cQ)
{
  int bidx = blockIdx.x, t = threadIdx.x;
  int S, base;
  if (bidx < 256) { S = 16; base = bidx * 16; }
  else            { S = 4;  base = 4096 + (bidx - 256) * 4; }
  float h = 0.f;
  for (int s = 0; s < S; s++) {
    size_t off = (size_t)(base + s) * 256 + t;
    float p = cP[off], q = cQ[off];
    cP[off] = h;
    h = p * h + q;
  }
}

#define SCAN_STEPY(DVV, XVV, BVV, CVV, COL) {      \
    float e_ = __expf((DVV) * A);                  \
    h = h * e_ + (DVV) * (BVV) * (XVV);            \
    float pp_ = h * (CVV);                         \
    pp_ = ror_add<1>(pp_);                         \
    pp_ = ror_add<2>(pp_);                         \
    pp_ = ror_add<4>(pp_);                         \
    pp_ = ror_add<8>(pp_);                         \
    float yv_ = pp_ + (XVV) * Dvv;                 \
    ysel = (((COL) & 15) == n) ? yv_ : ysel; }

__global__ __launch_bounds__(256) void scanC_k(
    const float* __restrict__ f1, const float* __restrict__ f2, const float* __restrict__ f3,
    const float* __restrict__ d1f, const float* __restrict__ bc1f,
    const float* __restrict__ d1b, const float* __restrict__ bc1b,
    const float* __restrict__ d2,  const float* __restrict__ bc2,
    const float* __restrict__ d3,  const float* __restrict__ bc3,
    float* __restrict__ y1f, float* __restrict__ y1b,
    float* __restrict__ y2f, float* __restrict__ y2b,
    float* __restrict__ y3f, float* __restrict__ y3b,
    const float* __restrict__ Al1, const float* __restrict__ Dv1,
    const float* __restrict__ Al2, const float* __restrict__ Dv2,
    const float* __restrict__ Al3, const float* __restrict__ Dv3,
    const float* __restrict__ cP)
{
  __shared__ __align__(16) float lds[64][68];
  int bid = blockIdx.x;
  int sid, tseg, L, slot; const float *xin, *dlp, *bcp, *Alp, *Dvp; float* yo;
  if (bid < 4096) {
    sid = bid >> 4; tseg = bid & 15; slot = bid; L = 1024; xin = f1;
    if (((sid >> 4) & 1) == 0) { dlp = d1f; bcp = bc1f; Alp = Al1; Dvp = Dv1; yo = y1f; }
    else                       { dlp = d1b; bcp = bc1b; Alp = Al2; Dvp = Dv2; yo = y1b; }
  } else if (bid < 5120) {
    int idx = bid - 4096; sid = idx >> 2; tseg = idx & 3; slot = bid; L = 256;
    xin = f2; dlp = d2; bcp = bc2; Alp = Al2; Dvp = Dv2;
    yo = ((sid >> 4) & 1) ? y2b : y2f;
  } else {
    sid = bid - 5120; tseg = 0; slot = -1; L = 64;
    xin = f3; dlp = d3; bcp = bc3; Alp = Al3; Dvp = Dv3;
    yo = ((sid >> 4) & 1) ? y3b : y3f;
  }
  int b = sid >> 5, dir = (sid >> 4) & 1, g = sid & 15;
  int t = threadIdx.x, n = t & 15, dloc = t >> 4, d = g * 16 + dloc;
  int mbase = dir ? (L - 64 * (tseg + 1)) : 64 * tseg;

  int r0 = t >> 4, cs = t & 15;
  {
    const float* p0 = dlp + ((size_t)b * 256 + g * 16 + r0) * L + mbase;
    const float* p1 = xin + ((size_t)b * 256 + g * 16 + r0) * L + mbase;
    const float* p2 = bcp + ((size_t)b * 32 + r0) * L + mbase;
    const float* p3 = bcp + ((size_t)b * 32 + 16 + r0) * L + mbase;
    float4 v0 = *(const float4*)(p0 + cs * 4);
    float4 v1 = *(const float4*)(p1 + cs * 4);
    float4 v2 = *(const float4*)(p2 + cs * 4);
    float4 v3 = *(const float4*)(p3 + cs * 4);
    *(float4*)&lds[r0][cs * 4]      = v0;
    *(float4*)&lds[16 + r0][cs * 4] = v1;
    *(float4*)&lds[32 + r0][cs * 4] = v2;
    *(float4*)&lds[48 + r0][cs * 4] = v3;
  }
  float A   = -expf(Alp[d * 16 + n]);
  float Dvv = Dvp[d];
  float h = (slot >= 0) ? cP[(size_t)slot * 256 + t] : 0.f;
  __syncthreads();

  float* ybase = yo + ((size_t)b * L + mbase) * 256 + d;
#pragma unroll
  for (int jj0 = 0; jj0 < 64; jj0 += 16) {
    float ysel = 0.f;
    if (dir == 0) {
#pragma unroll
      for (int g4 = 0; g4 < 4; g4++) {
        int cb = jj0 + 4 * g4;
        float4 dv4 = *(const float4*)&lds[dloc][cb];
        float4 xv4 = *(const float4*)&lds[16 + dloc][cb];
        float4 bv4 = *(const float4*)&lds[32 + n][cb];
        float4 cv4 = *(const float4*)&lds[48 + n][cb];
        SCAN_STEPY(dv4.x, xv4.x, bv4.x, cv4.x, cb + 0);
        SCAN_STEPY(dv4.y, xv4.y, bv4.y, cv4.y, cb + 1);
        SCAN_STEPY(dv4.z, xv4.z, bv4.z, cv4.z, cb + 2);
        SCAN_STEPY(dv4.w, xv4.w, bv4.w, cv4.w, cb + 3);
      }
    } else {
#pragma unroll
      for (int g4 = 0; g4 < 4; g4++) {
        int cb = 60 - jj0 - 4 * g4;
        float4 dv4 = *(const float4*)&lds[dloc][cb];
        float4 xv4 = *(const float4*)&lds[16 + dloc][cb];
        float4 bv4 = *(const float4*)&lds[32 + n][cb];
        float4 cv4 = *(const float4*)&lds[48 + n][cb];
        SCAN_STEPY(dv4.w, xv4.w, bv4.w, cv4.w, cb + 3);
        SCAN_STEPY(dv4.z, xv4.z, bv4.z, cv4.z, cb + 2);
        SCAN_STEPY(dv4.y, xv4.y, bv4.y, cv4.y, cb + 1);
        SCAN_STEPY(dv4.x, xv4.x, bv4.x, cv4.x, cb + 0);
      }
    }
    int colbase = dir ? 48 - jj0 : jj0;
    ybase[(size_t)(colbase + n) * 256] = ysel;
  }
}

// ---------------------------------------------------------------------------
// LayerNorm(fwd)+LayerNorm(bwd) + optional upsample add + optional *szT.
// OUTBF=1 writes bf16 (for the final GEMM operand G).
// ---------------------------------------------------------------------------
template <int OUTBF>
__global__ __launch_bounds__(256) void ln_combine(
    const float* __restrict__ yf, const float* __restrict__ yb,
    const float* __restrict__ gf, const float* __restrict__ bef,
    const float* __restrict__ gb, const float* __restrict__ beb,
    const float* __restrict__ up, int Wc,
    const float* __restrict__ szT, void* __restrict__ outv,
    int L, int Wf)
{
  int bid = blockIdx.x;
  int b = bid / L;
  int l = bid - b * L;
  int d = threadIdx.x;
  size_t base = ((size_t)b * L + l) * 256 + d;
  float vf = yf[base], vb = yb[base];
  float4 s = make_float4(vf, vf * vf, vb, vb * vb);
#pragma unroll
  for (int m = 1; m < 64; m <<= 1) {
    s.x += __shfl_xor(s.x, m);
    s.y += __shfl_xor(s.y, m);
    s.z += __shfl_xor(s.z, m);
    s.w += __shfl_xor(s.w, m);
  }
  __shared__ float red[4][4];
  int w = threadIdx.x >> 6;
  if ((threadIdx.x & 63) == 0) {
    red[w][0] = s.x; red[w][1] = s.y; red[w][2] = s.z; red[w][3] = s.w;
  }
  __syncthreads();
  float s0 = red[0][0] + red[1][0] + red[2][0] + red[3][0];
  float s1 = red[0][1] + red[1][1] + red[2][1] + red[3][1];
  float s2 = red[0][2] + red[1][2] + red[2][2] + red[3][2];
  float s3 = red[0][3] + red[1][3] + red[2][3] + red[3][3];
  const float inv = 1.f / 256.f;
  float muf = s0 * inv, varf = s1 * inv - muf * muf;
  float mub = s2 * inv, varb = s3 * inv - mub * mub;
  float rf = rsqrtf(varf + 1e-5f);
  float rb = rsqrtf(varb + 1e-5f);
  float v = (vf - muf) * rf * gf[d] + bef[d] + (vb - mub) * rb * gb[d] + beb[d];
  if (up) {
    int y = l / Wf, x = l - y * Wf;
    int lc = (y >> 1) * Wc + (x >> 1);
    v += up[((size_t)b * (L >> 2) + lc) * 256 + d];
  }
  if (szT) v *= szT[base];
  if (OUTBF) ((unsigned short*)outv)[base] = f2bf(v);
  else       ((float*)outv)[base] = v;
}

// ---------------------------------------------------------------------------
extern "C" void kernel_launch(void* const* d_in, const int* in_sizes, int n_in,
                              void* d_out, int out_size, void* d_ws, size_t ws_size,
                              hipStream_t stream) {
  (void)in_sizes; (void)n_in; (void)out_size; (void)ws_size;
  const float* input_f = (const float*)d_in[0];
  const float* in_w  = (const float*)d_in[1];
  const float* in_b  = (const float*)d_in[2];
  const float* c1_w  = (const float*)d_in[3];
  const float* c1_b  = (const float*)d_in[4];
  const float* c2_w  = (const float*)d_in[5];
  const float* c2_b  = (const float*)d_in[6];
  const float* c3_w  = (const float*)d_in[7];
  const float* c3_b  = (const float*)d_in[8];
  const float* out_w = (const float*)d_in[9];
  const float* out_b = (const float*)d_in[10];
  const float* xw1  = (const float*)d_in[11];
  const float* dtw1 = (const float*)d_in[12];
  const float* dtb1 = (const float*)d_in[13];
  const float* Al1  = (const float*)d_in[14];
  const float* Dv1  = (const float*)d_in[15];
  const float* g1   = (const float*)d_in[16];
  const float* be1  = (const float*)d_in[17];
  const float* xw2  = (const float*)d_in[18];
  const float* dtw2 = (const float*)d_in[19];
  const float* dtb2 = (const float*)d_in[20];
  const float* Al2  = (const float*)d_in[21];
  const float* Dv2  = (const float*)d_in[22];
  const float* g2   = (const float*)d_in[23];
  const float* be2  = (const float*)d_in[24];
  const float* xw3  = (const float*)d_in[25];
  const float* dtw3 = (const float*)d_in[26];
  const float* dtb3 = (const float*)d_in[27];
  const float* Al3  = (const float*)d_in[28];
  const float* Dv3  = (const float*)d_in[29];
  const float* g3   = (const float*)d_in[30];
  const float* be3  = (const float*)d_in[31];

  float* ws = (float*)d_ws;
  constexpr size_t M1 = 2097152;   // 8*256*1024 floats
  // Region map (float offsets), lifetimes verified against launch order:
  float* d1f = ws;                                      // R0
  unsigned short* xt = (unsigned short*)(ws + M1);      // R1 (bf16; dead after c1)
  unsigned short* f1t = (unsigned short*)(ws + M1);     // R1 (bf16 of f1^T; written
                                                        //     after c1, dead after xd12)
  float* y1f = ws + M1;                                 // R1 (after f1t dead)
  float* szT = ws + 2 * M1;                             // R2
  float* f1  = ws + 3 * M1;                             // R3
  unsigned short* G = (unsigned short*)(ws + 3 * M1);   // R3 (after f1 dead)
  float* d1b = ws + 4 * M1;                             // R4
  unsigned short* inT = (unsigned short*)(ws + 5 * M1); // R5 (bf16, full)
  unsigned short* ic2 = (unsigned short*)(ws + 5 * M1);           // after inT dead
  unsigned short* ic3 = (unsigned short*)(ws + 5 * M1) + 2097152; // bf16 offset
  float* y1b = ws + 5 * M1;                             // R5 (after ic2/ic3 dead)
  size_t o = 6 * M1;
  float* f2   = ws + o; o += 524288;
  float* f3   = ws + o; o += 131072;
  float* bc1f = ws + o; o += 262144;
  float* bc1b = ws + o; o += 262144;
  float* d2   = ws + o; o += 524288;
  float* bc2  = ws + o; o += 65536;
  float* d3   = ws + o; o += 131072;
  float* bc3  = ws + o; o += 16384;
  float* y2f  = ws + o; o += 524288;
  float* y2b  = ws + o; o += 524288;
  float* y3f  = ws + o; o += 131072;
  float* y3b  = ws + o; o += 131072;
  float* y3c  = ws + o; o += 131072;
  float* y2c  = ws + o; o += 524288;
  float* cP   = ws + o; o += 1310720;
  float* cQ   = ws + o; o += 1310720;
  unsigned short* wsW = (unsigned short*)(ws + o); o += 506880;
  // xd buffers alias cP (dead before scanA writes cP):
  float* xd12 = cP;                 // (b,80,1024) = 655360
  float* xd2  = cP + 655360;        // (b,40,256)  = 81920
  float* xd3  = cP + 737280;        // (b,40,64)   = 20480
  // transposed bf16 f2/f3 alias cQ:
  unsigned short* f2t = (unsigned short*)cQ;            // (b,256,256)
  unsigned short* f3t = (unsigned short*)(cQ + 262144); // (b,64,256)
  // bf16 weight sub-pointers:
  unsigned short* w_in   = wsW;
  unsigned short* w_c1   = wsW + 262144;
  unsigned short* w_c2   = wsW + 327680;
  unsigned short* w_c3   = wsW + 589824;
  unsigned short* w_out  = wsW + 851968;
  unsigned short* w_xw12 = wsW + 983040;   // [xw1;xw2] stacked (80x256)
  unsigned short* w_xw2  = wsW + 993280;
  unsigned short* w_xw3  = wsW + 1003520;

  dim3 blk(256);

  // 1. convert all weights/params to bf16
  cvt_w_k<<<dim3(3960), blk, 0, stream>>>(in_w, c1_w, c2_w, c3_w, out_w,
                                          xw1, xw2, xw3, wsW);
  // 2. transpose-convert input_f -> inT bf16 (b,1024,512)
  tcvt_k<<<dim3(512, 8), blk, 0, stream>>>(input_f, inT, 512, 1024);
  // 3. in-proj MFMA GEMM -> xt bf16 (b,1024,256) + szT fp32 (b,1024,256)
  mgemm_k<1><<<dim3(256), blk, 0, stream>>>(w_in, inT, in_b, nullptr, xt, szT,
                                            512, 1024, 512, 4, 8);
  // 4. c1 -> f1 fp32 (b,256,1024)
  mgemm_k<0><<<dim3(128), blk, 0, stream>>>(w_c1, xt, c1_b, f1, nullptr, nullptr,
                                            256, 1024, 256, 2, 8);
  // 4b. f1 -> f1t bf16 (b,1024,256): the level-1 SSM projection input is
  //     fx1 = f1 (the c1 OUTPUT), not x. (Round-5 bug: xd12 used xt.)
  tcvt_k<<<dim3(256, 8), blk, 0, stream>>>(f1, f1t, 256, 1024);
  // 5-6. c2 (im2col bf16 + GEMM) -> f2
  im2col2_k<<<dim3(2048), blk, 0, stream>>>(f1, ic2);
  mgemm_k<0><<<dim3(32), blk, 0, stream>>>(w_c2, ic2, c2_b, f2, nullptr, nullptr,
                                           256, 256, 1024, 2, 2);
  // 7-8. c3 -> f3
  im2col3_k<<<dim3(512), blk, 0, stream>>>(f2, ic3);
  mgemm_k<0><<<dim3(16), blk, 0, stream>>>(w_c3, ic3, c3_b, f3, nullptr, nullptr,
                                           256, 64, 1024, 2, 1);
  // 9-10. transposed bf16 copies of f2, f3 for the xd GEMMs
  tcvt_k<<<dim3(64, 8), blk, 0, stream>>>(f2, f2t, 256, 256);
  tcvt_k<<<dim3(16, 8), blk, 0, stream>>>(f3, f3t, 256, 64);
  // 11-13. xd = xw @ fx GEMMs (lvl1 fwd+bwd stacked as M=80, input f1t)
  mgemm_k<0><<<dim3(64), blk, 0, stream>>>(w_xw12, f1t, nullptr, xd12, nullptr, nullptr,
                                           80, 1024, 256, 1, 8);
  mgemm_k<0><<<dim3(16), blk, 0, stream>>>(w_xw2, f2t, nullptr, xd2, nullptr, nullptr,
                                           40, 256, 256, 1, 2);
  mgemm_k<0><<<dim3(8), blk, 0, stream>>>(w_xw3, f3t, nullptr, xd3, nullptr, nullptr,
                                          40, 64, 256, 1, 1);
  // 14-17. delta/softplus + B/C repack
  post_k<<<dim3(64, 8), blk, 0, stream>>>(xd12,             80 * 1024, 1024,
                                          dtw1, dtb1, d1f, bc1f);
  post_k<<<dim3(64, 8), blk, 0, stream>>>(xd12 + 40 * 1024, 80 * 1024, 1024,
                                          dtw2, dtb2, d1b, bc1b);
  post_k<<<dim3(16, 8), blk, 0, stream>>>(xd2,              40 * 256,  256,
                                          dtw2, dtb2, d2, bc2);
  post_k<<<dim3(4, 8),  blk, 0, stream>>>(xd3,              40 * 64,   64,
                                          dtw3, dtb3, d3, bc3);
  // 18-20. segment-parallel scan
  scanA_k<<<dim3(5120), blk, 0, stream>>>(f1, f2, d1f, bc1f, d1b, bc1b,
                                          d2, bc2, Al1, Al2, cP, cQ);
  scanB_k<<<dim3(512), blk, 0, stream>>>(cP, cQ);
  scanC_k<<<dim3(5376), blk, 0, stream>>>(f1, f2, f3,
                                          d1f, bc1f, d1b, bc1b, d2, bc2, d3, bc3,
                                          y1f, y1b, y2f, y2b, y3f, y3b,
                                          Al1, Dv1, Al2, Dv2, Al3, Dv3, cP);
  // 21-23. LN + combine (level 1 writes bf16 G for the out-proj GEMM)
  ln_combine<0><<<dim3(512), blk, 0, stream>>>(y3f, y3b, g3, be3, g3, be3,
                                               nullptr, 0, nullptr, y3c, 64, 8);
  ln_combine<0><<<dim3(2048), blk, 0, stream>>>(y2f, y2b, g2, be2, g2, be2,
                                                y3c, 8, nullptr, y2c, 256, 16);
  ln_combine<1><<<dim3(8192), blk, 0, stream>>>(y1f, y1b, g1, be1, g2, be2,
                                                y2c, 16, szT, G, 1024, 32);
  // 24. out-proj MFMA GEMM -> d_out fp32 (b,512,1024)
  mgemm_k<0><<<dim3(256), blk, 0, stream>>>(w_out, G, out_b, (float*)d_out,
                                            nullptr, nullptr, 512, 1024, 256, 4, 8);
}

// Round 8
// 387.222 us; speedup vs baseline: 2.5613x; 1.1502x over previous
//
#include <hip/hip_runtime.h>
#include <cstddef>

#define DEV static __device__ __forceinline__

typedef __attribute__((ext_vector_type(8))) short short8;
typedef __attribute__((ext_vector_type(4))) float floatx4;

DEV float siluf(float v) { return v / (1.f + expf(-v)); }

DEV unsigned short f2bf(float f) {             // RNE fp32 -> bf16
  unsigned int u = __float_as_uint(f);
  u += 0x7fff + ((u >> 16) & 1);
  return (unsigned short)(u >> 16);
}

// DPP row-rotate add: sums within each 16-lane row after amounts 1,2,4,8.
template <int AMT>
DEV float ror_add(float v) {
  int s = __builtin_amdgcn_update_dpp(0, __float_as_int(v), 0x120 | AMT, 0xF, 0xF, false);
  return v + __int_as_float(s);
}

// ---------------------------------------------------------------------------
// Weight/params fp32 -> bf16. c2/c3 are k-REORDERED: dest[o][ij*256+c] =
// src[o][c][i][j]  (matches the k-order im2col2/3 emit).
// ---------------------------------------------------------------------------
__global__ __launch_bounds__(256) void cvt_w_k(
    const float* __restrict__ in_w, const float* __restrict__ c1_w,
    const float* __restrict__ c2_w, const float* __restrict__ c3_w,
    const float* __restrict__ out_w, const float* __restrict__ xw1,
    const float* __restrict__ xw2, const float* __restrict__ xw3,
    unsigned short* __restrict__ wsW)
{
  int gid = blockIdx.x * 256 + threadIdx.x;   // < 1013760
  float v;
  if      (gid < 262144)  v = in_w[gid];
  else if (gid < 327680)  v = c1_w[gid - 262144];
  else if (gid < 589824)  {
    int off = gid - 327680;
    int o = off >> 10, kk = off & 1023, ij = kk >> 8, c = kk & 255;
    v = c2_w[o * 1024 + c * 4 + ij];
  }
  else if (gid < 851968)  {
    int off = gid - 589824;
    int o = off >> 10, kk = off & 1023, ij = kk >> 8, c = kk & 255;
    v = c3_w[o * 1024 + c * 4 + ij];
  }
  else if (gid < 983040)  v = out_w[gid - 851968];
  else if (gid < 993280)  v = xw1[gid - 983040];
  else if (gid < 1003520) v = xw2[gid - 993280];
  else                    v = xw3[gid - 1003520];
  wsW[gid] = f2bf(v);
}

// ---------------------------------------------------------------------------
// Transpose-convert: fp32 (b, C, L) -> bf16 (b, L, C). Used only for input_f.
// ---------------------------------------------------------------------------
__global__ __launch_bounds__(256) void tcvt_k(const float* __restrict__ in,
                                              unsigned short* __restrict__ outp,
                                              int C, int L)
{
  __shared__ float tile[32][33];
  int b = blockIdx.y;
  int nLt = L >> 5;
  int pt = blockIdx.x % nLt, ct = blockIdx.x / nLt;
  int p0 = pt * 32, c0 = ct * 32;
  int r = threadIdx.x >> 5, cc = threadIdx.x & 31;
#pragma unroll
  for (int i = 0; i < 4; i++) {
    int row = r + 8 * i;
    tile[row][cc] = in[((size_t)b * C + c0 + row) * L + p0 + cc];
  }
  __syncthreads();
#pragma unroll
  for (int i = 0; i < 4; i++) {
    int row = r + 8 * i;
    outp[((size_t)b * L + p0 + row) * C + c0 + cc] = f2bf(tile[cc][row]);
  }
}

// ---------------------------------------------------------------------------
// im2col from PIXEL-MAJOR bf16 sources, k = ij*256 + c (fully coalesced).
// ---------------------------------------------------------------------------
__global__ __launch_bounds__(256) void im2col2_k(const unsigned short* __restrict__ f1t,
                                                 unsigned short* __restrict__ outp)
{
  int idx = blockIdx.x * 256 + threadIdx.x;   // 8b * 256n * 4ij * 32cs = 262144
  int cs = idx & 31, ij = (idx >> 5) & 3, n = (idx >> 7) & 255, b = idx >> 15;
  int i = ij >> 1, j = ij & 1;
  int y = n >> 4, x = n & 15;
  int pix = (2 * y + i) * 32 + 2 * x + j;
  uint4 v = *(const uint4*)&f1t[((size_t)b * 1024 + pix) * 256 + cs * 8];
  *(uint4*)&outp[((size_t)b * 256 + n) * 1024 + ij * 256 + cs * 8] = v;
}

__global__ __launch_bounds__(256) void im2col3_k(const unsigned short* __restrict__ f2t,
                                                 unsigned short* __restrict__ outp)
{
  int idx = blockIdx.x * 256 + threadIdx.x;   // 8b * 64n * 4ij * 32cs = 65536
  int cs = idx & 31, ij = (idx >> 5) & 3, n = (idx >> 7) & 63, b = idx >> 13;
  int i = ij >> 1, j = ij & 1;
  int y = n >> 3, x = n & 7;
  int pix = (2 * y + i) * 16 + 2 * x + j;
  uint4 v = *(const uint4*)&f2t[((size_t)b * 256 + pix) * 256 + cs * 8];
  *(uint4*)&outp[((size_t)b * 64 + n) * 1024 + ij * 256 + cs * 8] = v;
}

// ---------------------------------------------------------------------------
// bf16 MFMA GEMM: Y[m,n] = sum_k A[bb*sA + m*K + k] * B[bb*sB + n*K + k].
// 128x128 tile / 4 waves / 4x4 mfma_16x16x32_bf16. Rows clamped, stores guarded.
// EPI=0: Y0 fp32 (b,M,N), bias[m] (nullable).
// EPI=1: in-proj (M=1024 pixels, N=512 chans), bias[n]:
//        n<256 -> Yt bf16 [(b*1024+m)*256+n]; n>=256 -> Ys fp32 silu.
// EPI=2: Y0 fp32 (b,M,N) + Yt bf16 transposed [(b*N+n)*M+m], bias[m].
// ---------------------------------------------------------------------------
template <int EPI>
__global__ __launch_bounds__(256) void mgemm_k(
    const unsigned short* __restrict__ A, long long sA,
    const unsigned short* __restrict__ B, long long sB,
    const float* __restrict__ bias, float* __restrict__ Y0,
    unsigned short* __restrict__ Yt, float* __restrict__ Ys,
    int M, int N, int K, int Mt, int Nt)
{
  __shared__ __align__(16) unsigned short Ab[128 * 40];
  __shared__ __align__(16) unsigned short Bb[128 * 40];
  int bid = blockIdx.x;
  int tiles = Mt * Nt;
  int bb = bid / tiles;
  int rr = bid - bb * tiles;
  int m0 = (rr / Nt) * 128;
  int n0 = (rr % Nt) * 128;
  const unsigned short* Ap = A + (size_t)bb * sA;
  const unsigned short* Bp = B + (size_t)bb * sB;

  int t = threadIdx.x;
  int lane = t & 63;
  int wm = ((t >> 7) & 1) * 64;
  int wn = ((t >> 6) & 1) * 64;
  int l15 = lane & 15, quad = lane >> 4;

  int srow = t >> 1;
  int shalf = (t & 1) * 16;
  int arow = m0 + srow; if (arow > M - 1) arow = M - 1;
  int brow = n0 + srow; if (brow > N - 1) brow = N - 1;
  const unsigned short* ap = Ap + (size_t)arow * K + shalf;
  const unsigned short* bp = Bp + (size_t)brow * K + shalf;
  unsigned short* as = &Ab[srow * 40 + shalf];
  unsigned short* bs = &Bb[srow * 40 + shalf];

  floatx4 acc[4][4] = {};

  for (int k0 = 0; k0 < K; k0 += 32) {
    uint4 a0 = *(const uint4*)(ap + k0);
    uint4 a1 = *(const uint4*)(ap + k0 + 8);
    uint4 b0 = *(const uint4*)(bp + k0);
    uint4 b1 = *(const uint4*)(bp + k0 + 8);
    __syncthreads();
    *(uint4*)as = a0; *(uint4*)(as + 8) = a1;
    *(uint4*)bs = b0; *(uint4*)(bs + 8) = b1;
    __syncthreads();
    short8 af[4], bf[4];
#pragma unroll
    for (int i = 0; i < 4; i++)
      af[i] = *(const short8*)&Ab[(wm + i * 16 + l15) * 40 + quad * 8];
#pragma unroll
    for (int j = 0; j < 4; j++)
      bf[j] = *(const short8*)&Bb[(wn + j * 16 + l15) * 40 + quad * 8];
#pragma unroll
    for (int i = 0; i < 4; i++)
#pragma unroll
      for (int j = 0; j < 4; j++)
        acc[i][j] = __builtin_amdgcn_mfma_f32_16x16x32_bf16(af[i], bf[j],
                                                            acc[i][j], 0, 0, 0);
  }

  if (EPI == 1) {
    float bn[4]; int nn[4];
#pragma unroll
    for (int j = 0; j < 4; j++) { nn[j] = n0 + wn + j * 16 + l15; bn[j] = bias[nn[j]]; }
#pragma unroll
    for (int i = 0; i < 4; i++) {
      int pixb = m0 + wm + i * 16 + quad * 4;
#pragma unroll
      for (int j = 0; j < 4; j++) {
        int n = nn[j];
        if (n < 256) {
#pragma unroll
          for (int r = 0; r < 4; r++)
            Yt[((size_t)bb * 1024 + pixb + r) * 256 + n] = f2bf(acc[i][j][r] + bn[j]);
        } else {
#pragma unroll
          for (int r = 0; r < 4; r++)
            Ys[((size_t)bb * 1024 + pixb + r) * 256 + (n - 256)] =
                siluf(acc[i][j][r] + bn[j]);
        }
      }
    }
  } else {
#pragma unroll
    for (int i = 0; i < 4; i++) {
      int m = m0 + wm + i * 16 + quad * 4;
#pragma unroll
      for (int j = 0; j < 4; j++) {
        int n = n0 + wn + j * 16 + l15;
        if (m < M && n < N) {
          float vr[4];
#pragma unroll
          for (int r = 0; r < 4; r++)
            vr[r] = acc[i][j][r] + (bias ? bias[m + r] : 0.f);
          float* yp = &Y0[((size_t)bb * M + m) * N + n];
#pragma unroll
          for (int r = 0; r < 4; r++) yp[(size_t)r * N] = vr[r];
          if (EPI == 2) {
            ushort4 o;
            o.x = f2bf(vr[0]); o.y = f2bf(vr[1]); o.z = f2bf(vr[2]); o.w = f2bf(vr[3]);
            *(ushort4*)&Yt[((size_t)bb * N + n) * M + m] = o;
          }
        }
      }
    }
  }
}

// ---------------------------------------------------------------------------
// Merged post-projection for all 4 param-sets. Body identical to old post_k.
// ---------------------------------------------------------------------------
__global__ __launch_bounds__(256) void post_all_k(
    const float* __restrict__ xd12, const float* __restrict__ xd2,
    const float* __restrict__ xd3,
    const float* __restrict__ dtw1, const float* __restrict__ dtb1,
    const float* __restrict__ dtw2, const float* __restrict__ dtb2,
    const float* __restrict__ dtw3, const float* __restrict__ dtb3,
    float* __restrict__ d1f, float* __restrict__ bc1f,
    float* __restrict__ d1b, float* __restrict__ bc1b,
    float* __restrict__ d2g, float* __restrict__ bc2,
    float* __restrict__ d3g, float* __restrict__ bc3)
{
  int bid = blockIdx.x;
  const float* xd; int bstride, L; const float *dtw, *dtb; float *dg, *bg;
  int lt, b;
  if (bid < 512) {
    int r = bid; lt = r & 63; b = r >> 6;
    xd = xd12; bstride = 80 * 1024; L = 1024; dtw = dtw1; dtb = dtb1; dg = d1f; bg = bc1f;
  } else if (bid < 1024) {
    int r = bid - 512; lt = r & 63; b = r >> 6;
    xd = xd12 + 40 * 1024; bstride = 80 * 1024; L = 1024; dtw = dtw2; dtb = dtb2; dg = d1b; bg = bc1b;
  } else if (bid < 1152) {
    int r = bid - 1024; lt = r & 15; b = r >> 4;
    xd = xd2; bstride = 40 * 256; L = 256; dtw = dtw2; dtb = dtb2; dg = d2g; bg = bc2;
  } else {
    int r = bid - 1152; lt = r & 3; b = r >> 2;
    xd = xd3; bstride = 40 * 64; L = 64; dtw = dtw3; dtb = dtb3; dg = d3g; bg = bc3;
  }
  int l0 = lt * 16;
  __shared__ float dl[8][16];
  int t = threadIdx.x;
  const float* xb = xd + (size_t)b * bstride + l0;
  if (t < 128) {
    int r = t >> 4, l = t & 15;
    dl[r][l] = xb[(size_t)r * L + l];
  } else {
    int tt = t - 128;
    int c = tt >> 2, seg = tt & 3;
    float4 v = *(const float4*)&xb[(size_t)(8 + c) * L + seg * 4];
    *(float4*)&bg[((size_t)b * 32 + c) * L + l0 + seg * 4] = v;
  }
  __syncthreads();
  int d = t;
  float dtwv[8];
#pragma unroll
  for (int r = 0; r < 8; r++) dtwv[r] = dtw[d * 8 + r];
  float dtbv = dtb[d];
  float spv[16];
#pragma unroll
  for (int l = 0; l < 16; l++) {
    float s = dtbv;
#pragma unroll
    for (int r = 0; r < 8; r++) s += dl[r][l] * dtwv[r];
    spv[l] = fmaxf(s, 0.f) + log1pf(expf(-fabsf(s)));
  }
  float* dout = dg + ((size_t)b * 256 + d) * L + l0;
#pragma unroll
  for (int i = 0; i < 4; i++)
    *(float4*)&dout[4 * i] = make_float4(spv[4 * i], spv[4 * i + 1],
                                         spv[4 * i + 2], spv[4 * i + 3]);
}

// ---------------------------------------------------------------------------
// Segment-parallel selective scan, 3 passes. dx = delta*x precomputed in LDS
// during the load phase (saves VALU in the serial chain).
// ---------------------------------------------------------------------------
#define SCAN_STEPA(DVV, DXV, BVV) {                \
    float e_ = __expf((DVV) * A);                  \
    h = h * e_ + (BVV) * (DXV);                    \
    P *= e_; }

__global__ __launch_bounds__(256) void scanA_k(
    const float* __restrict__ f1, const float* __restrict__ f2,
    const float* __restrict__ d1f, const float* __restrict__ bc1f,
    const float* __restrict__ d1b, const float* __restrict__ bc1b,
    const float* __restrict__ d2,  const float* __restrict__ bc2,
    const float* __restrict__ Al1, const float* __restrict__ Al2,
    float* __restrict__ cP, float* __restrict__ cQ)
{
  __shared__ __align__(16) float lds[48][68];   // delta[0,16) dx[16,32) B[32,48)
  int bid = blockIdx.x;
  int sid, tseg, L; const float *xin, *dlp, *bcp, *Alp;
  if (bid < 4096) {
    sid = bid >> 4; tseg = bid & 15; L = 1024; xin = f1;
    if (((sid >> 4) & 1) == 0) { dlp = d1f; bcp = bc1f; Alp = Al1; }
    else                       { dlp = d1b; bcp = bc1b; Alp = Al2; }
  } else {
    int idx = bid - 4096; sid = idx >> 2; tseg = idx & 3; L = 256;
    xin = f2; dlp = d2; bcp = bc2; Alp = Al2;
  }
  int b = sid >> 5, dir = (sid >> 4) & 1, g = sid & 15;
  int t = threadIdx.x, n = t & 15, dloc = t >> 4, d = g * 16 + dloc;
  int mbase = dir ? (L - 64 * (tseg + 1)) : 64 * tseg;

  int r0 = t >> 4, cs = t & 15;
  {
    const float* p0 = dlp + ((size_t)b * 256 + g * 16 + r0) * L + mbase;
    const float* p1 = xin + ((size_t)b * 256 + g * 16 + r0) * L + mbase;
    const float* p2 = bcp + ((size_t)b * 32 + r0) * L + mbase;
    float4 v0 = *(const float4*)(p0 + cs * 4);
    float4 v1 = *(const float4*)(p1 + cs * 4);
    float4 v2 = *(const float4*)(p2 + cs * 4);
    float4 dx = make_float4(v0.x * v1.x, v0.y * v1.y, v0.z * v1.z, v0.w * v1.w);
    *(float4*)&lds[r0][cs * 4]      = v0;
    *(float4*)&lds[16 + r0][cs * 4] = dx;
    *(float4*)&lds[32 + r0][cs * 4] = v2;
  }
  __syncthreads();

  float A = -expf(Alp[d * 16 + n]);
  float h = 0.f, P = 1.f;
  if (dir == 0) {
#pragma unroll
    for (int g4 = 0; g4 < 16; g4++) {
      int cb = 4 * g4;
      float4 dv4 = *(const float4*)&lds[dloc][cb];
      float4 dx4 = *(const float4*)&lds[16 + dloc][cb];
      float4 bv4 = *(const float4*)&lds[32 + n][cb];
      SCAN_STEPA(dv4.x, dx4.x, bv4.x);
      SCAN_STEPA(dv4.y, dx4.y, bv4.y);
      SCAN_STEPA(dv4.z, dx4.z, bv4.z);
      SCAN_STEPA(dv4.w, dx4.w, bv4.w);
    }
  } else {
#pragma unroll
    for (int g4 = 0; g4 < 16; g4++) {
      int cb = 60 - 4 * g4;
      float4 dv4 = *(const float4*)&lds[dloc][cb];
      float4 dx4 = *(const float4*)&lds[16 + dloc][cb];
      float4 bv4 = *(const float4*)&lds[32 + n][cb];
      SCAN_STEPA(dv4.w, dx4.w, bv4.w);
      SCAN_STEPA(dv4.z, dx4.z, bv4.z);
      SCAN_STEPA(dv4.y, dx4.y, bv4.y);
      SCAN_STEPA(dv4.x, dx4.x, bv4.x);
    }
  }
  cP[(size_t)bid * 256 + t] = P;
  cQ[(size_t)bid * 256 + t] = h;
}

__global__ __launch_bounds__(256) void scanB_k(float* __restrict__ cP,
                                               const float* __restrict__ cQ)
{
  int bidx = blockIdx.x, t = threadIdx.x;
  int S, base;
  if (bidx < 256) { S = 16; base = bidx * 16; }
  else            { S = 4;  base = 4096 + (bidx - 256) * 4; }
  float h = 0.f;
  for (int s = 0; s < S; s++) {
    size_t off = (size_t)(base + s) * 256 + t;
    float p = cP[off], q = cQ[off];
    cP[off] = h;
    h = p * h + q;
  }
}

#define SCAN_STEPY(DVV, DXV, BVV, CVV, COL) {      \
    float e_ = __expf((DVV) * A);                  \
    h = h * e_ + (BVV) * (DXV);                    \
    float pp_ = h * (CVV);                         \
    pp_ = ror_add<1>(pp_);                         \
    pp_ = ror_add<2>(pp_);                         \
    pp_ = ror_add<4>(pp_);                         \
    pp_ = ror_add<8>(pp_);                         \
    ysel = (((COL) & 15) == n) ? pp_ : ysel; }

__global__ __launch_bounds__(256) void scanC_k(
    const float* __restrict__ f1, const float* __restrict__ f2, const float* __restrict__ f3,
    const float* __restrict__ d1f, const float* __restrict__ bc1f,
    const float* __restrict__ d1b, const float* __restrict__ bc1b,
    const float* __restrict__ d2,  const float* __restrict__ bc2,
    const float* __restrict__ d3,  const float* __restrict__ bc3,
    float* __restrict__ y1f, float* __restrict__ y1b,
    float* __restrict__ y2f, float* __restrict__ y2b,
    float* __restrict__ y3f, float* __restrict__ y3b,
    const float* __restrict__ Al1, const float* __restrict__ Dv1,
    const float* __restrict__ Al2, const float* __restrict__ Dv2,
    const float* __restrict__ Al3, const float* __restrict__ Dv3,
    const float* __restrict__ cP)
{
  // rows: delta[0,16) dx[16,32) x[32,48) B[48,64) C[64,80)
  __shared__ __align__(16) float lds[80][68];
  int bid = blockIdx.x;
  int sid, tseg, L, slot; const float *xin, *dlp, *bcp, *Alp, *Dvp; float* yo;
  if (bid < 4096) {
    sid = bid >> 4; tseg = bid & 15; slot = bid; L = 1024; xin = f1;
    if (((sid >> 4) & 1) == 0) { dlp = d1f; bcp = bc1f; Alp = Al1; Dvp = Dv1; yo = y1f; }
    else                       { dlp = d1b; bcp = bc1b; Alp = Al2; Dvp = Dv2; yo = y1b; }
  } else if (bid < 5120) {
    int idx = bid - 4096; sid = idx >> 2; tseg = idx & 3; slot = bid; L = 256;
    xin = f2; dlp = d2; bcp = bc2; Alp = Al2; Dvp = Dv2;
    yo = ((sid >> 4) & 1) ? y2b : y2f;
  } else {
    sid = bid - 5120; tseg = 0; slot = -1; L = 64;
    xin = f3; dlp = d3; bcp = bc3; Alp = Al3; Dvp = Dv3;
    yo = ((sid >> 4) & 1) ? y3b : y3f;
  }
  int b = sid >> 5, dir = (sid >> 4) & 1, g = sid & 15;
  int t = threadIdx.x, n = t & 15, dloc = t >> 4, d = g * 16 + dloc;
  int mbase = dir ? (L - 64 * (tseg + 1)) : 64 * tseg;

  int r0 = t >> 4, cs = t & 15;
  {
    const float* p0 = dlp + ((size_t)b * 256 + g * 16 + r0) * L + mbase;
    const float* p1 = xin + ((size_t)b * 256 + g * 16 + r0) * L + mbase;
    const float* p2 = bcp + ((size_t)b * 32 + r0) * L + mbase;
    const float* p3 = bcp + ((size_t)b * 32 + 16 + r0) * L + mbase;
    float4 v0 = *(const float4*)(p0 + cs * 4);
    float4 v1 = *(const float4*)(p1 + cs * 4);
    float4 v2 = *(const float4*)(p2 + cs * 4);
    float4 v3 = *(const float4*)(p3 + cs * 4);
    float4 dx = make_float4(v0.x * v1.x, v0.y * v1.y, v0.z * v1.z, v0.w * v1.w);
    *(float4*)&lds[r0][cs * 4]      = v0;
    *(float4*)&lds[16 + r0][cs * 4] = dx;
    *(float4*)&lds[32 + r0][cs * 4] = v1;
    *(float4*)&lds[48 + r0][cs * 4] = v2;
    *(float4*)&lds[64 + r0][cs * 4] = v3;
  }
  float A   = -expf(Alp[d * 16 + n]);
  float Dvv = Dvp[d];
  float h = (slot >= 0) ? cP[(size_t)slot * 256 + t] : 0.f;
  __syncthreads();

  float* ybase = yo + ((size_t)b * L + mbase) * 256 + d;
#pragma unroll
  for (int jj0 = 0; jj0 < 64; jj0 += 16) {
    float ysel = 0.f;
    if (dir == 0) {
#pragma unroll
      for (int g4 = 0; g4 < 4; g4++) {
        int cb = jj0 + 4 * g4;
        float4 dv4 = *(const float4*)&lds[dloc][cb];
        float4 dx4 = *(const float4*)&lds[16 + dloc][cb];
        float4 bv4 = *(const float4*)&lds[48 + n][cb];
        float4 cv4 = *(const float4*)&lds[64 + n][cb];
        SCAN_STEPY(dv4.x, dx4.x, bv4.x, cv4.x, cb + 0);
        SCAN_STEPY(dv4.y, dx4.y, bv4.y, cv4.y, cb + 1);
        SCAN_STEPY(dv4.z, dx4.z, bv4.z, cv4.z, cb + 2);
        SCAN_STEPY(dv4.w, dx4.w, bv4.w, cv4.w, cb + 3);
      }
    } else {
#pragma unroll
      for (int g4 = 0; g4 < 4; g4++) {
        int cb = 60 - jj0 - 4 * g4;
        float4 dv4 = *(const float4*)&lds[dloc][cb];
        float4 dx4 = *(const float4*)&lds[16 + dloc][cb];
        float4 bv4 = *(const float4*)&lds[48 + n][cb];
        float4 cv4 = *(const float4*)&lds[64 + n][cb];
        SCAN_STEPY(dv4.w, dx4.w, bv4.w, cv4.w, cb + 3);
        SCAN_STEPY(dv4.z, dx4.z, bv4.z, cv4.z, cb + 2);
        SCAN_STEPY(dv4.y, dx4.y, bv4.y, cv4.y, cb + 1);
        SCAN_STEPY(dv4.x, dx4.x, bv4.x, cv4.x, cb + 0);
      }
    }
    int colbase = dir ? 48 - jj0 : jj0;
    float xsel = lds[32 + dloc][colbase + n];        // x at the selected col
    ybase[(size_t)(colbase + n) * 256] = ysel + xsel * Dvv;
  }
}

// ---------------------------------------------------------------------------
// LayerNorm(fwd)+LayerNorm(bwd) + optional upsample add + optional *szT.
// ---------------------------------------------------------------------------
template <int OUTBF>
__global__ __launch_bounds__(256) void ln_combine(
    const float* __restrict__ yf, const float* __restrict__ yb,
    const float* __restrict__ gf, const float* __restrict__ bef,
    const float* __restrict__ gb, const float* __restrict__ beb,
    const float* __restrict__ up, int Wc,
    const float* __restrict__ szT, void* __restrict__ outv,
    int L, int Wf)
{
  int bid = blockIdx.x;
  int b = bid / L;
  int l = bid - b * L;
  int d = threadIdx.x;
  size_t base = ((size_t)b * L + l) * 256 + d;
  float vf = yf[base], vb = yb[base];
  float4 s = make_float4(vf, vf * vf, vb, vb * vb);
#pragma unroll
  for (int m = 1; m < 64; m <<= 1) {
    s.x += __shfl_xor(s.x, m);
    s.y += __shfl_xor(s.y, m);
    s.z += __shfl_xor(s.z, m);
    s.w += __shfl_xor(s.w, m);
  }
  __shared__ float red[4][4];
  int w = threadIdx.x >> 6;
  if ((threadIdx.x & 63) == 0) {
    red[w][0] = s.x; red[w][1] = s.y; red[w][2] = s.z; red[w][3] = s.w;
  }
  __syncthreads();
  float s0 = red[0][0] + red[1][0] + red[2][0] + red[3][0];
  float s1 = red[0][1] + red[1][1] + red[2][1] + red[3][1];
  float s2 = red[0][2] + red[1][2] + red[2][2] + red[3][2];
  float s3 = red[0][3] + red[1][3] + red[2][3] + red[3][3];
  const float inv = 1.f / 256.f;
  float muf = s0 * inv, varf = s1 * inv - muf * muf;
  float mub = s2 * inv, varb = s3 * inv - mub * mub;
  float rf = rsqrtf(varf + 1e-5f);
  float rb = rsqrtf(varb + 1e-5f);
  float v = (vf - muf) * rf * gf[d] + bef[d] + (vb - mub) * rb * gb[d] + beb[d];
  if (up) {
    int y = l / Wf, x = l - y * Wf;
    int lc = (y >> 1) * Wc + (x >> 1);
    v += up[((size_t)b * (L >> 2) + lc) * 256 + d];
  }
  if (szT) v *= szT[base];
  if (OUTBF) ((unsigned short*)outv)[base] = f2bf(v);
  else       ((float*)outv)[base] = v;
}

// ---------------------------------------------------------------------------
extern "C" void kernel_launch(void* const* d_in, const int* in_sizes, int n_in,
                              void* d_out, int out_size, void* d_ws, size_t ws_size,
                              hipStream_t stream) {
  (void)in_sizes; (void)n_in; (void)out_size; (void)ws_size;
  const float* input_f = (const float*)d_in[0];
  const float* in_w  = (const float*)d_in[1];
  const float* in_b  = (const float*)d_in[2];
  const float* c1_w  = (const float*)d_in[3];
  const float* c1_b  = (const float*)d_in[4];
  const float* c2_w  = (const float*)d_in[5];
  const float* c2_b  = (const float*)d_in[6];
  const float* c3_w  = (const float*)d_in[7];
  const float* c3_b  = (const float*)d_in[8];
  const float* out_w = (const float*)d_in[9];
  const float* out_b = (const float*)d_in[10];
  const float* xw1  = (const float*)d_in[11];
  const float* dtw1 = (const float*)d_in[12];
  const float* dtb1 = (const float*)d_in[13];
  const float* Al1  = (const float*)d_in[14];
  const float* Dv1  = (const float*)d_in[15];
  const float* g1   = (const float*)d_in[16];
  const float* be1  = (const float*)d_in[17];
  const float* xw2  = (const float*)d_in[18];
  const float* dtw2 = (const float*)d_in[19];
  const float* dtb2 = (const float*)d_in[20];
  const float* Al2  = (const float*)d_in[21];
  const float* Dv2  = (const float*)d_in[22];
  const float* g2   = (const float*)d_in[23];
  const float* be2  = (const float*)d_in[24];
  const float* xw3  = (const float*)d_in[25];
  const float* dtw3 = (const float*)d_in[26];
  const float* dtb3 = (const float*)d_in[27];
  const float* Al3  = (const float*)d_in[28];
  const float* Dv3  = (const float*)d_in[29];
  const float* g3   = (const float*)d_in[30];
  const float* be3  = (const float*)d_in[31];

  float* ws = (float*)d_ws;
  constexpr size_t M1 = 2097152;   // 8*256*1024 floats = 8 MB
  // Region map (float offsets); lifetimes verified against launch order:
  float* d1f = ws;                                      // R0
  unsigned short* xt = (unsigned short*)(ws + M1);      // R1 (dead after c1)
  float* y1f = ws + M1;                                 // R1 (after xt dead)
  float* szT = ws + 2 * M1;                             // R2
  float* f1  = ws + 3 * M1;                             // R3
  unsigned short* G = (unsigned short*)(ws + 3 * M1);   // R3 (after f1 dead)
  float* d1b = ws + 4 * M1;                             // R4
  unsigned short* inT = (unsigned short*)(ws + 5 * M1); // R5 bytes [0,8MB)
  unsigned short* ic2 = inT;                            // R5 [0,4MB) after inT dead
  unsigned short* f1t = inT + 2097152;                  // R5 [4,8MB) after inT dead
  unsigned short* ic3 = f1t;                            // R5 [4,8MB) after f1t dead
  float* y1b = ws + 5 * M1;                             // R5 (after ic2/ic3 dead)
  size_t o = 6 * M1;
  float* f2   = ws + o; o += 524288;
  float* f3   = ws + o; o += 131072;
  float* bc1f = ws + o; o += 262144;
  float* bc1b = ws + o; o += 262144;
  float* d2   = ws + o; o += 524288;
  float* bc2  = ws + o; o += 65536;
  float* d3   = ws + o; o += 131072;
  float* bc3  = ws + o; o += 16384;
  float* y2f  = ws + o; o += 524288;
  float* y2b  = ws + o; o += 524288;
  float* y3f  = ws + o; o += 131072;
  float* y3b  = ws + o; o += 131072;
  float* y3c  = ws + o; o += 131072;
  float* y2c  = ws + o; o += 524288;
  float* cP   = ws + o; o += 1310720;
  float* cQ   = ws + o; o += 1310720;
  unsigned short* wsW = (unsigned short*)(ws + o); o += 506880;
  // xd buffers alias cP (dead before scanA writes cP):
  float* xd12 = cP;                 // (b,80,1024)
  float* xd2  = cP + 655360;        // (b,40,256)
  float* xd3  = cP + 737280;        // (b,40,64)
  // pixel-major bf16 f2/f3 alias cQ (dead before scanA writes cQ):
  unsigned short* f2t = (unsigned short*)cQ;            // (b,256,256)
  unsigned short* f3t = (unsigned short*)(cQ + 262144); // (b,64,256)
  // bf16 weight sub-pointers:
  unsigned short* w_in   = wsW;
  unsigned short* w_c1   = wsW + 262144;
  unsigned short* w_c2   = wsW + 327680;   // k-reordered
  unsigned short* w_c3   = wsW + 589824;   // k-reordered
  unsigned short* w_out  = wsW + 851968;
  unsigned short* w_xw12 = wsW + 983040;   // [xw1;xw2] stacked (80x256)
  unsigned short* w_xw2  = wsW + 993280;
  unsigned short* w_xw3  = wsW + 1003520;

  dim3 blk(256);

  // 1. weights -> bf16 (c2/c3 k-reordered)
  cvt_w_k<<<dim3(3960), blk, 0, stream>>>(in_w, c1_w, c2_w, c3_w, out_w,
                                          xw1, xw2, xw3, wsW);
  // 2. input_f -> inT bf16 (b,1024,512)
  tcvt_k<<<dim3(512, 8), blk, 0, stream>>>(input_f, inT, 512, 1024);
  // 3. in-proj (pixels as M-operand): -> xt bf16 (b,p,256) + szT fp32 (b,p,256)
  mgemm_k<1><<<dim3(256), blk, 0, stream>>>(inT, 1024 * 512, w_in, 0, in_b,
                                            nullptr, xt, szT, 1024, 512, 512, 8, 4);
  // 4. c1 (dual): f1 fp32 (b,256,1024) + f1t bf16 (b,1024,256)
  mgemm_k<2><<<dim3(128), blk, 0, stream>>>(w_c1, 0, xt, 1024 * 256, c1_b,
                                            f1, f1t, nullptr, 256, 1024, 256, 2, 8);
  // 5. xd12 GEMM (input f1t = c1 output, pixel-major)
  mgemm_k<0><<<dim3(64), blk, 0, stream>>>(w_xw12, 0, f1t, 1024 * 256, nullptr,
                                           xd12, nullptr, nullptr, 80, 1024, 256, 1, 8);
  // 6. im2col2 from f1t (k = ij*256+c) -> ic2; f1t dead after
  im2col2_k<<<dim3(1024), blk, 0, stream>>>(f1t, ic2);
  // 7. c2 (dual): f2 fp32 + f2t bf16 pixel-major
  mgemm_k<2><<<dim3(32), blk, 0, stream>>>(w_c2, 0, ic2, 256 * 1024, c2_b,
                                           f2, f2t, nullptr, 256, 256, 1024, 2, 2);
  // 8. im2col3 from f2t -> ic3 (overwrites dead f1t)
  im2col3_k<<<dim3(256), blk, 0, stream>>>(f2t, ic3);
  // 9. c3 (dual): f3 fp32 + f3t bf16 pixel-major
  mgemm_k<2><<<dim3(16), blk, 0, stream>>>(w_c3, 0, ic3, 64 * 1024, c3_b,
                                           f3, f3t, nullptr, 256, 64, 1024, 2, 1);
  // 10-11. xd2 / xd3 GEMMs
  mgemm_k<0><<<dim3(16), blk, 0, stream>>>(w_xw2, 0, f2t, 256 * 256, nullptr,
                                           xd2, nullptr, nullptr, 40, 256, 256, 1, 2);
  mgemm_k<0><<<dim3(8), blk, 0, stream>>>(w_xw3, 0, f3t, 64 * 256, nullptr,
                                          xd3, nullptr, nullptr, 40, 64, 256, 1, 1);
  // 12. merged delta/softplus + B/C repack (all 4 param-sets)
  post_all_k<<<dim3(1184), blk, 0, stream>>>(xd12, xd2, xd3,
                                             dtw1, dtb1, dtw2, dtb2, dtw3, dtb3,
                                             d1f, bc1f, d1b, bc1b, d2, bc2, d3, bc3);
  // 13-15. segment-parallel scan
  scanA_k<<<dim3(5120), blk, 0, stream>>>(f1, f2, d1f, bc1f, d1b, bc1b,
                                          d2, bc2, Al1, Al2, cP, cQ);
  scanB_k<<<dim3(512), blk, 0, stream>>>(cP, cQ);
  scanC_k<<<dim3(5376), blk, 0, stream>>>(f1, f2, f3,
                                          d1f, bc1f, d1b, bc1b, d2, bc2, d3, bc3,
                                          y1f, y1b, y2f, y2b, y3f, y3b,
                                          Al1, Dv1, Al2, Dv2, Al3, Dv3, cP);
  // 16-18. LN + combine (level 1 writes bf16 G)
  ln_combine<0><<<dim3(512), blk, 0, stream>>>(y3f, y3b, g3, be3, g3, be3,
                                               nullptr, 0, nullptr, y3c, 64, 8);
  ln_combine<0><<<dim3(2048), blk, 0, stream>>>(y2f, y2b, g2, be2, g2, be2,
                                                y3c, 8, nullptr, y2c, 256, 16);
  ln_combine<1><<<dim3(8192), blk, 0, stream>>>(y1f, y1b, g1, be1, g2, be2,
                                                y2c, 16, szT, G, 1024, 32);
  // 19. out-proj -> d_out fp32 (b,512,1024)
  mgemm_k<0><<<dim3(256), blk, 0, stream>>>(w_out, 0, G, 1024 * 256, out_b,
                                            (float*)d_out, nullptr, nullptr,
                                            512, 1024, 256, 4, 8);
}

// Round 9
// 377.274 us; speedup vs baseline: 2.6289x; 1.0264x over previous
//
#include <hip/hip_runtime.h>
#include <cstddef>

#define DEV static __device__ __forceinline__

typedef __attribute__((ext_vector_type(8))) short short8;
typedef __attribute__((ext_vector_type(4))) float floatx4;

DEV float siluf(float v) { return v / (1.f + expf(-v)); }

DEV unsigned short f2bf(float f) {             // RNE fp32 -> bf16
  unsigned int u = __float_as_uint(f);
  u += 0x7fff + ((u >> 16) & 1);
  return (unsigned short)(u >> 16);
}
DEV float bf2f(unsigned short u) {
  return __uint_as_float(((unsigned int)u) << 16);
}
DEV float4 bf2f4(ushort4 v) {
  return make_float4(bf2f(v.x), bf2f(v.y), bf2f(v.z), bf2f(v.w));
}

// DPP row-rotate add: sums within each 16-lane row after amounts 1,2,4,8.
template <int AMT>
DEV float ror_add(float v) {
  int s = __builtin_amdgcn_update_dpp(0, __float_as_int(v), 0x120 | AMT, 0xF, 0xF, false);
  return v + __int_as_float(s);
}

// ---------------------------------------------------------------------------
// prep_k: [0,3960) weight fp32->bf16 (c2/c3 k-reordered: k = ij*256+c);
//         [3960,8056) transpose-convert input_f -> inT bf16 (b,1024,512).
// ---------------------------------------------------------------------------
__global__ __launch_bounds__(256) void prep_k(
    const float* __restrict__ in_w, const float* __restrict__ c1_w,
    const float* __restrict__ c2_w, const float* __restrict__ c3_w,
    const float* __restrict__ out_w, const float* __restrict__ xw1,
    const float* __restrict__ xw2, const float* __restrict__ xw3,
    unsigned short* __restrict__ wsW,
    const float* __restrict__ input_f, unsigned short* __restrict__ inT)
{
  __shared__ float tile[32][33];
  int bid = blockIdx.x;
  int t = threadIdx.x;
  if (bid < 3960) {
    int gid = bid * 256 + t;
    float v;
    if      (gid < 262144)  v = in_w[gid];
    else if (gid < 327680)  v = c1_w[gid - 262144];
    else if (gid < 589824)  {
      int off = gid - 327680;
      int o = off >> 10, kk = off & 1023, ij = kk >> 8, c = kk & 255;
      v = c2_w[o * 1024 + c * 4 + ij];
    }
    else if (gid < 851968)  {
      int off = gid - 589824;
      int o = off >> 10, kk = off & 1023, ij = kk >> 8, c = kk & 255;
      v = c3_w[o * 1024 + c * 4 + ij];
    }
    else if (gid < 983040)  v = out_w[gid - 851968];
    else if (gid < 993280)  v = xw1[gid - 983040];
    else if (gid < 1003520) v = xw2[gid - 993280];
    else                    v = xw3[gid - 1003520];
    wsW[gid] = f2bf(v);
  } else {
    int idx = bid - 3960;              // < 4096
    int b = idx >> 9, blk = idx & 511;
    int pt = blk & 31, ct = blk >> 5;  // L=1024 -> 32 p-tiles; C=512 -> 16 c-tiles
    int p0 = pt * 32, c0 = ct * 32;
    int r = t >> 5, cc = t & 31;
#pragma unroll
    for (int i = 0; i < 4; i++) {
      int row = r + 8 * i;
      tile[row][cc] = input_f[((size_t)b * 512 + c0 + row) * 1024 + p0 + cc];
    }
    __syncthreads();
#pragma unroll
    for (int i = 0; i < 4; i++) {
      int row = r + 8 * i;
      inT[((size_t)b * 1024 + p0 + row) * 512 + c0 + cc] = f2bf(tile[cc][row]);
    }
  }
}

// ---------------------------------------------------------------------------
// bf16 MFMA GEMM body: Y[m,n] = sum_k A[bb*sA+m*K+k] * B[bb*sB+n*K+k].
// 128x128 tile / 4 waves / 4x4 mfma_16x16x32_bf16. Rows clamped, stores guarded.
// EPI=0: O1 = fp32 Y0 (b,M,N), bias[m] (nullable).
// EPI=1: in-proj (M=1024 pix, N=512 ch), bias[n]:
//        n<256 -> O1 bf16 [(b*1024+m)*256+n]; n>=256 -> O2 bf16 silu.
// EPI=3: O1 bf16 (b,M,N) n-contig + O2 bf16 transposed [(b*N+n)*M+m], bias[m].
// ---------------------------------------------------------------------------
template <int EPI>
DEV void mgemm_body(const unsigned short* __restrict__ A, long long sA,
                    const unsigned short* __restrict__ B, long long sB,
                    const float* __restrict__ bias,
                    void* __restrict__ O1, void* __restrict__ O2,
                    int M, int N, int K, int Mt, int Nt, int bid)
{
  __shared__ __align__(16) unsigned short Ab[128 * 40];
  __shared__ __align__(16) unsigned short Bb[128 * 40];
  int tiles = Mt * Nt;
  int bb = bid / tiles;
  int rr = bid - bb * tiles;
  int m0 = (rr / Nt) * 128;
  int n0 = (rr % Nt) * 128;
  const unsigned short* Ap = A + (size_t)bb * sA;
  const unsigned short* Bp = B + (size_t)bb * sB;

  int t = threadIdx.x;
  int lane = t & 63;
  int wm = ((t >> 7) & 1) * 64;
  int wn = ((t >> 6) & 1) * 64;
  int l15 = lane & 15, quad = lane >> 4;

  int srow = t >> 1;
  int shalf = (t & 1) * 16;
  int arow = m0 + srow; if (arow > M - 1) arow = M - 1;
  int brow = n0 + srow; if (brow > N - 1) brow = N - 1;
  const unsigned short* ap = Ap + (size_t)arow * K + shalf;
  const unsigned short* bp = Bp + (size_t)brow * K + shalf;
  unsigned short* as = &Ab[srow * 40 + shalf];
  unsigned short* bs = &Bb[srow * 40 + shalf];

  floatx4 acc[4][4] = {};

  for (int k0 = 0; k0 < K; k0 += 32) {
    uint4 a0 = *(const uint4*)(ap + k0);
    uint4 a1 = *(const uint4*)(ap + k0 + 8);
    uint4 b0 = *(const uint4*)(bp + k0);
    uint4 b1 = *(const uint4*)(bp + k0 + 8);
    __syncthreads();
    *(uint4*)as = a0; *(uint4*)(as + 8) = a1;
    *(uint4*)bs = b0; *(uint4*)(bs + 8) = b1;
    __syncthreads();
    short8 af[4], bf[4];
#pragma unroll
    for (int i = 0; i < 4; i++)
      af[i] = *(const short8*)&Ab[(wm + i * 16 + l15) * 40 + quad * 8];
#pragma unroll
    for (int j = 0; j < 4; j++)
      bf[j] = *(const short8*)&Bb[(wn + j * 16 + l15) * 40 + quad * 8];
#pragma unroll
    for (int i = 0; i < 4; i++)
#pragma unroll
      for (int j = 0; j < 4; j++)
        acc[i][j] = __builtin_amdgcn_mfma_f32_16x16x32_bf16(af[i], bf[j],
                                                            acc[i][j], 0, 0, 0);
  }

  if (EPI == 1) {
    unsigned short* Yt = (unsigned short*)O1;
    unsigned short* Ys = (unsigned short*)O2;
    float bn[4]; int nn[4];
#pragma unroll
    for (int j = 0; j < 4; j++) { nn[j] = n0 + wn + j * 16 + l15; bn[j] = bias[nn[j]]; }
#pragma unroll
    for (int i = 0; i < 4; i++) {
      int pixb = m0 + wm + i * 16 + quad * 4;
#pragma unroll
      for (int j = 0; j < 4; j++) {
        int n = nn[j];
        if (n < 256) {
#pragma unroll
          for (int r = 0; r < 4; r++)
            Yt[((size_t)bb * 1024 + pixb + r) * 256 + n] = f2bf(acc[i][j][r] + bn[j]);
        } else {
#pragma unroll
          for (int r = 0; r < 4; r++)
            Ys[((size_t)bb * 1024 + pixb + r) * 256 + (n - 256)] =
                f2bf(siluf(acc[i][j][r] + bn[j]));
        }
      }
    }
  } else {
#pragma unroll
    for (int i = 0; i < 4; i++) {
      int m = m0 + wm + i * 16 + quad * 4;
#pragma unroll
      for (int j = 0; j < 4; j++) {
        int n = n0 + wn + j * 16 + l15;
        if (m < M && n < N) {
          float vr[4];
#pragma unroll
          for (int r = 0; r < 4; r++)
            vr[r] = acc[i][j][r] + (bias ? bias[m + r] : 0.f);
          if (EPI == 0) {
            float* Y0 = (float*)O1;
            float* yp = &Y0[((size_t)bb * M + m) * N + n];
#pragma unroll
            for (int r = 0; r < 4; r++) yp[(size_t)r * N] = vr[r];
          } else {           // EPI == 3
            unsigned short* Y0b = (unsigned short*)O1;
            unsigned short* Yt  = (unsigned short*)O2;
#pragma unroll
            for (int r = 0; r < 4; r++)
              Y0b[((size_t)bb * M + m + r) * N + n] = f2bf(vr[r]);
            ushort4 o;
            o.x = f2bf(vr[0]); o.y = f2bf(vr[1]); o.z = f2bf(vr[2]); o.w = f2bf(vr[3]);
            *(ushort4*)&Yt[((size_t)bb * N + n) * M + m] = o;
          }
        }
      }
    }
  }
}

template <int EPI>
__global__ __launch_bounds__(256) void mgemm_k(
    const unsigned short* __restrict__ A, long long sA,
    const unsigned short* __restrict__ B, long long sB,
    const float* __restrict__ bias, void* __restrict__ O1, void* __restrict__ O2,
    int M, int N, int K, int Mt, int Nt)
{
  mgemm_body<EPI>(A, sA, B, sB, bias, O1, O2, M, N, K, Mt, Nt, blockIdx.x);
}

// ---------------------------------------------------------------------------
// fat1: bid<64 -> xd12 GEMM (M=80,N=1024,K=256); else im2col2 from f1t.
// fat2: bid<16 -> xd2 GEMM (M=40,N=256,K=256); else im2col3 from f2t.
// ---------------------------------------------------------------------------
__global__ __launch_bounds__(256) void fat1_k(
    const unsigned short* __restrict__ w_xw12, const unsigned short* __restrict__ f1t,
    float* __restrict__ xd12, unsigned short* __restrict__ ic2)
{
  int bid = blockIdx.x;
  if (bid < 64) {
    mgemm_body<0>(w_xw12, 0, f1t, 1024 * 256, nullptr, xd12, nullptr,
                  80, 1024, 256, 1, 8, bid);
  } else {
    int idx = (bid - 64) * 256 + threadIdx.x;   // 262144
    int cs = idx & 31, ij = (idx >> 5) & 3, n = (idx >> 7) & 255, b = idx >> 15;
    int i = ij >> 1, j = ij & 1;
    int y = n >> 4, x = n & 15;
    int pix = (2 * y + i) * 32 + 2 * x + j;
    uint4 v = *(const uint4*)&f1t[((size_t)b * 1024 + pix) * 256 + cs * 8];
    *(uint4*)&ic2[((size_t)b * 256 + n) * 1024 + ij * 256 + cs * 8] = v;
  }
}

__global__ __launch_bounds__(256) void fat2_k(
    const unsigned short* __restrict__ w_xw2, const unsigned short* __restrict__ f2t,
    float* __restrict__ xd2, unsigned short* __restrict__ ic3)
{
  int bid = blockIdx.x;
  if (bid < 16) {
    mgemm_body<0>(w_xw2, 0, f2t, 256 * 256, nullptr, xd2, nullptr,
                  40, 256, 256, 1, 2, bid);
  } else {
    int idx = (bid - 16) * 256 + threadIdx.x;   // 65536
    int cs = idx & 31, ij = (idx >> 5) & 3, n = (idx >> 7) & 63, b = idx >> 13;
    int i = ij >> 1, j = ij & 1;
    int y = n >> 3, x = n & 7;
    int pix = (2 * y + i) * 16 + 2 * x + j;
    uint4 v = *(const uint4*)&f2t[((size_t)b * 256 + pix) * 256 + cs * 8];
    *(uint4*)&ic3[((size_t)b * 64 + n) * 1024 + ij * 256 + cs * 8] = v;
  }
}

// ---------------------------------------------------------------------------
// Merged post-projection for all 4 param-sets (unchanged from round 8).
// ---------------------------------------------------------------------------
__global__ __launch_bounds__(256) void post_all_k(
    const float* __restrict__ xd12, const float* __restrict__ xd2,
    const float* __restrict__ xd3,
    const float* __restrict__ dtw1, const float* __restrict__ dtb1,
    const float* __restrict__ dtw2, const float* __restrict__ dtb2,
    const float* __restrict__ dtw3, const float* __restrict__ dtb3,
    float* __restrict__ d1f, float* __restrict__ bc1f,
    float* __restrict__ d1b, float* __restrict__ bc1b,
    float* __restrict__ d2g, float* __restrict__ bc2,
    float* __restrict__ d3g, float* __restrict__ bc3)
{
  int bid = blockIdx.x;
  const float* xd; int bstride, L; const float *dtw, *dtb; float *dg, *bg;
  int lt, b;
  if (bid < 512) {
    int r = bid; lt = r & 63; b = r >> 6;
    xd = xd12; bstride = 80 * 1024; L = 1024; dtw = dtw1; dtb = dtb1; dg = d1f; bg = bc1f;
  } else if (bid < 1024) {
    int r = bid - 512; lt = r & 63; b = r >> 6;
    xd = xd12 + 40 * 1024; bstride = 80 * 1024; L = 1024; dtw = dtw2; dtb = dtb2; dg = d1b; bg = bc1b;
  } else if (bid < 1152) {
    int r = bid - 1024; lt = r & 15; b = r >> 4;
    xd = xd2; bstride = 40 * 256; L = 256; dtw = dtw2; dtb = dtb2; dg = d2g; bg = bc2;
  } else {
    int r = bid - 1152; lt = r & 3; b = r >> 2;
    xd = xd3; bstride = 40 * 64; L = 64; dtw = dtw3; dtb = dtb3; dg = d3g; bg = bc3;
  }
  int l0 = lt * 16;
  __shared__ float dl[8][16];
  int t = threadIdx.x;
  const float* xb = xd + (size_t)b * bstride + l0;
  if (t < 128) {
    int r = t >> 4, l = t & 15;
    dl[r][l] = xb[(size_t)r * L + l];
  } else {
    int tt = t - 128;
    int c = tt >> 2, seg = tt & 3;
    float4 v = *(const float4*)&xb[(size_t)(8 + c) * L + seg * 4];
    *(float4*)&bg[((size_t)b * 32 + c) * L + l0 + seg * 4] = v;
  }
  __syncthreads();
  int d = t;
  float dtwv[8];
#pragma unroll
  for (int r = 0; r < 8; r++) dtwv[r] = dtw[d * 8 + r];
  float dtbv = dtb[d];
  float spv[16];
#pragma unroll
  for (int l = 0; l < 16; l++) {
    float s = dtbv;
#pragma unroll
    for (int r = 0; r < 8; r++) s += dl[r][l] * dtwv[r];
    spv[l] = fmaxf(s, 0.f) + log1pf(expf(-fabsf(s)));
  }
  float* dout = dg + ((size_t)b * 256 + d) * L + l0;
#pragma unroll
  for (int i = 0; i < 4; i++)
    *(float4*)&dout[4 * i] = make_float4(spv[4 * i], spv[4 * i + 1],
                                         spv[4 * i + 2], spv[4 * i + 3]);
}

// ---------------------------------------------------------------------------
// Segment-parallel selective scan. x streams are bf16; dx = delta*x built at
// load. scanC does its own carry lookback (scanB eliminated).
// ---------------------------------------------------------------------------
#define SCAN_STEPA(DVV, DXV, BVV) {                \
    float e_ = __expf((DVV) * A);                  \
    h = h * e_ + (BVV) * (DXV);                    \
    P *= e_; }

__global__ __launch_bounds__(256) void scanA_k(
    const unsigned short* __restrict__ f1b, const unsigned short* __restrict__ f2b,
    const float* __restrict__ d1f, const float* __restrict__ bc1f,
    const float* __restrict__ d1b, const float* __restrict__ bc1b,
    const float* __restrict__ d2,  const float* __restrict__ bc2,
    const float* __restrict__ Al1, const float* __restrict__ Al2,
    float* __restrict__ cP, float* __restrict__ cQ)
{
  __shared__ __align__(16) float lds[48][68];   // delta[0,16) dx[16,32) B[32,48)
  int bid = blockIdx.x;
  int sid, tseg, L; const unsigned short* xin; const float *dlp, *bcp, *Alp;
  if (bid < 4096) {
    sid = bid >> 4; tseg = bid & 15; L = 1024; xin = f1b;
    if (((sid >> 4) & 1) == 0) { dlp = d1f; bcp = bc1f; Alp = Al1; }
    else                       { dlp = d1b; bcp = bc1b; Alp = Al2; }
  } else {
    int idx = bid - 4096; sid = idx >> 2; tseg = idx & 3; L = 256;
    xin = f2b; dlp = d2; bcp = bc2; Alp = Al2;
  }
  int b = sid >> 5, dir = (sid >> 4) & 1, g = sid & 15;
  int t = threadIdx.x, n = t & 15, dloc = t >> 4, d = g * 16 + dloc;
  int mbase = dir ? (L - 64 * (tseg + 1)) : 64 * tseg;

  int r0 = t >> 4, cs = t & 15;
  {
    const float* p0 = dlp + ((size_t)b * 256 + g * 16 + r0) * L + mbase;
    const unsigned short* p1 = xin + ((size_t)b * 256 + g * 16 + r0) * L + mbase;
    const float* p2 = bcp + ((size_t)b * 32 + r0) * L + mbase;
    float4 v0 = *(const float4*)(p0 + cs * 4);
    float4 xf = bf2f4(*(const ushort4*)(p1 + cs * 4));
    float4 v2 = *(const float4*)(p2 + cs * 4);
    float4 dx = make_float4(v0.x * xf.x, v0.y * xf.y, v0.z * xf.z, v0.w * xf.w);
    *(float4*)&lds[r0][cs * 4]      = v0;
    *(float4*)&lds[16 + r0][cs * 4] = dx;
    *(float4*)&lds[32 + r0][cs * 4] = v2;
  }
  __syncthreads();

  float A = -expf(Alp[d * 16 + n]);
  float h = 0.f, P = 1.f;
  if (dir == 0) {
#pragma unroll
    for (int g4 = 0; g4 < 16; g4++) {
      int cb = 4 * g4;
      float4 dv4 = *(const float4*)&lds[dloc][cb];
      float4 dx4 = *(const float4*)&lds[16 + dloc][cb];
      float4 bv4 = *(const float4*)&lds[32 + n][cb];
      SCAN_STEPA(dv4.x, dx4.x, bv4.x);
      SCAN_STEPA(dv4.y, dx4.y, bv4.y);
      SCAN_STEPA(dv4.z, dx4.z, bv4.z);
      SCAN_STEPA(dv4.w, dx4.w, bv4.w);
    }
  } else {
#pragma unroll
    for (int g4 = 0; g4 < 16; g4++) {
      int cb = 60 - 4 * g4;
      float4 dv4 = *(const float4*)&lds[dloc][cb];
      float4 dx4 = *(const float4*)&lds[16 + dloc][cb];
      float4 bv4 = *(const float4*)&lds[32 + n][cb];
      SCAN_STEPA(dv4.w, dx4.w, bv4.w);
      SCAN_STEPA(dv4.z, dx4.z, bv4.z);
      SCAN_STEPA(dv4.y, dx4.y, bv4.y);
      SCAN_STEPA(dv4.x, dx4.x, bv4.x);
    }
  }
  cP[(size_t)bid * 256 + t] = P;
  cQ[(size_t)bid * 256 + t] = h;
}

#define SCAN_STEPY(DVV, DXV, BVV, CVV, COL) {      \
    float e_ = __expf((DVV) * A);                  \
    h = h * e_ + (BVV) * (DXV);                    \
    float pp_ = h * (CVV);                         \
    pp_ = ror_add<1>(pp_);                         \
    pp_ = ror_add<2>(pp_);                         \
    pp_ = ror_add<4>(pp_);                         \
    pp_ = ror_add<8>(pp_);                         \
    ysel = (((COL) & 15) == n) ? pp_ : ysel; }

__global__ __launch_bounds__(256) void scanC_k(
    const unsigned short* __restrict__ f1b, const unsigned short* __restrict__ f2b,
    const unsigned short* __restrict__ f3b,
    const float* __restrict__ d1f, const float* __restrict__ bc1f,
    const float* __restrict__ d1b, const float* __restrict__ bc1b,
    const float* __restrict__ d2,  const float* __restrict__ bc2,
    const float* __restrict__ d3,  const float* __restrict__ bc3,
    float* __restrict__ y1f, float* __restrict__ y1b,
    float* __restrict__ y2f, float* __restrict__ y2b,
    float* __restrict__ y3f, float* __restrict__ y3b,
    const float* __restrict__ Al1, const float* __restrict__ Dv1,
    const float* __restrict__ Al2, const float* __restrict__ Dv2,
    const float* __restrict__ Al3, const float* __restrict__ Dv3,
    const float* __restrict__ cP, const float* __restrict__ cQ)
{
  // rows: delta[0,16) dx[16,32) B[32,48) C[48,64)
  __shared__ __align__(16) float lds[64][68];
  int bid = blockIdx.x;
  int sid, tseg, L, sbase; const unsigned short* xin;
  const float *dlp, *bcp, *Alp, *Dvp; float* yo;
  if (bid < 4096) {
    sid = bid >> 4; tseg = bid & 15; sbase = sid * 16; L = 1024; xin = f1b;
    if (((sid >> 4) & 1) == 0) { dlp = d1f; bcp = bc1f; Alp = Al1; Dvp = Dv1; yo = y1f; }
    else                       { dlp = d1b; bcp = bc1b; Alp = Al2; Dvp = Dv2; yo = y1b; }
  } else if (bid < 5120) {
    int idx = bid - 4096; sid = idx >> 2; tseg = idx & 3; sbase = 4096 + sid * 4;
    L = 256; xin = f2b; dlp = d2; bcp = bc2; Alp = Al2; Dvp = Dv2;
    yo = ((sid >> 4) & 1) ? y2b : y2f;
  } else {
    sid = bid - 5120; tseg = 0; sbase = -1; L = 64;
    xin = f3b; dlp = d3; bcp = bc3; Alp = Al3; Dvp = Dv3;
    yo = ((sid >> 4) & 1) ? y3b : y3f;
  }
  int b = sid >> 5, dir = (sid >> 4) & 1, g = sid & 15;
  int t = threadIdx.x, n = t & 15, dloc = t >> 4, d = g * 16 + dloc;
  int mbase = dir ? (L - 64 * (tseg + 1)) : 64 * tseg;

  int r0 = t >> 4, cs = t & 15;
  {
    const float* p0 = dlp + ((size_t)b * 256 + g * 16 + r0) * L + mbase;
    const unsigned short* p1 = xin + ((size_t)b * 256 + g * 16 + r0) * L + mbase;
    const float* p2 = bcp + ((size_t)b * 32 + r0) * L + mbase;
    const float* p3 = bcp + ((size_t)b * 32 + 16 + r0) * L + mbase;
    float4 v0 = *(const float4*)(p0 + cs * 4);
    float4 xf = bf2f4(*(const ushort4*)(p1 + cs * 4));
    float4 v2 = *(const float4*)(p2 + cs * 4);
    float4 v3 = *(const float4*)(p3 + cs * 4);
    float4 dx = make_float4(v0.x * xf.x, v0.y * xf.y, v0.z * xf.z, v0.w * xf.w);
    *(float4*)&lds[r0][cs * 4]      = v0;
    *(float4*)&lds[16 + r0][cs * 4] = dx;
    *(float4*)&lds[32 + r0][cs * 4] = v2;
    *(float4*)&lds[48 + r0][cs * 4] = v3;
  }
  float A   = -expf(Alp[d * 16 + n]);
  float Dvv = Dvp[d];
  // carry lookback over finished scanA results (replaces scanB)
  float h = 0.f;
  if (sbase >= 0) {
    for (int s = 0; s < tseg; ++s) {
      size_t off = (size_t)(sbase + s) * 256 + t;
      h = cP[off] * h + cQ[off];
    }
  }
  __syncthreads();

  float* ybase = yo + ((size_t)b * L + mbase) * 256 + d;
#pragma unroll
  for (int jj0 = 0; jj0 < 64; jj0 += 16) {
    float ysel = 0.f;
    if (dir == 0) {
#pragma unroll
      for (int g4 = 0; g4 < 4; g4++) {
        int cb = jj0 + 4 * g4;
        float4 dv4 = *(const float4*)&lds[dloc][cb];
        float4 dx4 = *(const float4*)&lds[16 + dloc][cb];
        float4 bv4 = *(const float4*)&lds[32 + n][cb];
        float4 cv4 = *(const float4*)&lds[48 + n][cb];
        SCAN_STEPY(dv4.x, dx4.x, bv4.x, cv4.x, cb + 0);
        SCAN_STEPY(dv4.y, dx4.y, bv4.y, cv4.y, cb + 1);
        SCAN_STEPY(dv4.z, dx4.z, bv4.z, cv4.z, cb + 2);
        SCAN_STEPY(dv4.w, dx4.w, bv4.w, cv4.w, cb + 3);
      }
    } else {
#pragma unroll
      for (int g4 = 0; g4 < 4; g4++) {
        int cb = 60 - jj0 - 4 * g4;
        float4 dv4 = *(const float4*)&lds[dloc][cb];
        float4 dx4 = *(const float4*)&lds[16 + dloc][cb];
        float4 bv4 = *(const float4*)&lds[32 + n][cb];
        float4 cv4 = *(const float4*)&lds[48 + n][cb];
        SCAN_STEPY(dv4.w, dx4.w, bv4.w, cv4.w, cb + 3);
        SCAN_STEPY(dv4.z, dx4.z, bv4.z, cv4.z, cb + 2);
        SCAN_STEPY(dv4.y, dx4.y, bv4.y, cv4.y, cb + 1);
        SCAN_STEPY(dv4.x, dx4.x, bv4.x, cv4.x, cb + 0);
      }
    }
    int colbase = dir ? 48 - jj0 : jj0;
    float dsel  = lds[dloc][colbase + n];
    float dxsel = lds[16 + dloc][colbase + n];
    float xsel  = dxsel / fmaxf(dsel, 1e-30f);       // recover x (delta>0)
    ybase[(size_t)(colbase + n) * 256] = ysel + xsel * Dvv;
  }
}

// ---------------------------------------------------------------------------
// LayerNorm(fwd)+LayerNorm(bwd) + optional upsample add + optional *silu(z).
// szb is bf16. OUTBF=1 writes bf16 (for the final GEMM operand G).
// ---------------------------------------------------------------------------
template <int OUTBF>
__global__ __launch_bounds__(256) void ln_combine(
    const float* __restrict__ yf, const float* __restrict__ yb,
    const float* __restrict__ gf, const float* __restrict__ bef,
    const float* __restrict__ gb, const float* __restrict__ beb,
    const float* __restrict__ up, int Wc,
    const unsigned short* __restrict__ szb, void* __restrict__ outv,
    int L, int Wf)
{
  int bid = blockIdx.x;
  int b = bid / L;
  int l = bid - b * L;
  int d = threadIdx.x;
  size_t base = ((size_t)b * L + l) * 256 + d;
  float vf = yf[base], vb = yb[base];
  float4 s = make_float4(vf, vf * vf, vb, vb * vb);
#pragma unroll
  for (int m = 1; m < 64; m <<= 1) {
    s.x += __shfl_xor(s.x, m);
    s.y += __shfl_xor(s.y, m);
    s.z += __shfl_xor(s.z, m);
    s.w += __shfl_xor(s.w, m);
  }
  __shared__ float red[4][4];
  int w = threadIdx.x >> 6;
  if ((threadIdx.x & 63) == 0) {
    red[w][0] = s.x; red[w][1] = s.y; red[w][2] = s.z; red[w][3] = s.w;
  }
  __syncthreads();
  float s0 = red[0][0] + red[1][0] + red[2][0] + red[3][0];
  float s1 = red[0][1] + red[1][1] + red[2][1] + red[3][1];
  float s2 = red[0][2] + red[1][2] + red[2][2] + red[3][2];
  float s3 = red[0][3] + red[1][3] + red[2][3] + red[3][3];
  const float inv = 1.f / 256.f;
  float muf = s0 * inv, varf = s1 * inv - muf * muf;
  float mub = s2 * inv, varb = s3 * inv - mub * mub;
  float rf = rsqrtf(varf + 1e-5f);
  float rb = rsqrtf(varb + 1e-5f);
  float v = (vf - muf) * rf * gf[d] + bef[d] + (vb - mub) * rb * gb[d] + beb[d];
  if (up) {
    int y = l / Wf, x = l - y * Wf;
    int lc = (y >> 1) * Wc + (x >> 1);
    v += up[((size_t)b * (L >> 2) + lc) * 256 + d];
  }
  if (szb) v *= bf2f(szb[base]);
  if (OUTBF) ((unsigned short*)outv)[base] = f2bf(v);
  else       ((float*)outv)[base] = v;
}

// ---------------------------------------------------------------------------
extern "C" void kernel_launch(void* const* d_in, const int* in_sizes, int n_in,
                              void* d_out, int out_size, void* d_ws, size_t ws_size,
                              hipStream_t stream) {
  (void)in_sizes; (void)n_in; (void)out_size; (void)ws_size;
  const float* input_f = (const float*)d_in[0];
  const float* in_w  = (const float*)d_in[1];
  const float* in_b  = (const float*)d_in[2];
  const float* c1_w  = (const float*)d_in[3];
  const float* c1_b  = (const float*)d_in[4];
  const float* c2_w  = (const float*)d_in[5];
  const float* c2_b  = (const float*)d_in[6];
  const float* c3_w  = (const float*)d_in[7];
  const float* c3_b  = (const float*)d_in[8];
  const float* out_w = (const float*)d_in[9];
  const float* out_b = (const float*)d_in[10];
  const float* xw1  = (const float*)d_in[11];
  const float* dtw1 = (const float*)d_in[12];
  const float* dtb1 = (const float*)d_in[13];
  const float* Al1  = (const float*)d_in[14];
  const float* Dv1  = (const float*)d_in[15];
  const float* g1   = (const float*)d_in[16];
  const float* be1  = (const float*)d_in[17];
  const float* xw2  = (const float*)d_in[18];
  const float* dtw2 = (const float*)d_in[19];
  const float* dtb2 = (const float*)d_in[20];
  const float* Al2  = (const float*)d_in[21];
  const float* Dv2  = (const float*)d_in[22];
  const float* g2   = (const float*)d_in[23];
  const float* be2  = (const float*)d_in[24];
  const float* xw3  = (const float*)d_in[25];
  const float* dtw3 = (const float*)d_in[26];
  const float* dtb3 = (const float*)d_in[27];
  const float* Al3  = (const float*)d_in[28];
  const float* Dv3  = (const float*)d_in[29];
  const float* g3   = (const float*)d_in[30];
  const float* be3  = (const float*)d_in[31];

  float* ws = (float*)d_ws;
  constexpr size_t M1 = 2097152;   // 8*256*1024 floats = 8 MB
  // Region map; lifetimes verified against launch order:
  float* d1f = ws;                                      // R0 fp32 8MB
  unsigned short* xt = (unsigned short*)(ws + M1);      // R1 [0,4MB) dead after c1
  float* y1f = ws + M1;                                 // R1 (after xt dead)
  unsigned short* szb = (unsigned short*)(ws + 2 * M1); // R2 [0,4MB) alive->ln1
  unsigned short* f1b = (unsigned short*)(ws + 3 * M1); // R3 [0,4MB) alive->scanC
  unsigned short* G = (unsigned short*)(ws + 3 * M1) + 2097152; // R3 [4,8MB)
  float* d1b = ws + 4 * M1;                             // R4 fp32 8MB
  unsigned short* inT = (unsigned short*)(ws + 5 * M1); // R5 [0,8MB) dead after inproj
  unsigned short* ic2 = inT;                            // R5 [0,4MB)
  unsigned short* f1t = inT + 2097152;                  // R5 [4,8MB) dead after fat1
  unsigned short* ic3 = f1t;                            // R5 [4,8MB) after f1t dead
  float* y1b = ws + 5 * M1;                             // R5 (after ic2/ic3 dead)
  size_t o = 6 * M1;
  unsigned short* f2b = (unsigned short*)(ws + o); o += 524288;  // 1MB used
  unsigned short* f3b = (unsigned short*)(ws + o); o += 131072;
  float* bc1f = ws + o; o += 262144;
  float* bc1b = ws + o; o += 262144;
  float* d2   = ws + o; o += 524288;
  float* bc2  = ws + o; o += 65536;
  float* d3   = ws + o; o += 131072;
  float* bc3  = ws + o; o += 16384;
  float* y2f  = ws + o; o += 524288;
  float* y2b  = ws + o; o += 524288;
  float* y3f  = ws + o; o += 131072;
  float* y3b  = ws + o; o += 131072;
  float* y3c  = ws + o; o += 131072;
  float* y2c  = ws + o; o += 524288;
  float* cP   = ws + o; o += 1310720;
  float* cQ   = ws + o; o += 1310720;
  unsigned short* wsW = (unsigned short*)(ws + o); o += 506880;
  // xd buffers alias cP (dead before scanA writes cP):
  float* xd12 = cP;                 // (b,80,1024)
  float* xd2  = cP + 655360;        // (b,40,256)
  float* xd3  = cP + 737280;        // (b,40,64)
  // pixel-major bf16 f2/f3 alias cQ (dead before scanA writes cQ):
  unsigned short* f2t = (unsigned short*)cQ;            // (b,256,256)
  unsigned short* f3t = (unsigned short*)(cQ + 262144); // (b,64,256)
  // bf16 weight sub-pointers:
  unsigned short* w_in   = wsW;
  unsigned short* w_c1   = wsW + 262144;
  unsigned short* w_c2   = wsW + 327680;   // k-reordered
  unsigned short* w_c3   = wsW + 589824;   // k-reordered
  unsigned short* w_out  = wsW + 851968;
  unsigned short* w_xw12 = wsW + 983040;   // [xw1;xw2] stacked (80x256)
  unsigned short* w_xw2  = wsW + 993280;
  unsigned short* w_xw3  = wsW + 1003520;

  dim3 blk(256);

  // 1. weights->bf16 + input transpose-convert (fused)
  prep_k<<<dim3(8056), blk, 0, stream>>>(in_w, c1_w, c2_w, c3_w, out_w,
                                         xw1, xw2, xw3, wsW, input_f, inT);
  // 2. in-proj: xt bf16 (b,p,256) + szb bf16 (b,p,256)
  mgemm_k<1><<<dim3(256), blk, 0, stream>>>(inT, 1024 * 512, w_in, 0, in_b,
                                            xt, szb, 1024, 512, 512, 8, 4);
  // 3. c1 (dual bf16): f1b (b,256,1024) + f1t (b,1024,256)
  mgemm_k<3><<<dim3(128), blk, 0, stream>>>(w_c1, 0, xt, 1024 * 256, c1_b,
                                            f1b, f1t, 256, 1024, 256, 2, 8);
  // 4. fat1: xd12 GEMM + im2col2 (both read f1t only)
  fat1_k<<<dim3(1088), blk, 0, stream>>>(w_xw12, f1t, xd12, ic2);
  // 5. c2 (dual bf16): f2b + f2t
  mgemm_k<3><<<dim3(32), blk, 0, stream>>>(w_c2, 0, ic2, 256 * 1024, c2_b,
                                           f2b, f2t, 256, 256, 1024, 2, 2);
  // 6. fat2: xd2 GEMM + im2col3 (both read f2t only)
  fat2_k<<<dim3(272), blk, 0, stream>>>(w_xw2, f2t, xd2, ic3);
  // 7. c3 (dual bf16): f3b + f3t
  mgemm_k<3><<<dim3(16), blk, 0, stream>>>(w_c3, 0, ic3, 64 * 1024, c3_b,
                                           f3b, f3t, 256, 64, 1024, 2, 1);
  // 8. xd3
  mgemm_k<0><<<dim3(8), blk, 0, stream>>>(w_xw3, 0, f3t, 64 * 256, nullptr,
                                          xd3, nullptr, 40, 64, 256, 1, 1);
  // 9. merged delta/softplus + B/C repack
  post_all_k<<<dim3(1184), blk, 0, stream>>>(xd12, xd2, xd3,
                                             dtw1, dtb1, dtw2, dtb2, dtw3, dtb3,
                                             d1f, bc1f, d1b, bc1b, d2, bc2, d3, bc3);
  // 10-11. segment-parallel scan (scanC does its own carry lookback)
  scanA_k<<<dim3(5120), blk, 0, stream>>>(f1b, f2b, d1f, bc1f, d1b, bc1b,
                                          d2, bc2, Al1, Al2, cP, cQ);
  scanC_k<<<dim3(5376), blk, 0, stream>>>(f1b, f2b, f3b,
                                          d1f, bc1f, d1b, bc1b, d2, bc2, d3, bc3,
                                          y1f, y1b, y2f, y2b, y3f, y3b,
                                          Al1, Dv1, Al2, Dv2, Al3, Dv3, cP, cQ);
  // 12-14. LN + combine (level 1 multiplies silu(z) and writes bf16 G)
  ln_combine<0><<<dim3(512), blk, 0, stream>>>(y3f, y3b, g3, be3, g3, be3,
                                               nullptr, 0, nullptr, y3c, 64, 8);
  ln_combine<0><<<dim3(2048), blk, 0, stream>>>(y2f, y2b, g2, be2, g2, be2,
                                                y3c, 8, nullptr, y2c, 256, 16);
  ln_combine<1><<<dim3(8192), blk, 0, stream>>>(y1f, y1b, g1, be1, g2, be2,
                                                y2c, 16, szb, G, 1024, 32);
  // 15. out-proj -> d_out fp32 (b,512,1024)
  mgemm_k<0><<<dim3(256), blk, 0, stream>>>(w_out, 0, G, 1024 * 256, out_b,
                                            (float*)d_out, nullptr,
                                            512, 1024, 256, 4, 8);
}